// Round 4
// baseline (6001.391 us; speedup 1.0000x reference)
//
#include <hip/hip_runtime.h>

// ---------------------------------------------------------------------------
// BiNet R4: per-node gather, 2 lanes/node, count-sorted for balance.
//   * counting-sort nodes by (branch, count) -> wave lanes have equal work,
//     branch wave-uniform -> weights via scalar s_load.
//   * 2 lanes per node: each lane runs full 68->32->32 MLP on half the edges
//     (h1b hoist of the x_dna part), pair-reduce via shfl_xor(1).
//   * zero atomics on output; every node stored once (no memset/copy).
//   * VGPR <= 128 enforced (launch_bounds) -- R3 died at 132 VGPR (2 waves/SIMD).
// ---------------------------------------------------------------------------

#define IN_C 32
#define IN_F 68

__device__ __forceinline__ float angf(float ax, float ay, float az,
                                      float bx, float by, float bz) {
    float cx = ay * bz - az * by;
    float cy = az * bx - ax * bz;
    float cz = ax * by - ay * bx;
    float cn = sqrtf(cx * cx + cy * cy + cz * cz);
    float dt = ax * bx + ay * by + az * bz;
    return atan2f(cn, dt);
}

__device__ __forceinline__ int branch_of(int m) {
    if (m == 0 || m == 10) return 0;
    if (m == 1 || m == 9)  return 1;
    if (m >= 2 && m <= 5)  return 2;
    return 3;
}

// slot(dst): group-major, then rank-in-group, then idx = dst/11
__device__ __forceinline__ int slot_of(int dst, int NB) {
    int idx = dst / 11;
    int m = dst - idx * 11;
    int g, rank;
    if (m == 0)       { g = 0; rank = 0; }
    else if (m == 10) { g = 0; rank = 1; }
    else if (m == 1)  { g = 1; rank = 0; }
    else if (m == 9)  { g = 1; rank = 1; }
    else if (m <= 5)  { g = 2; rank = m - 2; }
    else              { g = 3; rank = m - 6; }
    static const int base_nb[4] = {0, 2, 4, 8};
    return (base_nb[g] + rank) * NB + idx;
}

__device__ __forceinline__ int group_of_q(int q) {
    return (q < 2) ? 0 : ((q < 4) ? 1 : ((q < 8) ? 2 : 3));
}

// --- CSR build ---------------------------------------------------------------
__global__ void k_count(const int* __restrict__ edst, int E, int* counts, int NB) {
    int t = blockIdx.x * blockDim.x + threadIdx.x;
    if (t >= E) return;
    atomicAdd(&counts[slot_of(edst[t], NB)], 1);
}

__global__ __launch_bounds__(1024) void k_scan1(const int* __restrict__ counts,
                                                int NN, int* cursor, int* blk) {
    __shared__ int wsum[16];
    int t = blockIdx.x * 1024 + threadIdx.x;
    int lane = threadIdx.x & 63;
    int wid = threadIdx.x >> 6;
    int c = (t < NN) ? counts[t] : 0;
    int inc = c;
    #pragma unroll
    for (int d = 1; d < 64; d <<= 1) {
        int v = __shfl_up(inc, d, 64);
        if (lane >= d) inc += v;
    }
    if (lane == 63) wsum[wid] = inc;
    __syncthreads();
    if (threadIdx.x < 16) {
        int v = wsum[threadIdx.x];
        int wi = v;
        #pragma unroll
        for (int d = 1; d < 16; d <<= 1) {
            int u = __shfl_up(wi, d, 64);
            if (threadIdx.x >= d) wi += u;
        }
        wsum[threadIdx.x] = wi - v;
        if (threadIdx.x == 15) blk[blockIdx.x] = wi;
    }
    __syncthreads();
    if (t < NN) cursor[t] = inc - c + wsum[wid];
}

// exclusive scan of up to 256 ints in place
__global__ __launch_bounds__(256) void k_scan2(int* blk, int nblk) {
    __shared__ int wsum[4];
    int lane = threadIdx.x & 63;
    int wid = threadIdx.x >> 6;
    int v = (threadIdx.x < nblk) ? blk[threadIdx.x] : 0;
    int inc = v;
    #pragma unroll
    for (int d = 1; d < 64; d <<= 1) {
        int u = __shfl_up(inc, d, 64);
        if (lane >= d) inc += u;
    }
    if (lane == 63) wsum[wid] = inc;
    __syncthreads();
    if (threadIdx.x < 4) {
        int w = wsum[threadIdx.x];
        int wi = w;
        #pragma unroll
        for (int d = 1; d < 4; d <<= 1) {
            int u = __shfl_up(wi, d, 64);
            if (threadIdx.x >= d) wi += u;
        }
        wsum[threadIdx.x] = wi - w;
    }
    __syncthreads();
    if (threadIdx.x < nblk) blk[threadIdx.x] = inc - v + wsum[wid];
}

__global__ __launch_bounds__(1024) void k_scan3(int* cursor, const int* blk, int NN) {
    int t = blockIdx.x * 1024 + threadIdx.x;
    if (t >= NN) return;
    cursor[t] += blk[blockIdx.x];
}

__global__ void k_fill(const int* __restrict__ esrc, const int* __restrict__ edst,
                       int E, int* cursor, int* __restrict__ pool_src, int NB) {
    int t = blockIdx.x * blockDim.x + threadIdx.x;
    if (t >= E) return;
    int pos = atomicAdd(&cursor[slot_of(edst[t], NB)], 1);
    pool_src[pos] = esrc[t];
}

// --- (branch, count) histogram: LDS-aggregated, grid-stride ------------------
__global__ __launch_bounds__(256) void k_hist(const int* __restrict__ counts,
                                              int NN, int NB, int* hist) {
    __shared__ int lh[256];
    lh[threadIdx.x] = 0;
    __syncthreads();
    for (int t = blockIdx.x * 256 + threadIdx.x; t < NN; t += gridDim.x * 256) {
        int g = group_of_q(t / NB);
        int c = counts[t]; c = c > 63 ? 63 : c;
        atomicAdd(&lh[g * 64 + c], 1);
    }
    __syncthreads();
    if (lh[threadIdx.x]) atomicAdd(&hist[threadIdx.x], lh[threadIdx.x]);
}

__global__ void k_assign(const int* __restrict__ counts, int NN, int NB,
                         int* cur, int* __restrict__ node_order) {
    int t = blockIdx.x * blockDim.x + threadIdx.x;
    if (t >= NN) return;
    int g = group_of_q(t / NB);
    int c = counts[t]; c = c > 63 ? 63 : c;
    int pos = atomicAdd(&cur[g * 64 + c], 1);
    node_order[pos] = t;
}

// --- main kernel: 2 lanes per node, branch wave-uniform ----------------------
__global__ __launch_bounds__(256, 4) void k_nodes2(
    const float* __restrict__ x_dna, const float* __restrict__ v_dna,
    const float* __restrict__ x_prot, const float* __restrict__ v_prot,
    const float* __restrict__ prot_vec, const float* __restrict__ dna_vec,
    const float* __restrict__ W1, const float* __restrict__ b1,
    const float* __restrict__ W2, const float* __restrict__ b2,
    const int* __restrict__ node_order, const int* __restrict__ rowend,
    const int* __restrict__ counts, const int* __restrict__ pool_src,
    float* __restrict__ out, float* __restrict__ conv, int NB)
{
    int t = blockIdx.x * 256 + threadIdx.x;
    int NN = NB * 11;
    int pid = t >> 1;
    int half = t & 1;
    bool valid = (pid < NN);
    int slot = valid ? node_order[pid] : 0;

    // decode slot -> (branch g, dst)
    int q = slot / NB;
    int idx = slot - q * NB;
    int g = group_of_q(q);
    int m;
    if (g == 0)      m = (q == 0) ? 0 : 10;
    else if (g == 1) m = (q == 2) ? 1 : 9;
    else if (g == 2) m = 2 + (q - 4);
    else             m = 6 + (q - 8);
    int dst = idx * 11 + m;
    int b = valid ? g : -1;

    int n_all = valid ? counts[slot] : 0;
    int start_all = valid ? (rowend[slot] - n_all) : 0;
    int n0 = (n_all + 1) >> 1;
    int start = half ? (start_all + n0) : start_all;
    int n = half ? (n_all - n0) : n0;

    float acc[IN_C];
    #pragma unroll
    for (int c = 0; c < IN_C; ++c) acc[c] = 0.0f;

    // branch passes (count-sort is branch-major: ~1 pass for all but ~3 waves)
    unsigned long long todo = __ballot(valid);
    while (todo) {
        int bb = __builtin_amdgcn_readlane(b, __ffsll((long long)todo) - 1);
        bool mine = valid && (b == bb);
        if (mine) {
            const float* Wa  = W1 + bb * (IN_F * IN_C);
            const float* Wb  = W2 + bb * (IN_C * IN_C);
            const float* ba  = b1 + bb * IN_C;
            const float* bb2 = b2 + bb * IN_C;

            float vdx = v_dna[dst * 3 + 0], vdy = v_dna[dst * 3 + 1], vdz = v_dna[dst * 3 + 2];
            float nix = dna_vec[dst * 3 + 0], niy = dna_vec[dst * 3 + 1], niz = dna_vec[dst * 3 + 2];

            // h1b = b1 + W1[rows 36..67] . x_dna[dst]  (hoisted; scalar weights)
            float h1b[IN_C];
            #pragma unroll
            for (int c = 0; c < IN_C; ++c) h1b[c] = ba[c];
            {
                const float4* xd = reinterpret_cast<const float4*>(x_dna + (size_t)dst * IN_C);
                #pragma unroll
                for (int kk = 0; kk < 8; ++kk) {
                    float4 xv = xd[kk];
                    float fs[4] = {xv.x, xv.y, xv.z, xv.w};
                    #pragma unroll
                    for (int j = 0; j < 4; ++j)
                        #pragma unroll
                        for (int c = 0; c < IN_C; ++c)
                            h1b[c] = fmaf(fs[j], Wa[(36 + kk * 4 + j) * IN_C + c], h1b[c]);
                }
            }

            for (int k = 0; k < n; ++k) {
                int src = pool_src[start + k];

                float vpx = v_prot[src * 3 + 0], vpy = v_prot[src * 3 + 1], vpz = v_prot[src * 3 + 2];
                float njx = prot_vec[src * 3 + 0], njy = prot_vec[src * 3 + 1], njz = prot_vec[src * 3 + 2];
                float dx = vpx - vdx, dy = vpy - vdy, dz = vpz - vdz;
                float pf[4];
                pf[0] = sqrtf(dx * dx + dy * dy + dz * dz);
                pf[1] = angf(nix, niy, niz, dx, dy, dz);
                pf[2] = angf(njx, njy, njz, dx, dy, dz);
                pf[3] = angf(nix, niy, niz, njx, njy, njz);

                float h1[IN_C];
                #pragma unroll
                for (int c = 0; c < IN_C; ++c) h1[c] = h1b[c];

                const float4* xp = reinterpret_cast<const float4*>(x_prot + (size_t)src * IN_C);
                #pragma unroll
                for (int kk = 0; kk < 8; ++kk) {
                    float4 xv = xp[kk];
                    float fs[4] = {xv.x, xv.y, xv.z, xv.w};
                    #pragma unroll
                    for (int j = 0; j < 4; ++j)
                        #pragma unroll
                        for (int c = 0; c < IN_C; ++c)
                            h1[c] = fmaf(fs[j], Wa[(kk * 4 + j) * IN_C + c], h1[c]);
                }
                #pragma unroll
                for (int j = 0; j < 4; ++j)
                    #pragma unroll
                    for (int c = 0; c < IN_C; ++c)
                        h1[c] = fmaf(pf[j], Wa[(32 + j) * IN_C + c], h1[c]);

                float h2[IN_C];
                #pragma unroll
                for (int c = 0; c < IN_C; ++c) h2[c] = bb2[c];
                #pragma unroll
                for (int k2 = 0; k2 < IN_C; ++k2) {
                    float f = fmaxf(h1[k2], 0.0f);
                    #pragma unroll
                    for (int c = 0; c < IN_C; ++c)
                        h2[c] = fmaf(f, Wb[k2 * IN_C + c], h2[c]);
                }
                #pragma unroll
                for (int c = 0; c < IN_C; ++c)
                    acc[c] += fmaxf(h2[c], 0.0f);
            }
        }
        todo &= ~__ballot(mine);
    }

    // pair reduce: lanes (2i, 2i+1) hold the two halves of node i
    #pragma unroll
    for (int c = 0; c < IN_C; ++c)
        acc[c] += __shfl_xor(acc[c], 1, 64);

    if (valid) {
        // out == conv (messages >= 0 -> relu(agg) == agg)
        float* p = (half ? conv : out) + (size_t)dst * IN_C;
        float4* p4 = reinterpret_cast<float4*>(p);
        #pragma unroll
        for (int qq = 0; qq < 8; ++qq) {
            float4 v;
            v.x = acc[qq * 4 + 0]; v.y = acc[qq * 4 + 1];
            v.z = acc[qq * 4 + 2]; v.w = acc[qq * 4 + 3];
            p4[qq] = v;
        }
    }
}

// --- fallback (ws too small / odd shape): per-edge atomics -------------------
__global__ __launch_bounds__(256) void k_edges_fallback(
    const float* __restrict__ x_dna, const float* __restrict__ v_dna,
    const float* __restrict__ x_prot, const float* __restrict__ v_prot,
    const float* __restrict__ prot_vec, const float* __restrict__ dna_vec,
    const int* __restrict__ esrc, const int* __restrict__ edst,
    const float* __restrict__ W1, const float* __restrict__ b1,
    const float* __restrict__ W2, const float* __restrict__ b2,
    int E, float* __restrict__ conv)
{
    int t = blockIdx.x * blockDim.x + threadIdx.x;
    if (t >= E) return;
    int src = esrc[t], dst = edst[t];
    int b = branch_of(dst % 11);
    const float* Wa  = W1 + b * (IN_F * IN_C);
    const float* Wb  = W2 + b * (IN_C * IN_C);
    const float* ba  = b1 + b * IN_C;
    const float* bb2 = b2 + b * IN_C;

    float vdx = v_dna[dst * 3 + 0], vdy = v_dna[dst * 3 + 1], vdz = v_dna[dst * 3 + 2];
    float vpx = v_prot[src * 3 + 0], vpy = v_prot[src * 3 + 1], vpz = v_prot[src * 3 + 2];
    float nix = dna_vec[dst * 3 + 0], niy = dna_vec[dst * 3 + 1], niz = dna_vec[dst * 3 + 2];
    float njx = prot_vec[src * 3 + 0], njy = prot_vec[src * 3 + 1], njz = prot_vec[src * 3 + 2];
    float dx = vpx - vdx, dy = vpy - vdy, dz = vpz - vdz;
    float pf[4];
    pf[0] = sqrtf(dx * dx + dy * dy + dz * dz);
    pf[1] = angf(nix, niy, niz, dx, dy, dz);
    pf[2] = angf(njx, njy, njz, dx, dy, dz);
    pf[3] = angf(nix, niy, niz, njx, njy, njz);

    float h1[IN_C];
    #pragma unroll
    for (int c = 0; c < IN_C; ++c) h1[c] = ba[c];
    const float4* xp = reinterpret_cast<const float4*>(x_prot + (size_t)src * IN_C);
    #pragma unroll
    for (int kk = 0; kk < 8; ++kk) {
        float4 xv = xp[kk];
        float fs[4] = {xv.x, xv.y, xv.z, xv.w};
        #pragma unroll
        for (int j = 0; j < 4; ++j)
            #pragma unroll
            for (int c = 0; c < IN_C; ++c)
                h1[c] = fmaf(fs[j], Wa[(kk * 4 + j) * IN_C + c], h1[c]);
    }
    #pragma unroll
    for (int j = 0; j < 4; ++j)
        #pragma unroll
        for (int c = 0; c < IN_C; ++c)
            h1[c] = fmaf(pf[j], Wa[(32 + j) * IN_C + c], h1[c]);
    const float4* xd = reinterpret_cast<const float4*>(x_dna + (size_t)dst * IN_C);
    #pragma unroll
    for (int kk = 0; kk < 8; ++kk) {
        float4 xv = xd[kk];
        float fs[4] = {xv.x, xv.y, xv.z, xv.w};
        #pragma unroll
        for (int j = 0; j < 4; ++j)
            #pragma unroll
            for (int c = 0; c < IN_C; ++c)
                h1[c] = fmaf(fs[j], Wa[(36 + kk * 4 + j) * IN_C + c], h1[c]);
    }
    float h2[IN_C];
    #pragma unroll
    for (int c = 0; c < IN_C; ++c) h2[c] = bb2[c];
    #pragma unroll
    for (int k = 0; k < IN_C; ++k) {
        float f = fmaxf(h1[k], 0.0f);
        #pragma unroll
        for (int c = 0; c < IN_C; ++c)
            h2[c] = fmaf(f, Wb[k * IN_C + c], h2[c]);
    }
    float* cv = conv + (size_t)dst * IN_C;
    #pragma unroll
    for (int c = 0; c < IN_C; ++c)
        atomicAdd(&cv[c], fmaxf(h2[c], 0.0f));
}

extern "C" void kernel_launch(void* const* d_in, const int* in_sizes, int n_in,
                              void* d_out, int out_size, void* d_ws, size_t ws_size,
                              hipStream_t stream) {
    const float* x_dna    = (const float*)d_in[0];
    const float* v_dna    = (const float*)d_in[1];
    const float* x_prot   = (const float*)d_in[2];
    const float* v_prot   = (const float*)d_in[3];
    const float* prot_vec = (const float*)d_in[4];
    const float* dna_vec  = (const float*)d_in[5];
    const int*   esrc     = (const int*)d_in[6];
    const int*   edst     = (const int*)d_in[7];
    const float* W1       = (const float*)d_in[8];
    const float* b1       = (const float*)d_in[9];
    const float* W2       = (const float*)d_in[10];
    const float* b2       = (const float*)d_in[11];

    const int E  = in_sizes[6];
    const int ND = in_sizes[0] / IN_C;       // N_DNA
    const int NB = ND / 11;
    const int NN = NB * 11;
    const int half = out_size / 2;
    float* out  = (float*)d_out;
    float* conv = out + half;

    const int nblk_scan = (NN + 1023) / 1024;
    const size_t ws_need = ((size_t)3 * NN + 512 + E) * sizeof(int);
    const int eb = (E + 255) / 256;

    if (ND % 11 == 0 && NN == half / IN_C &&
        ws_size >= ws_need && nblk_scan <= 256) {
        int* counts     = (int*)d_ws;          // NN
        int* rowcur     = counts + NN;         // NN (scan -> cursor -> row end)
        int* node_order = rowcur + NN;         // NN
        int* blk        = node_order + NN;     // 256
        int* hist       = blk + 256;           // 256
        int* pool_src   = hist + 256;          // E

        hipMemsetAsync(counts, 0, (size_t)NN * sizeof(int), stream);
        hipMemsetAsync(hist, 0, 256 * sizeof(int), stream);

        k_count<<<eb, 256, 0, stream>>>(edst, E, counts, NB);
        k_scan1<<<nblk_scan, 1024, 0, stream>>>(counts, NN, rowcur, blk);
        k_scan2<<<1, 256, 0, stream>>>(blk, nblk_scan);
        k_scan3<<<nblk_scan, 1024, 0, stream>>>(rowcur, blk, NN);
        k_fill<<<eb, 256, 0, stream>>>(esrc, edst, E, rowcur, pool_src, NB);

        k_hist<<<128, 256, 0, stream>>>(counts, NN, NB, hist);
        k_scan2<<<1, 256, 0, stream>>>(hist, 256);
        int nb = (NN + 255) / 256;
        k_assign<<<nb, 256, 0, stream>>>(counts, NN, NB, hist, node_order);

        int nb2 = (2 * NN + 255) / 256;
        k_nodes2<<<nb2, 256, 0, stream>>>(
            x_dna, v_dna, x_prot, v_prot, prot_vec, dna_vec,
            W1, b1, W2, b2, node_order, rowcur, counts, pool_src,
            out, conv, NB);
        // k_nodes2 writes every element of out and conv -> no memset/copy
    } else {
        hipMemsetAsync(conv, 0, (size_t)half * sizeof(float), stream);
        k_edges_fallback<<<eb, 256, 0, stream>>>(
            x_dna, v_dna, x_prot, v_prot, prot_vec, dna_vec,
            esrc, edst, W1, b1, W2, b2, E, conv);
        hipMemcpyAsync(out, conv, (size_t)half * sizeof(float),
                       hipMemcpyDeviceToDevice, stream);
    }
}

// Round 5
// 882.152 us; speedup vs baseline: 6.8031x; 6.8031x over previous
//
#include <hip/hip_runtime.h>

// ---------------------------------------------------------------------------
// BiNet R5: per-node gather, 2 lanes/node, count-sorted (branch,count) order.
//   * counting-sort nodes by (branch, edge-count); group bases padded to
//     32 nodes (=64 lanes) -> branch wave-uniform WITHOUT ballot loops.
//   * 2 lanes per node, each runs the full 68->32->32 MLP on half the edges
//     (x_dna part of layer1 hoisted once per lane); pair-reduce shfl_xor(1).
//   * zero atomics on output; even lane stores out, odd stores conv.
//   * plain __launch_bounds__(256): R4 proved a min-waves cap forces scratch
//     spills (VGPR 64 + 8.3GB FETCH). Target: ~96-120 VGPR, AGPR spills only.
// ---------------------------------------------------------------------------

#define IN_C 32
#define IN_F 68

__device__ __forceinline__ float angf(float ax, float ay, float az,
                                      float bx, float by, float bz) {
    float cx = ay * bz - az * by;
    float cy = az * bx - ax * bz;
    float cz = ax * by - ay * bx;
    float cn = sqrtf(cx * cx + cy * cy + cz * cz);
    float dt = ax * bx + ay * by + az * bz;
    return atan2f(cn, dt);
}

__device__ __forceinline__ int branch_of(int m) {
    if (m == 0 || m == 10) return 0;
    if (m == 1 || m == 9)  return 1;
    if (m >= 2 && m <= 5)  return 2;
    return 3;
}

// --- CSR build (keyed by raw dst) --------------------------------------------
__global__ void k_count(const int* __restrict__ edst, int E, int* counts) {
    int t = blockIdx.x * blockDim.x + threadIdx.x;
    if (t >= E) return;
    atomicAdd(&counts[edst[t]], 1);
}

__global__ __launch_bounds__(1024) void k_scan1(const int* __restrict__ counts,
                                                int NN, int* cursor, int* blk) {
    __shared__ int wsum[16];
    int t = blockIdx.x * 1024 + threadIdx.x;
    int lane = threadIdx.x & 63;
    int wid = threadIdx.x >> 6;
    int c = (t < NN) ? counts[t] : 0;
    int inc = c;
    #pragma unroll
    for (int d = 1; d < 64; d <<= 1) {
        int v = __shfl_up(inc, d, 64);
        if (lane >= d) inc += v;
    }
    if (lane == 63) wsum[wid] = inc;
    __syncthreads();
    if (threadIdx.x < 16) {
        int v = wsum[threadIdx.x];
        int wi = v;
        #pragma unroll
        for (int d = 1; d < 16; d <<= 1) {
            int u = __shfl_up(wi, d, 64);
            if (threadIdx.x >= d) wi += u;
        }
        wsum[threadIdx.x] = wi - v;
        if (threadIdx.x == 15) blk[blockIdx.x] = wi;
    }
    __syncthreads();
    if (t < NN) cursor[t] = inc - c + wsum[wid];
}

__global__ __launch_bounds__(256) void k_scan2(int* blk, int nblk) {
    __shared__ int wsum[4];
    int lane = threadIdx.x & 63;
    int wid = threadIdx.x >> 6;
    int v = (threadIdx.x < nblk) ? blk[threadIdx.x] : 0;
    int inc = v;
    #pragma unroll
    for (int d = 1; d < 64; d <<= 1) {
        int u = __shfl_up(inc, d, 64);
        if (lane >= d) inc += u;
    }
    if (lane == 63) wsum[wid] = inc;
    __syncthreads();
    if (threadIdx.x < 4) {
        int w = wsum[threadIdx.x];
        int wi = w;
        #pragma unroll
        for (int d = 1; d < 4; d <<= 1) {
            int u = __shfl_up(wi, d, 64);
            if (threadIdx.x >= d) wi += u;
        }
        wsum[threadIdx.x] = wi - w;
    }
    __syncthreads();
    if (threadIdx.x < nblk) blk[threadIdx.x] = inc - v + wsum[wid];
}

__global__ __launch_bounds__(1024) void k_scan3(int* cursor, const int* blk, int NN) {
    int t = blockIdx.x * 1024 + threadIdx.x;
    if (t >= NN) return;
    cursor[t] += blk[blockIdx.x];
}

__global__ void k_fill(const int* __restrict__ esrc, const int* __restrict__ edst,
                       int E, int* cursor, int* __restrict__ pool_src) {
    int t = blockIdx.x * blockDim.x + threadIdx.x;
    if (t >= E) return;
    int pos = atomicAdd(&cursor[edst[t]], 1);
    pool_src[pos] = esrc[t];
}

// --- (branch, count) histogram ------------------------------------------------
__global__ __launch_bounds__(256) void k_hist(const int* __restrict__ counts,
                                              int ND, int* hist) {
    __shared__ int lh[256];
    lh[threadIdx.x] = 0;
    __syncthreads();
    for (int t = blockIdx.x * 256 + threadIdx.x; t < ND; t += gridDim.x * 256) {
        int g = branch_of(t % 11);
        int c = counts[t]; c = c > 63 ? 63 : c;
        atomicAdd(&lh[g * 64 + c], 1);
    }
    __syncthreads();
    if (lh[threadIdx.x]) atomicAdd(&hist[threadIdx.x], lh[threadIdx.x]);
}

// serial 256-entry scan: bin cursors (in hist, in place) + padded group bases
__global__ void k_padscan(int* hist, int* pbs) {
    int base = 0;
    for (int g = 0; g < 4; ++g) {
        pbs[g] = base;
        int s = 0;
        for (int c = 0; c < 64; ++c) {
            int v = hist[g * 64 + c];
            hist[g * 64 + c] = base + s;
            s += v;
        }
        base = (base + s + 31) & ~31;     // group base 32-node (=64 lane) aligned
    }
    pbs[4] = base;
}

__global__ void k_assign(const int* __restrict__ counts, int ND,
                         int* cur, int* __restrict__ node_order) {
    int t = blockIdx.x * blockDim.x + threadIdx.x;
    if (t >= ND) return;
    int g = branch_of(t % 11);
    int c = counts[t]; c = c > 63 ? 63 : c;
    int pos = atomicAdd(&cur[g * 64 + c], 1);
    node_order[pos] = t;
}

// --- main kernel: 2 lanes/node, branch wave-uniform by construction ----------
__global__ __launch_bounds__(256) void k_nodes2(
    const float* __restrict__ x_dna, const float* __restrict__ v_dna,
    const float* __restrict__ x_prot, const float* __restrict__ v_prot,
    const float* __restrict__ prot_vec, const float* __restrict__ dna_vec,
    const float* __restrict__ W1, const float* __restrict__ b1,
    const float* __restrict__ W2, const float* __restrict__ b2,
    const int* __restrict__ node_order, const int* __restrict__ rowend,
    const int* __restrict__ counts, const int* __restrict__ pool_src,
    const int* __restrict__ pbs,
    float* __restrict__ out, float* __restrict__ conv, int NDp)
{
    int t = blockIdx.x * 256 + threadIdx.x;
    int pid = t >> 1;
    int half = t & 1;
    if (pid >= NDp) return;

    // group: wave-uniform because group bases are 32-node aligned
    int pb1 = pbs[1], pb2 = pbs[2], pb3 = pbs[3];
    int g = (pid >= pb1) + (pid >= pb2) + (pid >= pb3);
    int bb = __builtin_amdgcn_readfirstlane(g);

    int dst = node_order[pid];
    bool valid = (dst >= 0);
    int dsafe = valid ? dst : 0;

    int n_all = valid ? counts[dsafe] : 0;
    int start_all = valid ? (rowend[dsafe] - n_all) : 0;
    int n0 = (n_all + 1) >> 1;
    int n = half ? (n_all - n0) : n0;
    int start = half ? (start_all + n0) : start_all;

    const float* Wa  = W1 + bb * (IN_F * IN_C);
    const float* Wb  = W2 + bb * (IN_C * IN_C);
    const float* ba  = b1 + bb * IN_C;
    const float* bb2 = b2 + bb * IN_C;

    float vdx = v_dna[dsafe * 3 + 0], vdy = v_dna[dsafe * 3 + 1], vdz = v_dna[dsafe * 3 + 2];
    float nix = dna_vec[dsafe * 3 + 0], niy = dna_vec[dsafe * 3 + 1], niz = dna_vec[dsafe * 3 + 2];

    // h1b = b1 + W1[rows 36..67] . x_dna[dst]   (hoisted; scalar weights)
    float h1b[IN_C];
    #pragma unroll
    for (int c = 0; c < IN_C; ++c) h1b[c] = ba[c];
    {
        const float4* xd = reinterpret_cast<const float4*>(x_dna + (size_t)dsafe * IN_C);
        #pragma unroll
        for (int kk = 0; kk < 8; ++kk) {
            float4 xv = xd[kk];
            float fs[4] = {xv.x, xv.y, xv.z, xv.w};
            #pragma unroll
            for (int j = 0; j < 4; ++j)
                #pragma unroll
                for (int c = 0; c < IN_C; ++c)
                    h1b[c] = fmaf(fs[j], Wa[(36 + kk * 4 + j) * IN_C + c], h1b[c]);
        }
    }

    float acc[IN_C];
    #pragma unroll
    for (int c = 0; c < IN_C; ++c) acc[c] = 0.0f;

    for (int k = 0; k < n; ++k) {
        int src = pool_src[start + k];

        float vpx = v_prot[src * 3 + 0], vpy = v_prot[src * 3 + 1], vpz = v_prot[src * 3 + 2];
        float njx = prot_vec[src * 3 + 0], njy = prot_vec[src * 3 + 1], njz = prot_vec[src * 3 + 2];
        float dx = vpx - vdx, dy = vpy - vdy, dz = vpz - vdz;
        float pf[4];
        pf[0] = sqrtf(dx * dx + dy * dy + dz * dz);
        pf[1] = angf(nix, niy, niz, dx, dy, dz);
        pf[2] = angf(njx, njy, njz, dx, dy, dz);
        pf[3] = angf(nix, niy, niz, njx, njy, njz);

        float h1[IN_C];
        #pragma unroll
        for (int c = 0; c < IN_C; ++c) h1[c] = h1b[c];

        const float4* xp = reinterpret_cast<const float4*>(x_prot + (size_t)src * IN_C);
        #pragma unroll
        for (int kk = 0; kk < 8; ++kk) {
            float4 xv = xp[kk];
            float fs[4] = {xv.x, xv.y, xv.z, xv.w};
            #pragma unroll
            for (int j = 0; j < 4; ++j)
                #pragma unroll
                for (int c = 0; c < IN_C; ++c)
                    h1[c] = fmaf(fs[j], Wa[(kk * 4 + j) * IN_C + c], h1[c]);
        }
        #pragma unroll
        for (int j = 0; j < 4; ++j)
            #pragma unroll
            for (int c = 0; c < IN_C; ++c)
                h1[c] = fmaf(pf[j], Wa[(32 + j) * IN_C + c], h1[c]);

        float h2[IN_C];
        #pragma unroll
        for (int c = 0; c < IN_C; ++c) h2[c] = bb2[c];
        #pragma unroll
        for (int k2 = 0; k2 < IN_C; ++k2) {
            float f = fmaxf(h1[k2], 0.0f);
            #pragma unroll
            for (int c = 0; c < IN_C; ++c)
                h2[c] = fmaf(f, Wb[k2 * IN_C + c], h2[c]);
        }
        #pragma unroll
        for (int c = 0; c < IN_C; ++c)
            acc[c] += fmaxf(h2[c], 0.0f);
    }

    // pair reduce: lanes (2i, 2i+1) hold the two halves of node pid
    #pragma unroll
    for (int c = 0; c < IN_C; ++c)
        acc[c] += __shfl_xor(acc[c], 1, 64);

    if (valid) {
        // out == conv (messages >= 0 -> relu(agg) == agg)
        float* p = (half ? conv : out) + (size_t)dst * IN_C;
        float4* p4 = reinterpret_cast<float4*>(p);
        #pragma unroll
        for (int qq = 0; qq < 8; ++qq) {
            float4 v;
            v.x = acc[qq * 4 + 0]; v.y = acc[qq * 4 + 1];
            v.z = acc[qq * 4 + 2]; v.w = acc[qq * 4 + 3];
            p4[qq] = v;
        }
    }
}

// --- fallback (ws too small): per-edge atomics -------------------------------
__global__ __launch_bounds__(256) void k_edges_fallback(
    const float* __restrict__ x_dna, const float* __restrict__ v_dna,
    const float* __restrict__ x_prot, const float* __restrict__ v_prot,
    const float* __restrict__ prot_vec, const float* __restrict__ dna_vec,
    const int* __restrict__ esrc, const int* __restrict__ edst,
    const float* __restrict__ W1, const float* __restrict__ b1,
    const float* __restrict__ W2, const float* __restrict__ b2,
    int E, float* __restrict__ conv)
{
    int t = blockIdx.x * blockDim.x + threadIdx.x;
    if (t >= E) return;
    int src = esrc[t], dst = edst[t];
    int b = branch_of(dst % 11);
    const float* Wa  = W1 + b * (IN_F * IN_C);
    const float* Wb  = W2 + b * (IN_C * IN_C);
    const float* ba  = b1 + b * IN_C;
    const float* bb2 = b2 + b * IN_C;

    float vdx = v_dna[dst * 3 + 0], vdy = v_dna[dst * 3 + 1], vdz = v_dna[dst * 3 + 2];
    float vpx = v_prot[src * 3 + 0], vpy = v_prot[src * 3 + 1], vpz = v_prot[src * 3 + 2];
    float nix = dna_vec[dst * 3 + 0], niy = dna_vec[dst * 3 + 1], niz = dna_vec[dst * 3 + 2];
    float njx = prot_vec[src * 3 + 0], njy = prot_vec[src * 3 + 1], njz = prot_vec[src * 3 + 2];
    float dx = vpx - vdx, dy = vpy - vdy, dz = vpz - vdz;
    float pf[4];
    pf[0] = sqrtf(dx * dx + dy * dy + dz * dz);
    pf[1] = angf(nix, niy, niz, dx, dy, dz);
    pf[2] = angf(njx, njy, njz, dx, dy, dz);
    pf[3] = angf(nix, niy, niz, njx, njy, njz);

    float h1[IN_C];
    #pragma unroll
    for (int c = 0; c < IN_C; ++c) h1[c] = ba[c];
    const float4* xp = reinterpret_cast<const float4*>(x_prot + (size_t)src * IN_C);
    #pragma unroll
    for (int kk = 0; kk < 8; ++kk) {
        float4 xv = xp[kk];
        float fs[4] = {xv.x, xv.y, xv.z, xv.w};
        #pragma unroll
        for (int j = 0; j < 4; ++j)
            #pragma unroll
            for (int c = 0; c < IN_C; ++c)
                h1[c] = fmaf(fs[j], Wa[(kk * 4 + j) * IN_C + c], h1[c]);
    }
    #pragma unroll
    for (int j = 0; j < 4; ++j)
        #pragma unroll
        for (int c = 0; c < IN_C; ++c)
            h1[c] = fmaf(pf[j], Wa[(32 + j) * IN_C + c], h1[c]);
    const float4* xd = reinterpret_cast<const float4*>(x_dna + (size_t)dst * IN_C);
    #pragma unroll
    for (int kk = 0; kk < 8; ++kk) {
        float4 xv = xd[kk];
        float fs[4] = {xv.x, xv.y, xv.z, xv.w};
        #pragma unroll
        for (int j = 0; j < 4; ++j)
            #pragma unroll
            for (int c = 0; c < IN_C; ++c)
                h1[c] = fmaf(fs[j], Wa[(36 + kk * 4 + j) * IN_C + c], h1[c]);
    }
    float h2[IN_C];
    #pragma unroll
    for (int c = 0; c < IN_C; ++c) h2[c] = bb2[c];
    #pragma unroll
    for (int k = 0; k < IN_C; ++k) {
        float f = fmaxf(h1[k], 0.0f);
        #pragma unroll
        for (int c = 0; c < IN_C; ++c)
            h2[c] = fmaf(f, Wb[k * IN_C + c], h2[c]);
    }
    float* cv = conv + (size_t)dst * IN_C;
    #pragma unroll
    for (int c = 0; c < IN_C; ++c)
        atomicAdd(&cv[c], fmaxf(h2[c], 0.0f));
}

extern "C" void kernel_launch(void* const* d_in, const int* in_sizes, int n_in,
                              void* d_out, int out_size, void* d_ws, size_t ws_size,
                              hipStream_t stream) {
    const float* x_dna    = (const float*)d_in[0];
    const float* v_dna    = (const float*)d_in[1];
    const float* x_prot   = (const float*)d_in[2];
    const float* v_prot   = (const float*)d_in[3];
    const float* prot_vec = (const float*)d_in[4];
    const float* dna_vec  = (const float*)d_in[5];
    const int*   esrc     = (const int*)d_in[6];
    const int*   edst     = (const int*)d_in[7];
    const float* W1       = (const float*)d_in[8];
    const float* b1       = (const float*)d_in[9];
    const float* W2       = (const float*)d_in[10];
    const float* b2       = (const float*)d_in[11];

    const int E  = in_sizes[6];
    const int ND = in_sizes[0] / IN_C;       // N_DNA
    const int half = out_size / 2;
    float* out  = (float*)d_out;
    float* conv = out + half;

    const int NDp = ND + 128;                // padded node_order length
    const int nblk_scan = (ND + 1023) / 1024;
    const size_t ws_need = ((size_t)2 * ND + NDp + 256 + 8 + 256 + E) * sizeof(int);
    const int eb = (E + 255) / 256;

    if (ND == half / IN_C && ws_size >= ws_need && nblk_scan <= 256) {
        int* counts     = (int*)d_ws;          // ND
        int* rowcur     = counts + ND;         // ND (scan -> fill cursor -> row end)
        int* node_order = rowcur + ND;         // NDp
        int* blk        = node_order + NDp;    // 256
        int* hist       = blk + 256;           // 256 (bin counts -> bin cursors)
        int* pbs        = hist + 256;          // 8  (padded group bases)
        int* pool_src   = pbs + 8;             // E

        hipMemsetAsync(counts, 0, (size_t)ND * sizeof(int), stream);
        hipMemsetAsync(node_order, 0xFF, (size_t)NDp * sizeof(int), stream);
        hipMemsetAsync(hist, 0, 256 * sizeof(int), stream);

        k_count<<<eb, 256, 0, stream>>>(edst, E, counts);
        k_scan1<<<nblk_scan, 1024, 0, stream>>>(counts, ND, rowcur, blk);
        k_scan2<<<1, 256, 0, stream>>>(blk, nblk_scan);
        k_scan3<<<nblk_scan, 1024, 0, stream>>>(rowcur, blk, ND);
        k_fill<<<eb, 256, 0, stream>>>(esrc, edst, E, rowcur, pool_src);

        k_hist<<<128, 256, 0, stream>>>(counts, ND, hist);
        k_padscan<<<1, 1, 0, stream>>>(hist, pbs);
        k_assign<<<(ND + 255) / 256, 256, 0, stream>>>(counts, ND, hist, node_order);

        int nb2 = (2 * NDp + 255) / 256;
        k_nodes2<<<nb2, 256, 0, stream>>>(
            x_dna, v_dna, x_prot, v_prot, prot_vec, dna_vec,
            W1, b1, W2, b2, node_order, rowcur, counts, pool_src, pbs,
            out, conv, NDp);
        // every node stored exactly once -> no memset/copy of out/conv
    } else {
        hipMemsetAsync(conv, 0, (size_t)half * sizeof(float), stream);
        k_edges_fallback<<<eb, 256, 0, stream>>>(
            x_dna, v_dna, x_prot, v_prot, prot_vec, dna_vec,
            esrc, edst, W1, b1, W2, b2, E, conv);
        hipMemcpyAsync(out, conv, (size_t)half * sizeof(float),
                       hipMemcpyDeviceToDevice, stream);
    }
}

// Round 6
// 589.225 us; speedup vs baseline: 10.1852x; 1.4971x over previous
//
#include <hip/hip_runtime.h>

// ---------------------------------------------------------------------------
// BiNet R6: per-node gather, 2 lanes/node, (branch,count)-sorted node order.
// Changes vs R5 (each tied to a measured counter):
//   * k_nodes2: __launch_bounds__(256,1) -> no forced 96-VGPR AGPR spills
//     (R5: VALUBusy*dur = 233us vs ~54us of real work = spill-move inflation).
//   * h1 computed in two 16-ch halves, each consumed into h2 immediately:
//     peak live ~130 floats (was ~150) -> fits real VGPRs, same FP order.
//   * k_padscan2: parallel (was <<<1,1>>> serial, ~70us of dependent L2 RTs).
//   * k_assign: block-LDS aggregated (was 220K same-address atomics, ~200us).
// ---------------------------------------------------------------------------

#define IN_C 32
#define IN_F 68

__device__ __forceinline__ float angf(float ax, float ay, float az,
                                      float bx, float by, float bz) {
    float cx = ay * bz - az * by;
    float cy = az * bx - ax * bz;
    float cz = ax * by - ay * bx;
    float cn = sqrtf(cx * cx + cy * cy + cz * cz);
    float dt = ax * bx + ay * by + az * bz;
    return atan2f(cn, dt);
}

__device__ __forceinline__ int branch_of(int m) {
    if (m == 0 || m == 10) return 0;
    if (m == 1 || m == 9)  return 1;
    if (m >= 2 && m <= 5)  return 2;
    return 3;
}

// --- CSR build (keyed by raw dst) --------------------------------------------
__global__ void k_count(const int* __restrict__ edst, int E, int* counts) {
    int t = blockIdx.x * blockDim.x + threadIdx.x;
    if (t >= E) return;
    atomicAdd(&counts[edst[t]], 1);
}

__global__ __launch_bounds__(1024) void k_scan1(const int* __restrict__ counts,
                                                int NN, int* cursor, int* blk) {
    __shared__ int wsum[16];
    int t = blockIdx.x * 1024 + threadIdx.x;
    int lane = threadIdx.x & 63;
    int wid = threadIdx.x >> 6;
    int c = (t < NN) ? counts[t] : 0;
    int inc = c;
    #pragma unroll
    for (int d = 1; d < 64; d <<= 1) {
        int v = __shfl_up(inc, d, 64);
        if (lane >= d) inc += v;
    }
    if (lane == 63) wsum[wid] = inc;
    __syncthreads();
    if (threadIdx.x < 16) {
        int v = wsum[threadIdx.x];
        int wi = v;
        #pragma unroll
        for (int d = 1; d < 16; d <<= 1) {
            int u = __shfl_up(wi, d, 64);
            if (threadIdx.x >= d) wi += u;
        }
        wsum[threadIdx.x] = wi - v;
        if (threadIdx.x == 15) blk[blockIdx.x] = wi;
    }
    __syncthreads();
    if (t < NN) cursor[t] = inc - c + wsum[wid];
}

__global__ __launch_bounds__(256) void k_scan2(int* blk, int nblk) {
    __shared__ int wsum[4];
    int lane = threadIdx.x & 63;
    int wid = threadIdx.x >> 6;
    int v = (threadIdx.x < nblk) ? blk[threadIdx.x] : 0;
    int inc = v;
    #pragma unroll
    for (int d = 1; d < 64; d <<= 1) {
        int u = __shfl_up(inc, d, 64);
        if (lane >= d) inc += u;
    }
    if (lane == 63) wsum[wid] = inc;
    __syncthreads();
    if (threadIdx.x < 4) {
        int w = wsum[threadIdx.x];
        int wi = w;
        #pragma unroll
        for (int d = 1; d < 4; d <<= 1) {
            int u = __shfl_up(wi, d, 64);
            if (threadIdx.x >= d) wi += u;
        }
        wsum[threadIdx.x] = wi - w;
    }
    __syncthreads();
    if (threadIdx.x < nblk) blk[threadIdx.x] = inc - v + wsum[wid];
}

__global__ __launch_bounds__(1024) void k_scan3(int* cursor, const int* blk, int NN) {
    int t = blockIdx.x * 1024 + threadIdx.x;
    if (t >= NN) return;
    cursor[t] += blk[blockIdx.x];
}

__global__ void k_fill(const int* __restrict__ esrc, const int* __restrict__ edst,
                       int E, int* cursor, int* __restrict__ pool_src) {
    int t = blockIdx.x * blockDim.x + threadIdx.x;
    if (t >= E) return;
    int pos = atomicAdd(&cursor[edst[t]], 1);
    pool_src[pos] = esrc[t];
}

// --- (branch, count) histogram ------------------------------------------------
__global__ __launch_bounds__(256) void k_hist(const int* __restrict__ counts,
                                              int ND, int* hist) {
    __shared__ int lh[256];
    lh[threadIdx.x] = 0;
    __syncthreads();
    for (int t = blockIdx.x * 256 + threadIdx.x; t < ND; t += gridDim.x * 256) {
        int g = branch_of(t % 11);
        int c = counts[t]; c = c > 63 ? 63 : c;
        atomicAdd(&lh[g * 64 + c], 1);
    }
    __syncthreads();
    if (lh[threadIdx.x]) atomicAdd(&hist[threadIdx.x], lh[threadIdx.x]);
}

// parallel padded scan: wave w scans group w's 64 bins; thread0 pads group bases
__global__ __launch_bounds__(256) void k_padscan2(int* hist, int* pbs) {
    __shared__ int gsum[4];
    __shared__ int gbase[5];
    int lane = threadIdx.x & 63;
    int w = threadIdx.x >> 6;
    int v = hist[threadIdx.x];
    int inc = v;
    #pragma unroll
    for (int d = 1; d < 64; d <<= 1) {
        int u = __shfl_up(inc, d, 64);
        if (lane >= d) inc += u;
    }
    if (lane == 63) gsum[w] = inc;
    __syncthreads();
    if (threadIdx.x == 0) {
        int base = 0;
        #pragma unroll
        for (int g = 0; g < 4; ++g) {
            gbase[g] = base;
            base = (base + gsum[g] + 31) & ~31;   // 32-node (=64-lane) aligned
        }
        gbase[4] = base;
    }
    __syncthreads();
    hist[threadIdx.x] = gbase[w] + inc - v;       // exclusive-in-group + base
    if (threadIdx.x < 5) pbs[threadIdx.x] = gbase[threadIdx.x];
}

// block-LDS-aggregated assign: one global atomic per nonzero bin per block
__global__ __launch_bounds__(256) void k_assign(const int* __restrict__ counts,
                                                int ND, int* cur,
                                                int* __restrict__ node_order) {
    __shared__ int lh[256];
    __shared__ int lbase[256];
    lh[threadIdx.x] = 0;
    __syncthreads();
    int t = blockIdx.x * 256 + threadIdx.x;
    bool v = (t < ND);
    int bin = 0, rank = 0;
    if (v) {
        int g = branch_of(t % 11);
        int c = counts[t]; c = c > 63 ? 63 : c;
        bin = g * 64 + c;
        rank = atomicAdd(&lh[bin], 1);
    }
    __syncthreads();
    int cnt = lh[threadIdx.x];
    if (cnt > 0) lbase[threadIdx.x] = atomicAdd(&cur[threadIdx.x], cnt);
    __syncthreads();
    if (v) node_order[lbase[bin] + rank] = t;
}

// --- main kernel: 2 lanes/node, branch wave-uniform, no spills ---------------
__global__ __launch_bounds__(256, 1) void k_nodes2(
    const float* __restrict__ x_dna, const float* __restrict__ v_dna,
    const float* __restrict__ x_prot, const float* __restrict__ v_prot,
    const float* __restrict__ prot_vec, const float* __restrict__ dna_vec,
    const float* __restrict__ W1, const float* __restrict__ b1,
    const float* __restrict__ W2, const float* __restrict__ b2,
    const int* __restrict__ node_order, const int* __restrict__ rowend,
    const int* __restrict__ counts, const int* __restrict__ pool_src,
    const int* __restrict__ pbs,
    float* __restrict__ out, float* __restrict__ conv, int NDp)
{
    int t = blockIdx.x * 256 + threadIdx.x;
    int pid = t >> 1;
    int half = t & 1;
    if (pid >= NDp) return;

    // group wave-uniform: group bases are 32-node aligned
    int pb1 = pbs[1], pb2 = pbs[2], pb3 = pbs[3];
    int g = (pid >= pb1) + (pid >= pb2) + (pid >= pb3);
    int bb = __builtin_amdgcn_readfirstlane(g);

    int dst = node_order[pid];
    bool valid = (dst >= 0);
    int dsafe = valid ? dst : 0;

    int n_all = valid ? counts[dsafe] : 0;
    int start_all = valid ? (rowend[dsafe] - n_all) : 0;
    int n0 = (n_all + 1) >> 1;
    int n = half ? (n_all - n0) : n0;
    int start = half ? (start_all + n0) : start_all;

    const float* Wa  = W1 + bb * (IN_F * IN_C);
    const float* Wb  = W2 + bb * (IN_C * IN_C);
    const float* ba  = b1 + bb * IN_C;
    const float* bb2 = b2 + bb * IN_C;

    float vdx = v_dna[dsafe * 3 + 0], vdy = v_dna[dsafe * 3 + 1], vdz = v_dna[dsafe * 3 + 2];
    float nix = dna_vec[dsafe * 3 + 0], niy = dna_vec[dsafe * 3 + 1], niz = dna_vec[dsafe * 3 + 2];

    // h1b = b1 + W1[rows 36..67] . x_dna[dst]   (hoisted; scalar weights)
    float h1b[IN_C];
    #pragma unroll
    for (int c = 0; c < IN_C; ++c) h1b[c] = ba[c];
    {
        const float4* xd = reinterpret_cast<const float4*>(x_dna + (size_t)dsafe * IN_C);
        #pragma unroll
        for (int kk = 0; kk < 8; ++kk) {
            float4 xv = xd[kk];
            float fs[4] = {xv.x, xv.y, xv.z, xv.w};
            #pragma unroll
            for (int j = 0; j < 4; ++j)
                #pragma unroll
                for (int c = 0; c < IN_C; ++c)
                    h1b[c] = fmaf(fs[j], Wa[(36 + kk * 4 + j) * IN_C + c], h1b[c]);
        }
    }

    float acc[IN_C];
    #pragma unroll
    for (int c = 0; c < IN_C; ++c) acc[c] = 0.0f;

    for (int k = 0; k < n; ++k) {
        int src = pool_src[start + k];

        float vpx = v_prot[src * 3 + 0], vpy = v_prot[src * 3 + 1], vpz = v_prot[src * 3 + 2];
        float njx = prot_vec[src * 3 + 0], njy = prot_vec[src * 3 + 1], njz = prot_vec[src * 3 + 2];
        float dx = vpx - vdx, dy = vpy - vdy, dz = vpz - vdz;
        float pf[4];
        pf[0] = sqrtf(dx * dx + dy * dy + dz * dz);
        pf[1] = angf(nix, niy, niz, dx, dy, dz);
        pf[2] = angf(njx, njy, njz, dx, dy, dz);
        pf[3] = angf(nix, niy, niz, njx, njy, njz);

        float h2[IN_C];
        #pragma unroll
        for (int c = 0; c < IN_C; ++c) h2[c] = bb2[c];

        // h1 in two 16-channel halves; each half consumed into h2 immediately.
        // k-accumulation order into h2 is 0..31, identical to R5 -> same FP.
        const float4* xp = reinterpret_cast<const float4*>(x_prot + (size_t)src * IN_C);
        #pragma unroll
        for (int hh = 0; hh < 2; ++hh) {
            float h1h[16];
            #pragma unroll
            for (int c = 0; c < 16; ++c) h1h[c] = h1b[hh * 16 + c];

            #pragma unroll
            for (int kk = 0; kk < 8; ++kk) {
                float4 xv = xp[kk];
                float fs[4] = {xv.x, xv.y, xv.z, xv.w};
                #pragma unroll
                for (int j = 0; j < 4; ++j)
                    #pragma unroll
                    for (int c = 0; c < 16; ++c)
                        h1h[c] = fmaf(fs[j], Wa[(kk * 4 + j) * IN_C + hh * 16 + c], h1h[c]);
            }
            #pragma unroll
            for (int j = 0; j < 4; ++j)
                #pragma unroll
                for (int c = 0; c < 16; ++c)
                    h1h[c] = fmaf(pf[j], Wa[(32 + j) * IN_C + hh * 16 + c], h1h[c]);

            #pragma unroll
            for (int k2 = 0; k2 < 16; ++k2) {
                float f = fmaxf(h1h[k2], 0.0f);
                #pragma unroll
                for (int c = 0; c < IN_C; ++c)
                    h2[c] = fmaf(f, Wb[(hh * 16 + k2) * IN_C + c], h2[c]);
            }
        }

        #pragma unroll
        for (int c = 0; c < IN_C; ++c)
            acc[c] += fmaxf(h2[c], 0.0f);
    }

    // pair reduce: lanes (2i, 2i+1) hold the two halves of node pid
    #pragma unroll
    for (int c = 0; c < IN_C; ++c)
        acc[c] += __shfl_xor(acc[c], 1, 64);

    if (valid) {
        // out == conv (messages >= 0 -> relu(agg) == agg)
        float* p = (half ? conv : out) + (size_t)dst * IN_C;
        float4* p4 = reinterpret_cast<float4*>(p);
        #pragma unroll
        for (int qq = 0; qq < 8; ++qq) {
            float4 v;
            v.x = acc[qq * 4 + 0]; v.y = acc[qq * 4 + 1];
            v.z = acc[qq * 4 + 2]; v.w = acc[qq * 4 + 3];
            p4[qq] = v;
        }
    }
}

// --- fallback (ws too small): per-edge atomics -------------------------------
__global__ __launch_bounds__(256) void k_edges_fallback(
    const float* __restrict__ x_dna, const float* __restrict__ v_dna,
    const float* __restrict__ x_prot, const float* __restrict__ v_prot,
    const float* __restrict__ prot_vec, const float* __restrict__ dna_vec,
    const int* __restrict__ esrc, const int* __restrict__ edst,
    const float* __restrict__ W1, const float* __restrict__ b1,
    const float* __restrict__ W2, const float* __restrict__ b2,
    int E, float* __restrict__ conv)
{
    int t = blockIdx.x * blockDim.x + threadIdx.x;
    if (t >= E) return;
    int src = esrc[t], dst = edst[t];
    int b = branch_of(dst % 11);
    const float* Wa  = W1 + b * (IN_F * IN_C);
    const float* Wb  = W2 + b * (IN_C * IN_C);
    const float* ba  = b1 + b * IN_C;
    const float* bb2 = b2 + b * IN_C;

    float vdx = v_dna[dst * 3 + 0], vdy = v_dna[dst * 3 + 1], vdz = v_dna[dst * 3 + 2];
    float vpx = v_prot[src * 3 + 0], vpy = v_prot[src * 3 + 1], vpz = v_prot[src * 3 + 2];
    float nix = dna_vec[dst * 3 + 0], niy = dna_vec[dst * 3 + 1], niz = dna_vec[dst * 3 + 2];
    float njx = prot_vec[src * 3 + 0], njy = prot_vec[src * 3 + 1], njz = prot_vec[src * 3 + 2];
    float dx = vpx - vdx, dy = vpy - vdy, dz = vpz - vdz;
    float pf[4];
    pf[0] = sqrtf(dx * dx + dy * dy + dz * dz);
    pf[1] = angf(nix, niy, niz, dx, dy, dz);
    pf[2] = angf(njx, njy, njz, dx, dy, dz);
    pf[3] = angf(nix, niy, niz, njx, njy, njz);

    float h1[IN_C];
    #pragma unroll
    for (int c = 0; c < IN_C; ++c) h1[c] = ba[c];
    const float4* xp = reinterpret_cast<const float4*>(x_prot + (size_t)src * IN_C);
    #pragma unroll
    for (int kk = 0; kk < 8; ++kk) {
        float4 xv = xp[kk];
        float fs[4] = {xv.x, xv.y, xv.z, xv.w};
        #pragma unroll
        for (int j = 0; j < 4; ++j)
            #pragma unroll
            for (int c = 0; c < IN_C; ++c)
                h1[c] = fmaf(fs[j], Wa[(kk * 4 + j) * IN_C + c], h1[c]);
    }
    #pragma unroll
    for (int j = 0; j < 4; ++j)
        #pragma unroll
        for (int c = 0; c < IN_C; ++c)
            h1[c] = fmaf(pf[j], Wa[(32 + j) * IN_C + c], h1[c]);
    const float4* xd = reinterpret_cast<const float4*>(x_dna + (size_t)dst * IN_C);
    #pragma unroll
    for (int kk = 0; kk < 8; ++kk) {
        float4 xv = xd[kk];
        float fs[4] = {xv.x, xv.y, xv.z, xv.w};
        #pragma unroll
        for (int j = 0; j < 4; ++j)
            #pragma unroll
            for (int c = 0; c < IN_C; ++c)
                h1[c] = fmaf(fs[j], Wa[(36 + kk * 4 + j) * IN_C + c], h1[c]);
    }
    float h2[IN_C];
    #pragma unroll
    for (int c = 0; c < IN_C; ++c) h2[c] = bb2[c];
    #pragma unroll
    for (int k = 0; k < IN_C; ++k) {
        float f = fmaxf(h1[k], 0.0f);
        #pragma unroll
        for (int c = 0; c < IN_C; ++c)
            h2[c] = fmaf(f, Wb[k * IN_C + c], h2[c]);
    }
    float* cv = conv + (size_t)dst * IN_C;
    #pragma unroll
    for (int c = 0; c < IN_C; ++c)
        atomicAdd(&cv[c], fmaxf(h2[c], 0.0f));
}

extern "C" void kernel_launch(void* const* d_in, const int* in_sizes, int n_in,
                              void* d_out, int out_size, void* d_ws, size_t ws_size,
                              hipStream_t stream) {
    const float* x_dna    = (const float*)d_in[0];
    const float* v_dna    = (const float*)d_in[1];
    const float* x_prot   = (const float*)d_in[2];
    const float* v_prot   = (const float*)d_in[3];
    const float* prot_vec = (const float*)d_in[4];
    const float* dna_vec  = (const float*)d_in[5];
    const int*   esrc     = (const int*)d_in[6];
    const int*   edst     = (const int*)d_in[7];
    const float* W1       = (const float*)d_in[8];
    const float* b1       = (const float*)d_in[9];
    const float* W2       = (const float*)d_in[10];
    const float* b2       = (const float*)d_in[11];

    const int E  = in_sizes[6];
    const int ND = in_sizes[0] / IN_C;       // N_DNA
    const int half = out_size / 2;
    float* out  = (float*)d_out;
    float* conv = out + half;

    const int NDp = ND + 128;                // padded node_order length
    const int nblk_scan = (ND + 1023) / 1024;
    const size_t ws_need = ((size_t)2 * ND + NDp + 256 + 8 + 256 + E) * sizeof(int);
    const int eb = (E + 255) / 256;

    if (ND == half / IN_C && ws_size >= ws_need && nblk_scan <= 256) {
        int* counts     = (int*)d_ws;          // ND
        int* rowcur     = counts + ND;         // ND (scan -> fill cursor -> row end)
        int* node_order = rowcur + ND;         // NDp
        int* blk        = node_order + NDp;    // 256
        int* hist       = blk + 256;           // 256 (bin counts -> bin cursors)
        int* pbs        = hist + 256;          // 8  (padded group bases)
        int* pool_src   = pbs + 8;             // E

        hipMemsetAsync(counts, 0, (size_t)ND * sizeof(int), stream);
        hipMemsetAsync(node_order, 0xFF, (size_t)NDp * sizeof(int), stream);
        hipMemsetAsync(hist, 0, 256 * sizeof(int), stream);

        k_count<<<eb, 256, 0, stream>>>(edst, E, counts);
        k_scan1<<<nblk_scan, 1024, 0, stream>>>(counts, ND, rowcur, blk);
        k_scan2<<<1, 256, 0, stream>>>(blk, nblk_scan);
        k_scan3<<<nblk_scan, 1024, 0, stream>>>(rowcur, blk, ND);
        k_fill<<<eb, 256, 0, stream>>>(esrc, edst, E, rowcur, pool_src);

        k_hist<<<128, 256, 0, stream>>>(counts, ND, hist);
        k_padscan2<<<1, 256, 0, stream>>>(hist, pbs);
        k_assign<<<(ND + 255) / 256, 256, 0, stream>>>(counts, ND, hist, node_order);

        int nb2 = (2 * NDp + 255) / 256;
        k_nodes2<<<nb2, 256, 0, stream>>>(
            x_dna, v_dna, x_prot, v_prot, prot_vec, dna_vec,
            W1, b1, W2, b2, node_order, rowcur, counts, pool_src, pbs,
            out, conv, NDp);
        // every node stored exactly once -> no memset/copy of out/conv
    } else {
        hipMemsetAsync(conv, 0, (size_t)half * sizeof(float), stream);
        k_edges_fallback<<<eb, 256, 0, stream>>>(
            x_dna, v_dna, x_prot, v_prot, prot_vec, dna_vec,
            esrc, edst, W1, b1, W2, b2, E, conv);
        hipMemcpyAsync(out, conv, (size_t)half * sizeof(float),
                       hipMemcpyDeviceToDevice, stream);
    }
}

// Round 7
// 491.081 us; speedup vs baseline: 12.2208x; 1.1999x over previous
//
#include <hip/hip_runtime.h>

// ---------------------------------------------------------------------------
// BiNet R7: factor the per-edge MLP.
//   h1 = b1 + W1a.x_prot[src] + W1p.ppf + W1c.x_dna[dst]
//   * yp[g][src] = W1a.x_prot[src]  precomputed ONCE (bf16, 30.7MB in ws,
//     runtime-gated on ws_size; fallback = exact R6 path).
//   * per-edge: load yp (64B) instead of 1024 FMA + 4.3KB weight stream.
//   * manual software pipeline: prefetch next src/v_prot/prot_vec.
//   * keep: (branch,count)-sorted nodes, 2 lanes/node, h1b dst-hoist,
//     16-ch half-split, shfl_xor pair reduce, atomic-free stores.
// ---------------------------------------------------------------------------

#define IN_C 32
#define IN_F 68

__device__ __forceinline__ float angf(float ax, float ay, float az,
                                      float bx, float by, float bz) {
    float cx = ay * bz - az * by;
    float cy = az * bx - ax * bz;
    float cz = ax * by - ay * bx;
    float cn = sqrtf(cx * cx + cy * cy + cz * cz);
    float dt = ax * bx + ay * by + az * bz;
    return atan2f(cn, dt);
}

__device__ __forceinline__ int branch_of(int m) {
    if (m == 0 || m == 10) return 0;
    if (m == 1 || m == 9)  return 1;
    if (m >= 2 && m <= 5)  return 2;
    return 3;
}

__device__ __forceinline__ unsigned bf16r(float f) {
    unsigned u = __float_as_uint(f);
    return (u + 0x7fffu + ((u >> 16) & 1u)) >> 16;
}

// --- CSR build (keyed by raw dst) --------------------------------------------
__global__ void k_count(const int* __restrict__ edst, int E, int* counts) {
    int t = blockIdx.x * blockDim.x + threadIdx.x;
    if (t >= E) return;
    atomicAdd(&counts[edst[t]], 1);
}

__global__ __launch_bounds__(1024) void k_scan1(const int* __restrict__ counts,
                                                int NN, int* cursor, int* blk) {
    __shared__ int wsum[16];
    int t = blockIdx.x * 1024 + threadIdx.x;
    int lane = threadIdx.x & 63;
    int wid = threadIdx.x >> 6;
    int c = (t < NN) ? counts[t] : 0;
    int inc = c;
    #pragma unroll
    for (int d = 1; d < 64; d <<= 1) {
        int v = __shfl_up(inc, d, 64);
        if (lane >= d) inc += v;
    }
    if (lane == 63) wsum[wid] = inc;
    __syncthreads();
    if (threadIdx.x < 16) {
        int v = wsum[threadIdx.x];
        int wi = v;
        #pragma unroll
        for (int d = 1; d < 16; d <<= 1) {
            int u = __shfl_up(wi, d, 64);
            if (threadIdx.x >= d) wi += u;
        }
        wsum[threadIdx.x] = wi - v;
        if (threadIdx.x == 15) blk[blockIdx.x] = wi;
    }
    __syncthreads();
    if (t < NN) cursor[t] = inc - c + wsum[wid];
}

__global__ __launch_bounds__(256) void k_scan2(int* blk, int nblk) {
    __shared__ int wsum[4];
    int lane = threadIdx.x & 63;
    int wid = threadIdx.x >> 6;
    int v = (threadIdx.x < nblk) ? blk[threadIdx.x] : 0;
    int inc = v;
    #pragma unroll
    for (int d = 1; d < 64; d <<= 1) {
        int u = __shfl_up(inc, d, 64);
        if (lane >= d) inc += u;
    }
    if (lane == 63) wsum[wid] = inc;
    __syncthreads();
    if (threadIdx.x < 4) {
        int w = wsum[threadIdx.x];
        int wi = w;
        #pragma unroll
        for (int d = 1; d < 4; d <<= 1) {
            int u = __shfl_up(wi, d, 64);
            if (threadIdx.x >= d) wi += u;
        }
        wsum[threadIdx.x] = wi - w;
    }
    __syncthreads();
    if (threadIdx.x < nblk) blk[threadIdx.x] = inc - v + wsum[wid];
}

__global__ __launch_bounds__(1024) void k_scan3(int* cursor, const int* blk, int NN) {
    int t = blockIdx.x * 1024 + threadIdx.x;
    if (t >= NN) return;
    cursor[t] += blk[blockIdx.x];
}

__global__ void k_fill(const int* __restrict__ esrc, const int* __restrict__ edst,
                       int E, int* cursor, int* __restrict__ pool_src) {
    int t = blockIdx.x * blockDim.x + threadIdx.x;
    if (t >= E) return;
    int pos = atomicAdd(&cursor[edst[t]], 1);
    pool_src[pos] = esrc[t];
}

// --- (branch, count) histogram ------------------------------------------------
__global__ __launch_bounds__(256) void k_hist(const int* __restrict__ counts,
                                              int ND, int* hist) {
    __shared__ int lh[256];
    lh[threadIdx.x] = 0;
    __syncthreads();
    for (int t = blockIdx.x * 256 + threadIdx.x; t < ND; t += gridDim.x * 256) {
        int g = branch_of(t % 11);
        int c = counts[t]; c = c > 63 ? 63 : c;
        atomicAdd(&lh[g * 64 + c], 1);
    }
    __syncthreads();
    if (lh[threadIdx.x]) atomicAdd(&hist[threadIdx.x], lh[threadIdx.x]);
}

__global__ __launch_bounds__(256) void k_padscan2(int* hist, int* pbs) {
    __shared__ int gsum[4];
    __shared__ int gbase[5];
    int lane = threadIdx.x & 63;
    int w = threadIdx.x >> 6;
    int v = hist[threadIdx.x];
    int inc = v;
    #pragma unroll
    for (int d = 1; d < 64; d <<= 1) {
        int u = __shfl_up(inc, d, 64);
        if (lane >= d) inc += u;
    }
    if (lane == 63) gsum[w] = inc;
    __syncthreads();
    if (threadIdx.x == 0) {
        int base = 0;
        #pragma unroll
        for (int g = 0; g < 4; ++g) {
            gbase[g] = base;
            base = (base + gsum[g] + 31) & ~31;
        }
        gbase[4] = base;
    }
    __syncthreads();
    hist[threadIdx.x] = gbase[w] + inc - v;
    if (threadIdx.x < 5) pbs[threadIdx.x] = gbase[threadIdx.x];
}

__global__ __launch_bounds__(256) void k_assign(const int* __restrict__ counts,
                                                int ND, int* cur,
                                                int* __restrict__ node_order) {
    __shared__ int lh[256];
    __shared__ int lbase[256];
    lh[threadIdx.x] = 0;
    __syncthreads();
    int t = blockIdx.x * 256 + threadIdx.x;
    bool v = (t < ND);
    int bin = 0, rank = 0;
    if (v) {
        int g = branch_of(t % 11);
        int c = counts[t]; c = c > 63 ? 63 : c;
        bin = g * 64 + c;
        rank = atomicAdd(&lh[bin], 1);
    }
    __syncthreads();
    int cnt = lh[threadIdx.x];
    if (cnt > 0) lbase[threadIdx.x] = atomicAdd(&cur[threadIdx.x], cnt);
    __syncthreads();
    if (v) node_order[lbase[bin] + rank] = t;
}

// --- yp precompute: yp[g][p][c] = sum_k x_prot[p][k] * W1[g][k][c], bf16 ------
__global__ __launch_bounds__(256) void k_prot(
    const float* __restrict__ x_prot, const float* __restrict__ W1,
    int NP, int NPpad, unsigned short* __restrict__ yp)
{
    int t = blockIdx.x * 256 + threadIdx.x;
    int g = t / NPpad;                 // wave-uniform (NPpad % 64 == 0)
    int p = t - g * NPpad;
    if (g > 3 || p >= NP) return;
    int bb = __builtin_amdgcn_readfirstlane(g);
    const float* Wa = W1 + bb * (IN_F * IN_C);

    float h[IN_C];
    #pragma unroll
    for (int c = 0; c < IN_C; ++c) h[c] = 0.0f;
    const float4* xp = reinterpret_cast<const float4*>(x_prot + (size_t)p * IN_C);
    #pragma unroll
    for (int kk = 0; kk < 8; ++kk) {
        float4 xv = xp[kk];
        float fs[4] = {xv.x, xv.y, xv.z, xv.w};
        #pragma unroll
        for (int j = 0; j < 4; ++j)
            #pragma unroll
            for (int c = 0; c < IN_C; ++c)
                h[c] = fmaf(fs[j], Wa[(kk * 4 + j) * IN_C + c], h[c]);
    }

    unsigned yw[16];
    #pragma unroll
    for (int j = 0; j < 16; ++j)
        yw[j] = bf16r(h[2 * j]) | (bf16r(h[2 * j + 1]) << 16);

    uint4* dst = reinterpret_cast<uint4*>(yp + ((size_t)bb * NP + p) * IN_C);
    dst[0] = make_uint4(yw[0], yw[1], yw[2], yw[3]);
    dst[1] = make_uint4(yw[4], yw[5], yw[6], yw[7]);
    dst[2] = make_uint4(yw[8], yw[9], yw[10], yw[11]);
    dst[3] = make_uint4(yw[12], yw[13], yw[14], yw[15]);
}

// --- main kernel: 2 lanes/node, branch wave-uniform ---------------------------
template <bool USE_YP>
__global__ __launch_bounds__(256) void k_nodes2(
    const float* __restrict__ x_dna, const float* __restrict__ v_dna,
    const float* __restrict__ x_prot, const float* __restrict__ v_prot,
    const float* __restrict__ prot_vec, const float* __restrict__ dna_vec,
    const float* __restrict__ W1, const float* __restrict__ b1,
    const float* __restrict__ W2, const float* __restrict__ b2,
    const int* __restrict__ node_order, const int* __restrict__ rowend,
    const int* __restrict__ counts, const int* __restrict__ pool_src,
    const int* __restrict__ pbs, const unsigned short* __restrict__ yp, int NP,
    float* __restrict__ out, float* __restrict__ conv, int NDp)
{
    int t = blockIdx.x * 256 + threadIdx.x;
    int pid = t >> 1;
    int half = t & 1;
    if (pid >= NDp) return;

    int pb1 = pbs[1], pb2 = pbs[2], pb3 = pbs[3];
    int g = (pid >= pb1) + (pid >= pb2) + (pid >= pb3);
    int bb = __builtin_amdgcn_readfirstlane(g);

    int dst = node_order[pid];
    bool valid = (dst >= 0);
    int dsafe = valid ? dst : 0;

    int n_all = valid ? counts[dsafe] : 0;
    int start_all = valid ? (rowend[dsafe] - n_all) : 0;
    int n0 = (n_all + 1) >> 1;
    int n = half ? (n_all - n0) : n0;
    int start = half ? (start_all + n0) : start_all;

    const float* Wa  = W1 + bb * (IN_F * IN_C);
    const float* Wb  = W2 + bb * (IN_C * IN_C);
    const float* ba  = b1 + bb * IN_C;
    const float* bb2 = b2 + bb * IN_C;

    float vdx = v_dna[dsafe * 3 + 0], vdy = v_dna[dsafe * 3 + 1], vdz = v_dna[dsafe * 3 + 2];
    float nix = dna_vec[dsafe * 3 + 0], niy = dna_vec[dsafe * 3 + 1], niz = dna_vec[dsafe * 3 + 2];

    // h1b = b1 + W1[rows 36..67] . x_dna[dst]
    float h1b[IN_C];
    #pragma unroll
    for (int c = 0; c < IN_C; ++c) h1b[c] = ba[c];
    {
        const float4* xd = reinterpret_cast<const float4*>(x_dna + (size_t)dsafe * IN_C);
        #pragma unroll
        for (int kk = 0; kk < 8; ++kk) {
            float4 xv = xd[kk];
            float fs[4] = {xv.x, xv.y, xv.z, xv.w};
            #pragma unroll
            for (int j = 0; j < 4; ++j)
                #pragma unroll
                for (int c = 0; c < IN_C; ++c)
                    h1b[c] = fmaf(fs[j], Wa[(36 + kk * 4 + j) * IN_C + c], h1b[c]);
        }
    }

    float acc[IN_C];
    #pragma unroll
    for (int c = 0; c < IN_C; ++c) acc[c] = 0.0f;

    if (USE_YP) {
        // software-pipelined edge loop: prefetch next src + geometry vectors
        int src_c = 0;
        float vpx_c = 0, vpy_c = 0, vpz_c = 0, njx_c = 0, njy_c = 0, njz_c = 0;
        if (n > 0) {
            src_c = pool_src[start];
            vpx_c = v_prot[src_c * 3 + 0]; vpy_c = v_prot[src_c * 3 + 1]; vpz_c = v_prot[src_c * 3 + 2];
            njx_c = prot_vec[src_c * 3 + 0]; njy_c = prot_vec[src_c * 3 + 1]; njz_c = prot_vec[src_c * 3 + 2];
        }
        for (int k = 0; k < n; ++k) {
            // issue yp load for current edge early
            const uint4* ypv = reinterpret_cast<const uint4*>(
                yp + ((size_t)bb * NP + src_c) * IN_C);
            uint4 y0 = ypv[0], y1 = ypv[1], y2 = ypv[2], y3 = ypv[3];

            // prefetch next edge
            int kn = (k + 1 < n) ? (k + 1) : k;
            int src_n = pool_src[start + kn];
            float vpx_n = v_prot[src_n * 3 + 0], vpy_n = v_prot[src_n * 3 + 1], vpz_n = v_prot[src_n * 3 + 2];
            float njx_n = prot_vec[src_n * 3 + 0], njy_n = prot_vec[src_n * 3 + 1], njz_n = prot_vec[src_n * 3 + 2];

            // geometry (hides yp latency)
            float dx = vpx_c - vdx, dy = vpy_c - vdy, dz = vpz_c - vdz;
            float pf[4];
            pf[0] = sqrtf(dx * dx + dy * dy + dz * dz);
            pf[1] = angf(nix, niy, niz, dx, dy, dz);
            pf[2] = angf(njx_c, njy_c, njz_c, dx, dy, dz);
            pf[3] = angf(nix, niy, niz, njx_c, njy_c, njz_c);

            unsigned yw[16];
            *reinterpret_cast<uint4*>(&yw[0])  = y0;
            *reinterpret_cast<uint4*>(&yw[4])  = y1;
            *reinterpret_cast<uint4*>(&yw[8])  = y2;
            *reinterpret_cast<uint4*>(&yw[12]) = y3;

            float h2[IN_C];
            #pragma unroll
            for (int c = 0; c < IN_C; ++c) h2[c] = bb2[c];

            #pragma unroll
            for (int hh = 0; hh < 2; ++hh) {
                float h1h[16];
                #pragma unroll
                for (int j = 0; j < 8; ++j) {
                    unsigned w = yw[hh * 8 + j];
                    h1h[2 * j]     = h1b[hh * 16 + 2 * j]     + __uint_as_float(w << 16);
                    h1h[2 * j + 1] = h1b[hh * 16 + 2 * j + 1] + __uint_as_float(w & 0xffff0000u);
                }
                #pragma unroll
                for (int j = 0; j < 4; ++j)
                    #pragma unroll
                    for (int c = 0; c < 16; ++c)
                        h1h[c] = fmaf(pf[j], Wa[(32 + j) * IN_C + hh * 16 + c], h1h[c]);

                #pragma unroll
                for (int k2 = 0; k2 < 16; ++k2) {
                    float f = fmaxf(h1h[k2], 0.0f);
                    #pragma unroll
                    for (int c = 0; c < IN_C; ++c)
                        h2[c] = fmaf(f, Wb[(hh * 16 + k2) * IN_C + c], h2[c]);
                }
            }

            #pragma unroll
            for (int c = 0; c < IN_C; ++c)
                acc[c] += fmaxf(h2[c], 0.0f);

            src_c = src_n;
            vpx_c = vpx_n; vpy_c = vpy_n; vpz_c = vpz_n;
            njx_c = njx_n; njy_c = njy_n; njz_c = njz_n;
        }
    } else {
        for (int k = 0; k < n; ++k) {
            int src = pool_src[start + k];

            float vpx = v_prot[src * 3 + 0], vpy = v_prot[src * 3 + 1], vpz = v_prot[src * 3 + 2];
            float njx = prot_vec[src * 3 + 0], njy = prot_vec[src * 3 + 1], njz = prot_vec[src * 3 + 2];
            float dx = vpx - vdx, dy = vpy - vdy, dz = vpz - vdz;
            float pf[4];
            pf[0] = sqrtf(dx * dx + dy * dy + dz * dz);
            pf[1] = angf(nix, niy, niz, dx, dy, dz);
            pf[2] = angf(njx, njy, njz, dx, dy, dz);
            pf[3] = angf(nix, niy, niz, njx, njy, njz);

            float h2[IN_C];
            #pragma unroll
            for (int c = 0; c < IN_C; ++c) h2[c] = bb2[c];

            const float4* xp = reinterpret_cast<const float4*>(x_prot + (size_t)src * IN_C);
            #pragma unroll
            for (int hh = 0; hh < 2; ++hh) {
                float h1h[16];
                #pragma unroll
                for (int c = 0; c < 16; ++c) h1h[c] = h1b[hh * 16 + c];

                #pragma unroll
                for (int kk = 0; kk < 8; ++kk) {
                    float4 xv = xp[kk];
                    float fs[4] = {xv.x, xv.y, xv.z, xv.w};
                    #pragma unroll
                    for (int j = 0; j < 4; ++j)
                        #pragma unroll
                        for (int c = 0; c < 16; ++c)
                            h1h[c] = fmaf(fs[j], Wa[(kk * 4 + j) * IN_C + hh * 16 + c], h1h[c]);
                }
                #pragma unroll
                for (int j = 0; j < 4; ++j)
                    #pragma unroll
                    for (int c = 0; c < 16; ++c)
                        h1h[c] = fmaf(pf[j], Wa[(32 + j) * IN_C + hh * 16 + c], h1h[c]);

                #pragma unroll
                for (int k2 = 0; k2 < 16; ++k2) {
                    float f = fmaxf(h1h[k2], 0.0f);
                    #pragma unroll
                    for (int c = 0; c < IN_C; ++c)
                        h2[c] = fmaf(f, Wb[(hh * 16 + k2) * IN_C + c], h2[c]);
                }
            }

            #pragma unroll
            for (int c = 0; c < IN_C; ++c)
                acc[c] += fmaxf(h2[c], 0.0f);
        }
    }

    #pragma unroll
    for (int c = 0; c < IN_C; ++c)
        acc[c] += __shfl_xor(acc[c], 1, 64);

    if (valid) {
        float* p = (half ? conv : out) + (size_t)dst * IN_C;
        float4* p4 = reinterpret_cast<float4*>(p);
        #pragma unroll
        for (int qq = 0; qq < 8; ++qq) {
            float4 v;
            v.x = acc[qq * 4 + 0]; v.y = acc[qq * 4 + 1];
            v.z = acc[qq * 4 + 2]; v.w = acc[qq * 4 + 3];
            p4[qq] = v;
        }
    }
}

// --- fallback (ws too small): per-edge atomics -------------------------------
__global__ __launch_bounds__(256) void k_edges_fallback(
    const float* __restrict__ x_dna, const float* __restrict__ v_dna,
    const float* __restrict__ x_prot, const float* __restrict__ v_prot,
    const float* __restrict__ prot_vec, const float* __restrict__ dna_vec,
    const int* __restrict__ esrc, const int* __restrict__ edst,
    const float* __restrict__ W1, const float* __restrict__ b1,
    const float* __restrict__ W2, const float* __restrict__ b2,
    int E, float* __restrict__ conv)
{
    int t = blockIdx.x * blockDim.x + threadIdx.x;
    if (t >= E) return;
    int src = esrc[t], dst = edst[t];
    int b = branch_of(dst % 11);
    const float* Wa  = W1 + b * (IN_F * IN_C);
    const float* Wb  = W2 + b * (IN_C * IN_C);
    const float* ba  = b1 + b * IN_C;
    const float* bb2 = b2 + b * IN_C;

    float vdx = v_dna[dst * 3 + 0], vdy = v_dna[dst * 3 + 1], vdz = v_dna[dst * 3 + 2];
    float vpx = v_prot[src * 3 + 0], vpy = v_prot[src * 3 + 1], vpz = v_prot[src * 3 + 2];
    float nix = dna_vec[dst * 3 + 0], niy = dna_vec[dst * 3 + 1], niz = dna_vec[dst * 3 + 2];
    float njx = prot_vec[src * 3 + 0], njy = prot_vec[src * 3 + 1], njz = prot_vec[src * 3 + 2];
    float dx = vpx - vdx, dy = vpy - vdy, dz = vpz - vdz;
    float pf[4];
    pf[0] = sqrtf(dx * dx + dy * dy + dz * dz);
    pf[1] = angf(nix, niy, niz, dx, dy, dz);
    pf[2] = angf(njx, njy, njz, dx, dy, dz);
    pf[3] = angf(nix, niy, niz, njx, njy, njz);

    float h1[IN_C];
    #pragma unroll
    for (int c = 0; c < IN_C; ++c) h1[c] = ba[c];
    const float4* xp = reinterpret_cast<const float4*>(x_prot + (size_t)src * IN_C);
    #pragma unroll
    for (int kk = 0; kk < 8; ++kk) {
        float4 xv = xp[kk];
        float fs[4] = {xv.x, xv.y, xv.z, xv.w};
        #pragma unroll
        for (int j = 0; j < 4; ++j)
            #pragma unroll
            for (int c = 0; c < IN_C; ++c)
                h1[c] = fmaf(fs[j], Wa[(kk * 4 + j) * IN_C + c], h1[c]);
    }
    #pragma unroll
    for (int j = 0; j < 4; ++j)
        #pragma unroll
        for (int c = 0; c < IN_C; ++c)
            h1[c] = fmaf(pf[j], Wa[(32 + j) * IN_C + c], h1[c]);
    const float4* xd = reinterpret_cast<const float4*>(x_dna + (size_t)dst * IN_C);
    #pragma unroll
    for (int kk = 0; kk < 8; ++kk) {
        float4 xv = xd[kk];
        float fs[4] = {xv.x, xv.y, xv.z, xv.w};
        #pragma unroll
        for (int j = 0; j < 4; ++j)
            #pragma unroll
            for (int c = 0; c < IN_C; ++c)
                h1[c] = fmaf(fs[j], Wa[(36 + kk * 4 + j) * IN_C + c], h1[c]);
    }
    float h2[IN_C];
    #pragma unroll
    for (int c = 0; c < IN_C; ++c) h2[c] = bb2[c];
    #pragma unroll
    for (int k = 0; k < IN_C; ++k) {
        float f = fmaxf(h1[k], 0.0f);
        #pragma unroll
        for (int c = 0; c < IN_C; ++c)
            h2[c] = fmaf(f, Wb[k * IN_C + c], h2[c]);
    }
    float* cv = conv + (size_t)dst * IN_C;
    #pragma unroll
    for (int c = 0; c < IN_C; ++c)
        atomicAdd(&cv[c], fmaxf(h2[c], 0.0f));
}

extern "C" void kernel_launch(void* const* d_in, const int* in_sizes, int n_in,
                              void* d_out, int out_size, void* d_ws, size_t ws_size,
                              hipStream_t stream) {
    const float* x_dna    = (const float*)d_in[0];
    const float* v_dna    = (const float*)d_in[1];
    const float* x_prot   = (const float*)d_in[2];
    const float* v_prot   = (const float*)d_in[3];
    const float* prot_vec = (const float*)d_in[4];
    const float* dna_vec  = (const float*)d_in[5];
    const int*   esrc     = (const int*)d_in[6];
    const int*   edst     = (const int*)d_in[7];
    const float* W1       = (const float*)d_in[8];
    const float* b1       = (const float*)d_in[9];
    const float* W2       = (const float*)d_in[10];
    const float* b2       = (const float*)d_in[11];

    const int E  = in_sizes[6];
    const int ND = in_sizes[0] / IN_C;       // N_DNA
    const int NP = in_sizes[2] / IN_C;       // N_PROT
    const int half = out_size / 2;
    float* out  = (float*)d_out;
    float* conv = out + half;

    const int NDp = ND + 128;
    const int nblk_scan = (ND + 1023) / 1024;
    const size_t base_ints = (size_t)2 * ND + NDp + 256 + 256 + 8 + E;
    const size_t ws_need = base_ints * sizeof(int);
    const size_t yp_off  = (ws_need + 255) & ~(size_t)255;          // 256B aligned
    const size_t yp_bytes = (size_t)NP * 4 * IN_C * sizeof(unsigned short);
    const size_t ws_need_yp = yp_off + yp_bytes;
    const int eb = (E + 255) / 256;

    if (ND == half / IN_C && ws_size >= ws_need && nblk_scan <= 256) {
        int* counts     = (int*)d_ws;          // ND
        int* rowcur     = counts + ND;         // ND
        int* node_order = rowcur + ND;         // NDp
        int* blk        = node_order + NDp;    // 256
        int* hist       = blk + 256;           // 256
        int* pbs        = hist + 256;          // 8
        int* pool_src   = pbs + 8;             // E
        unsigned short* yp = (unsigned short*)((char*)d_ws + yp_off);
        const bool use_yp = (ws_size >= ws_need_yp);

        hipMemsetAsync(counts, 0, (size_t)ND * sizeof(int), stream);
        hipMemsetAsync(node_order, 0xFF, (size_t)NDp * sizeof(int), stream);
        hipMemsetAsync(hist, 0, 256 * sizeof(int), stream);

        k_count<<<eb, 256, 0, stream>>>(edst, E, counts);
        k_scan1<<<nblk_scan, 1024, 0, stream>>>(counts, ND, rowcur, blk);
        k_scan2<<<1, 256, 0, stream>>>(blk, nblk_scan);
        k_scan3<<<nblk_scan, 1024, 0, stream>>>(rowcur, blk, ND);
        k_fill<<<eb, 256, 0, stream>>>(esrc, edst, E, rowcur, pool_src);

        k_hist<<<128, 256, 0, stream>>>(counts, ND, hist);
        k_padscan2<<<1, 256, 0, stream>>>(hist, pbs);
        k_assign<<<(ND + 255) / 256, 256, 0, stream>>>(counts, ND, hist, node_order);

        int nb2 = (2 * NDp + 255) / 256;
        if (use_yp) {
            int NPpad = (NP + 63) & ~63;
            int pbks = (4 * NPpad) / 256;
            k_prot<<<pbks, 256, 0, stream>>>(x_prot, W1, NP, NPpad, yp);
            k_nodes2<true><<<nb2, 256, 0, stream>>>(
                x_dna, v_dna, x_prot, v_prot, prot_vec, dna_vec,
                W1, b1, W2, b2, node_order, rowcur, counts, pool_src, pbs,
                yp, NP, out, conv, NDp);
        } else {
            k_nodes2<false><<<nb2, 256, 0, stream>>>(
                x_dna, v_dna, x_prot, v_prot, prot_vec, dna_vec,
                W1, b1, W2, b2, node_order, rowcur, counts, pool_src, pbs,
                nullptr, NP, out, conv, NDp);
        }
    } else {
        hipMemsetAsync(conv, 0, (size_t)half * sizeof(float), stream);
        k_edges_fallback<<<eb, 256, 0, stream>>>(
            x_dna, v_dna, x_prot, v_prot, prot_vec, dna_vec,
            esrc, edst, W1, b1, W2, b2, E, conv);
        hipMemcpyAsync(out, conv, (size_t)half * sizeof(float),
                       hipMemcpyDeviceToDevice, stream);
    }
}

// Round 8
// 465.459 us; speedup vs baseline: 12.8935x; 1.0550x over previous
//
#include <hip/hip_runtime.h>

// ---------------------------------------------------------------------------
// BiNet R8: per-node gather, 4 lanes/node, DESCENDING (branch,count) sort.
//   h1 = yd[dst] + yp[src] + W1p.ppf ;  msg = relu(relu(h1) @ W2 + b2)
//   * yp[g][src] (30.7MB bf16) and yd[dst] (14.1MB bf16, branch unique per
//     dst, b1 folded) precomputed in ONE fused kernel.
//   * descending count order -> long blocks dispatched first (makespan).
//   * 4 lanes/node, butterfly shfl_xor(1),(2); sub0 stores out, sub1 conv.
//   * h1 scalar-at-a-time (no h1h array) -> VGPR ~90, 4 waves/SIMD.
//   * build: fused memset, hist+node_order-init inside scan1, 10 dispatches.
//   * tiered: MODE2 (yp+yd) -> MODE1 (yp) -> MODE0 (basic) -> edge fallback.
// ---------------------------------------------------------------------------

#define IN_C 32
#define IN_F 68

__device__ __forceinline__ float angf(float ax, float ay, float az,
                                      float bx, float by, float bz) {
    float cx = ay * bz - az * by;
    float cy = az * bx - ax * bz;
    float cz = ax * by - ay * bx;
    float cn = sqrtf(cx * cx + cy * cy + cz * cz);
    float dt = ax * bx + ay * by + az * bz;
    return atan2f(cn, dt);
}

__device__ __forceinline__ int branch_of(int m) {
    if (m == 0 || m == 10) return 0;
    if (m == 1 || m == 9)  return 1;
    if (m >= 2 && m <= 5)  return 2;
    return 3;
}

__device__ __forceinline__ unsigned bf16r(float f) {
    unsigned u = __float_as_uint(f);
    return (u + 0x7fffu + ((u >> 16) & 1u)) >> 16;
}

// --- CSR build ----------------------------------------------------------------
__global__ void k_count(const int* __restrict__ edst, int E, int* counts) {
    int t = blockIdx.x * blockDim.x + threadIdx.x;
    if (t >= E) return;
    atomicAdd(&counts[edst[t]], 1);
}

// scan + (branch, desc-count) histogram + node_order init, one pass
__global__ __launch_bounds__(1024) void k_scan1(const int* __restrict__ counts,
                                                int NN, int NDp, int* cursor,
                                                int* blk, int* hist,
                                                int* node_order) {
    __shared__ int wsum[16];
    __shared__ int lh[256];
    if (threadIdx.x < 256) lh[threadIdx.x] = 0;
    __syncthreads();
    int t = blockIdx.x * 1024 + threadIdx.x;
    int lane = threadIdx.x & 63;
    int wid = threadIdx.x >> 6;
    int c = (t < NN) ? counts[t] : 0;
    if (t < NN) {
        int g = branch_of(t % 11);
        int cc = c > 63 ? 63 : c;
        atomicAdd(&lh[g * 64 + (63 - cc)], 1);   // descending count order
    }
    if (t < NDp) node_order[t] = -1;
    int inc = c;
    #pragma unroll
    for (int d = 1; d < 64; d <<= 1) {
        int v = __shfl_up(inc, d, 64);
        if (lane >= d) inc += v;
    }
    if (lane == 63) wsum[wid] = inc;
    __syncthreads();
    if (threadIdx.x < 16) {
        int v = wsum[threadIdx.x];
        int wi = v;
        #pragma unroll
        for (int d = 1; d < 16; d <<= 1) {
            int u = __shfl_up(wi, d, 64);
            if (threadIdx.x >= d) wi += u;
        }
        wsum[threadIdx.x] = wi - v;
        if (threadIdx.x == 15) blk[blockIdx.x] = wi;
    }
    __syncthreads();
    if (t < NN) cursor[t] = inc - c + wsum[wid];
    if (threadIdx.x < 256 && lh[threadIdx.x])
        atomicAdd(&hist[threadIdx.x], lh[threadIdx.x]);
}

__global__ __launch_bounds__(256) void k_scan2(int* blk, int nblk) {
    __shared__ int wsum[4];
    int lane = threadIdx.x & 63;
    int wid = threadIdx.x >> 6;
    int v = (threadIdx.x < nblk) ? blk[threadIdx.x] : 0;
    int inc = v;
    #pragma unroll
    for (int d = 1; d < 64; d <<= 1) {
        int u = __shfl_up(inc, d, 64);
        if (lane >= d) inc += u;
    }
    if (lane == 63) wsum[wid] = inc;
    __syncthreads();
    if (threadIdx.x < 4) {
        int w = wsum[threadIdx.x];
        int wi = w;
        #pragma unroll
        for (int d = 1; d < 4; d <<= 1) {
            int u = __shfl_up(wi, d, 64);
            if (threadIdx.x >= d) wi += u;
        }
        wsum[threadIdx.x] = wi - w;
    }
    __syncthreads();
    if (threadIdx.x < nblk) blk[threadIdx.x] = inc - v + wsum[wid];
}

__global__ __launch_bounds__(1024) void k_scan3(int* cursor, const int* blk, int NN) {
    int t = blockIdx.x * 1024 + threadIdx.x;
    if (t >= NN) return;
    cursor[t] += blk[blockIdx.x];
}

__global__ void k_fill(const int* __restrict__ esrc, const int* __restrict__ edst,
                       int E, int* cursor, int* __restrict__ pool_src) {
    int t = blockIdx.x * blockDim.x + threadIdx.x;
    if (t >= E) return;
    int pos = atomicAdd(&cursor[edst[t]], 1);
    pool_src[pos] = esrc[t];
}

__global__ __launch_bounds__(256) void k_padscan2(int* hist, int* pbs) {
    __shared__ int gsum[4];
    __shared__ int gbase[5];
    int lane = threadIdx.x & 63;
    int w = threadIdx.x >> 6;
    int v = hist[threadIdx.x];
    int inc = v;
    #pragma unroll
    for (int d = 1; d < 64; d <<= 1) {
        int u = __shfl_up(inc, d, 64);
        if (lane >= d) inc += u;
    }
    if (lane == 63) gsum[w] = inc;
    __syncthreads();
    if (threadIdx.x == 0) {
        int base = 0;
        #pragma unroll
        for (int g = 0; g < 4; ++g) {
            gbase[g] = base;
            base = (base + gsum[g] + 31) & ~31;   // 32-node aligned group base
        }
        gbase[4] = base;
    }
    __syncthreads();
    hist[threadIdx.x] = gbase[w] + inc - v;
    if (threadIdx.x < 5) pbs[threadIdx.x] = gbase[threadIdx.x];
}

__global__ __launch_bounds__(256) void k_assign(const int* __restrict__ counts,
                                                int ND, int* cur,
                                                int* __restrict__ node_order) {
    __shared__ int lh[256];
    __shared__ int lbase[256];
    lh[threadIdx.x] = 0;
    __syncthreads();
    int t = blockIdx.x * 256 + threadIdx.x;
    bool v = (t < ND);
    int bin = 0, rank = 0;
    if (v) {
        int g = branch_of(t % 11);
        int c = counts[t]; c = c > 63 ? 63 : c;
        bin = g * 64 + (63 - c);                  // descending count order
        rank = atomicAdd(&lh[bin], 1);
    }
    __syncthreads();
    int cnt = lh[threadIdx.x];
    if (cnt > 0) lbase[threadIdx.x] = atomicAdd(&cur[threadIdx.x], cnt);
    __syncthreads();
    if (v) node_order[lbase[bin] + rank] = t;
}

// --- fused precompute: yp[g][p] = W1a.x_prot[p];  yd[d] = b1 + W1c.x_dna[d] ---
__global__ __launch_bounds__(256) void k_precomp(
    const float* __restrict__ x_prot, const float* __restrict__ x_dna,
    const float* __restrict__ W1, const float* __restrict__ b1,
    int NP, int NPpad, int NB, int NBpad, int do_dna,
    unsigned short* __restrict__ yp, unsigned short* __restrict__ yd)
{
    int t = blockIdx.x * 256 + threadIdx.x;
    int NP4 = 4 * NPpad;
    float h[IN_C];
    unsigned short* dstp;

    if (t < NP4) {
        int g = t / NPpad;                        // wave-uniform (NPpad%64==0)
        int p = t - g * NPpad;
        if (p >= NP) return;
        int bb = __builtin_amdgcn_readfirstlane(g);
        const float* Wa = W1 + bb * (IN_F * IN_C);
        #pragma unroll
        for (int c = 0; c < IN_C; ++c) h[c] = 0.0f;
        const float4* xp = reinterpret_cast<const float4*>(x_prot + (size_t)p * IN_C);
        #pragma unroll
        for (int kk = 0; kk < 8; ++kk) {
            float4 xv = xp[kk];
            float fs[4] = {xv.x, xv.y, xv.z, xv.w};
            #pragma unroll
            for (int j = 0; j < 4; ++j)
                #pragma unroll
                for (int c = 0; c < IN_C; ++c)
                    h[c] = fmaf(fs[j], Wa[(kk * 4 + j) * IN_C + c], h[c]);
        }
        dstp = yp + ((size_t)bb * NP + p) * IN_C;
    } else {
        if (!do_dna) return;
        int t2 = t - NP4;
        int q = t2 / NBpad;                       // wave-uniform (NBpad%64==0)
        if (q >= 11) return;
        int idx = t2 - q * NBpad;
        if (idx >= NB) return;
        int g, m;
        if (q < 2)      { g = 0; m = q ? 10 : 0; }
        else if (q < 4) { g = 1; m = (q == 2) ? 1 : 9; }
        else if (q < 8) { g = 2; m = 2 + (q - 4); }
        else            { g = 3; m = 6 + (q - 8); }
        int bb = __builtin_amdgcn_readfirstlane(g);
        int dn = idx * 11 + m;
        const float* Wa = W1 + bb * (IN_F * IN_C);
        const float* ba = b1 + bb * IN_C;
        #pragma unroll
        for (int c = 0; c < IN_C; ++c) h[c] = ba[c];
        const float4* xd = reinterpret_cast<const float4*>(x_dna + (size_t)dn * IN_C);
        #pragma unroll
        for (int kk = 0; kk < 8; ++kk) {
            float4 xv = xd[kk];
            float fs[4] = {xv.x, xv.y, xv.z, xv.w};
            #pragma unroll
            for (int j = 0; j < 4; ++j)
                #pragma unroll
                for (int c = 0; c < IN_C; ++c)
                    h[c] = fmaf(fs[j], Wa[(36 + kk * 4 + j) * IN_C + c], h[c]);
        }
        dstp = yd + (size_t)dn * IN_C;
    }

    unsigned yw[16];
    #pragma unroll
    for (int j = 0; j < 16; ++j)
        yw[j] = bf16r(h[2 * j]) | (bf16r(h[2 * j + 1]) << 16);
    uint4* d4 = reinterpret_cast<uint4*>(dstp);
    d4[0] = make_uint4(yw[0], yw[1], yw[2], yw[3]);
    d4[1] = make_uint4(yw[4], yw[5], yw[6], yw[7]);
    d4[2] = make_uint4(yw[8], yw[9], yw[10], yw[11]);
    d4[3] = make_uint4(yw[12], yw[13], yw[14], yw[15]);
}

// --- main kernel: 4 lanes/node ------------------------------------------------
// MODE: 0 = basic (no precomp), 1 = yp only, 2 = yp + yd
template <int MODE>
__global__ __launch_bounds__(256) void k_nodes4(
    const float* __restrict__ x_dna, const float* __restrict__ v_dna,
    const float* __restrict__ x_prot, const float* __restrict__ v_prot,
    const float* __restrict__ prot_vec, const float* __restrict__ dna_vec,
    const float* __restrict__ W1, const float* __restrict__ b1,
    const float* __restrict__ W2, const float* __restrict__ b2,
    const int* __restrict__ node_order, const int* __restrict__ rowend,
    const int* __restrict__ counts, const int* __restrict__ pool_src,
    const int* __restrict__ pbs,
    const unsigned short* __restrict__ yp, const unsigned short* __restrict__ yd,
    int NP, float* __restrict__ out, float* __restrict__ conv, int NDp)
{
    int t = blockIdx.x * 256 + threadIdx.x;
    int pid = t >> 2;
    int sub = t & 3;
    if (pid >= NDp) return;

    int pb1 = pbs[1], pb2 = pbs[2], pb3 = pbs[3];
    int g = (pid >= pb1) + (pid >= pb2) + (pid >= pb3);
    int bb = __builtin_amdgcn_readfirstlane(g);

    int dst = node_order[pid];
    bool valid = (dst >= 0);
    int dsafe = valid ? dst : 0;

    int n_all = valid ? counts[dsafe] : 0;
    int start_all = valid ? (rowend[dsafe] - n_all) : 0;
    int nb4 = n_all >> 2, rem = n_all & 3;
    int n = nb4 + (sub < rem ? 1 : 0);
    int start = start_all + sub * nb4 + (sub < rem ? sub : rem);

    const float* Wa  = W1 + bb * (IN_F * IN_C);
    const float* Wp  = Wa + 32 * IN_C;            // rows 32..35
    const float* Wb  = W2 + bb * (IN_C * IN_C);
    const float* ba  = b1 + bb * IN_C;
    const float* bb2 = b2 + bb * IN_C;

    float vdx = v_dna[dsafe * 3 + 0], vdy = v_dna[dsafe * 3 + 1], vdz = v_dna[dsafe * 3 + 2];
    float nix = dna_vec[dsafe * 3 + 0], niy = dna_vec[dsafe * 3 + 1], niz = dna_vec[dsafe * 3 + 2];

    // h1b: dst-only part of layer 1 (bias folded)
    float h1b[IN_C];
    if constexpr (MODE == 2) {
        const uint4* ydv = reinterpret_cast<const uint4*>(yd + (size_t)dsafe * IN_C);
        uint4 w0 = ydv[0], w1 = ydv[1], w2 = ydv[2], w3 = ydv[3];
        unsigned dw[16];
        *reinterpret_cast<uint4*>(&dw[0])  = w0;
        *reinterpret_cast<uint4*>(&dw[4])  = w1;
        *reinterpret_cast<uint4*>(&dw[8])  = w2;
        *reinterpret_cast<uint4*>(&dw[12]) = w3;
        #pragma unroll
        for (int j = 0; j < 16; ++j) {
            h1b[2 * j]     = __uint_as_float(dw[j] << 16);
            h1b[2 * j + 1] = __uint_as_float(dw[j] & 0xffff0000u);
        }
    } else {
        #pragma unroll
        for (int c = 0; c < IN_C; ++c) h1b[c] = ba[c];
        const float4* xd = reinterpret_cast<const float4*>(x_dna + (size_t)dsafe * IN_C);
        #pragma unroll
        for (int kk = 0; kk < 8; ++kk) {
            float4 xv = xd[kk];
            float fs[4] = {xv.x, xv.y, xv.z, xv.w};
            #pragma unroll
            for (int j = 0; j < 4; ++j)
                #pragma unroll
                for (int c = 0; c < IN_C; ++c)
                    h1b[c] = fmaf(fs[j], Wa[(36 + kk * 4 + j) * IN_C + c], h1b[c]);
        }
    }

    float acc[IN_C];
    #pragma unroll
    for (int c = 0; c < IN_C; ++c) acc[c] = 0.0f;

    if constexpr (MODE >= 1) {
        const unsigned short* yprow = yp + (size_t)bb * NP * IN_C;
        int src_c = 0;
        float vpx_c = 0, vpy_c = 0, vpz_c = 0, njx_c = 0, njy_c = 0, njz_c = 0;
        if (n > 0) {
            src_c = pool_src[start];
            vpx_c = v_prot[src_c * 3 + 0]; vpy_c = v_prot[src_c * 3 + 1]; vpz_c = v_prot[src_c * 3 + 2];
            njx_c = prot_vec[src_c * 3 + 0]; njy_c = prot_vec[src_c * 3 + 1]; njz_c = prot_vec[src_c * 3 + 2];
        }
        for (int k = 0; k < n; ++k) {
            // yp load for CURRENT edge first (address ready at iter start)
            const uint4* ypv = reinterpret_cast<const uint4*>(yprow + (size_t)src_c * IN_C);
            uint4 y0 = ypv[0], y1 = ypv[1], y2 = ypv[2], y3 = ypv[3];

            // prefetch next edge's src + geometry
            int kn = (k + 1 < n) ? (k + 1) : k;
            int src_n = pool_src[start + kn];
            float vpx_n = v_prot[src_n * 3 + 0], vpy_n = v_prot[src_n * 3 + 1], vpz_n = v_prot[src_n * 3 + 2];
            float njx_n = prot_vec[src_n * 3 + 0], njy_n = prot_vec[src_n * 3 + 1], njz_n = prot_vec[src_n * 3 + 2];

            // geometry (covers yp latency)
            float dx = vpx_c - vdx, dy = vpy_c - vdy, dz = vpz_c - vdz;
            float pf0 = sqrtf(dx * dx + dy * dy + dz * dz);
            float pf1 = angf(nix, niy, niz, dx, dy, dz);
            float pf2 = angf(njx_c, njy_c, njz_c, dx, dy, dz);
            float pf3 = angf(nix, niy, niz, njx_c, njy_c, njz_c);

            unsigned yw[16];
            *reinterpret_cast<uint4*>(&yw[0])  = y0;
            *reinterpret_cast<uint4*>(&yw[4])  = y1;
            *reinterpret_cast<uint4*>(&yw[8])  = y2;
            *reinterpret_cast<uint4*>(&yw[12]) = y3;

            float h2[IN_C];
            #pragma unroll
            for (int c = 0; c < IN_C; ++c) h2[c] = bb2[c];

            // h1 scalar-at-a-time: no h1 array -> low VGPR
            #pragma unroll
            for (int k2 = 0; k2 < IN_C; ++k2) {
                unsigned w = yw[k2 >> 1];
                float ypf = (k2 & 1) ? __uint_as_float(w & 0xffff0000u)
                                     : __uint_as_float(w << 16);
                float h1v = h1b[k2] + ypf;
                h1v = fmaf(pf0, Wp[0 * IN_C + k2], h1v);
                h1v = fmaf(pf1, Wp[1 * IN_C + k2], h1v);
                h1v = fmaf(pf2, Wp[2 * IN_C + k2], h1v);
                h1v = fmaf(pf3, Wp[3 * IN_C + k2], h1v);
                float f = fmaxf(h1v, 0.0f);
                #pragma unroll
                for (int c = 0; c < IN_C; ++c)
                    h2[c] = fmaf(f, Wb[k2 * IN_C + c], h2[c]);
            }

            #pragma unroll
            for (int c = 0; c < IN_C; ++c)
                acc[c] += fmaxf(h2[c], 0.0f);

            src_c = src_n;
            vpx_c = vpx_n; vpy_c = vpy_n; vpz_c = vpz_n;
            njx_c = njx_n; njy_c = njy_n; njz_c = njz_n;
        }
    } else {
        for (int k = 0; k < n; ++k) {
            int src = pool_src[start + k];
            float vpx = v_prot[src * 3 + 0], vpy = v_prot[src * 3 + 1], vpz = v_prot[src * 3 + 2];
            float njx = prot_vec[src * 3 + 0], njy = prot_vec[src * 3 + 1], njz = prot_vec[src * 3 + 2];
            float dx = vpx - vdx, dy = vpy - vdy, dz = vpz - vdz;
            float pf[4];
            pf[0] = sqrtf(dx * dx + dy * dy + dz * dz);
            pf[1] = angf(nix, niy, niz, dx, dy, dz);
            pf[2] = angf(njx, njy, njz, dx, dy, dz);
            pf[3] = angf(nix, niy, niz, njx, njy, njz);

            float h2[IN_C];
            #pragma unroll
            for (int c = 0; c < IN_C; ++c) h2[c] = bb2[c];

            const float4* xp = reinterpret_cast<const float4*>(x_prot + (size_t)src * IN_C);
            #pragma unroll
            for (int hh = 0; hh < 2; ++hh) {
                float h1h[16];
                #pragma unroll
                for (int c = 0; c < 16; ++c) h1h[c] = h1b[hh * 16 + c];
                #pragma unroll
                for (int kk = 0; kk < 8; ++kk) {
                    float4 xv = xp[kk];
                    float fs[4] = {xv.x, xv.y, xv.z, xv.w};
                    #pragma unroll
                    for (int j = 0; j < 4; ++j)
                        #pragma unroll
                        for (int c = 0; c < 16; ++c)
                            h1h[c] = fmaf(fs[j], Wa[(kk * 4 + j) * IN_C + hh * 16 + c], h1h[c]);
                }
                #pragma unroll
                for (int j = 0; j < 4; ++j)
                    #pragma unroll
                    for (int c = 0; c < 16; ++c)
                        h1h[c] = fmaf(pf[j], Wp[j * IN_C + hh * 16 + c], h1h[c]);
                #pragma unroll
                for (int k2 = 0; k2 < 16; ++k2) {
                    float f = fmaxf(h1h[k2], 0.0f);
                    #pragma unroll
                    for (int c = 0; c < IN_C; ++c)
                        h2[c] = fmaf(f, Wb[(hh * 16 + k2) * IN_C + c], h2[c]);
                }
            }
            #pragma unroll
            for (int c = 0; c < IN_C; ++c)
                acc[c] += fmaxf(h2[c], 0.0f);
        }
    }

    // butterfly over the 4 lanes of this node -> all lanes hold the total
    #pragma unroll
    for (int c = 0; c < IN_C; ++c)
        acc[c] += __shfl_xor(acc[c], 1, 64);
    #pragma unroll
    for (int c = 0; c < IN_C; ++c)
        acc[c] += __shfl_xor(acc[c], 2, 64);

    if (valid && sub < 2) {
        // out == conv (messages >= 0 -> relu(agg) == agg)
        float* p = (sub ? conv : out) + (size_t)dst * IN_C;
        float4* p4 = reinterpret_cast<float4*>(p);
        #pragma unroll
        for (int qq = 0; qq < 8; ++qq) {
            float4 v;
            v.x = acc[qq * 4 + 0]; v.y = acc[qq * 4 + 1];
            v.z = acc[qq * 4 + 2]; v.w = acc[qq * 4 + 3];
            p4[qq] = v;
        }
    }
}

// --- fallback (ws too small): per-edge atomics ---------------------------------
__global__ __launch_bounds__(256) void k_edges_fallback(
    const float* __restrict__ x_dna, const float* __restrict__ v_dna,
    const float* __restrict__ x_prot, const float* __restrict__ v_prot,
    const float* __restrict__ prot_vec, const float* __restrict__ dna_vec,
    const int* __restrict__ esrc, const int* __restrict__ edst,
    const float* __restrict__ W1, const float* __restrict__ b1,
    const float* __restrict__ W2, const float* __restrict__ b2,
    int E, float* __restrict__ conv)
{
    int t = blockIdx.x * blockDim.x + threadIdx.x;
    if (t >= E) return;
    int src = esrc[t], dst = edst[t];
    int b = branch_of(dst % 11);
    const float* Wa  = W1 + b * (IN_F * IN_C);
    const float* Wb  = W2 + b * (IN_C * IN_C);
    const float* ba  = b1 + b * IN_C;
    const float* bb2 = b2 + b * IN_C;

    float vdx = v_dna[dst * 3 + 0], vdy = v_dna[dst * 3 + 1], vdz = v_dna[dst * 3 + 2];
    float vpx = v_prot[src * 3 + 0], vpy = v_prot[src * 3 + 1], vpz = v_prot[src * 3 + 2];
    float nix = dna_vec[dst * 3 + 0], niy = dna_vec[dst * 3 + 1], niz = dna_vec[dst * 3 + 2];
    float njx = prot_vec[src * 3 + 0], njy = prot_vec[src * 3 + 1], njz = prot_vec[src * 3 + 2];
    float dx = vpx - vdx, dy = vpy - vdy, dz = vpz - vdz;
    float pf[4];
    pf[0] = sqrtf(dx * dx + dy * dy + dz * dz);
    pf[1] = angf(nix, niy, niz, dx, dy, dz);
    pf[2] = angf(njx, njy, njz, dx, dy, dz);
    pf[3] = angf(nix, niy, niz, njx, njy, njz);

    float h1[IN_C];
    #pragma unroll
    for (int c = 0; c < IN_C; ++c) h1[c] = ba[c];
    const float4* xp = reinterpret_cast<const float4*>(x_prot + (size_t)src * IN_C);
    #pragma unroll
    for (int kk = 0; kk < 8; ++kk) {
        float4 xv = xp[kk];
        float fs[4] = {xv.x, xv.y, xv.z, xv.w};
        #pragma unroll
        for (int j = 0; j < 4; ++j)
            #pragma unroll
            for (int c = 0; c < IN_C; ++c)
                h1[c] = fmaf(fs[j], Wa[(kk * 4 + j) * IN_C + c], h1[c]);
    }
    #pragma unroll
    for (int j = 0; j < 4; ++j)
        #pragma unroll
        for (int c = 0; c < IN_C; ++c)
            h1[c] = fmaf(pf[j], Wa[(32 + j) * IN_C + c], h1[c]);
    const float4* xd = reinterpret_cast<const float4*>(x_dna + (size_t)dst * IN_C);
    #pragma unroll
    for (int kk = 0; kk < 8; ++kk) {
        float4 xv = xd[kk];
        float fs[4] = {xv.x, xv.y, xv.z, xv.w};
        #pragma unroll
        for (int j = 0; j < 4; ++j)
            #pragma unroll
            for (int c = 0; c < IN_C; ++c)
                h1[c] = fmaf(fs[j], Wa[(36 + kk * 4 + j) * IN_C + c], h1[c]);
    }
    float h2[IN_C];
    #pragma unroll
    for (int c = 0; c < IN_C; ++c) h2[c] = bb2[c];
    #pragma unroll
    for (int k = 0; k < IN_C; ++k) {
        float f = fmaxf(h1[k], 0.0f);
        #pragma unroll
        for (int c = 0; c < IN_C; ++c)
            h2[c] = fmaf(f, Wb[k * IN_C + c], h2[c]);
    }
    float* cv = conv + (size_t)dst * IN_C;
    #pragma unroll
    for (int c = 0; c < IN_C; ++c)
        atomicAdd(&cv[c], fmaxf(h2[c], 0.0f));
}

extern "C" void kernel_launch(void* const* d_in, const int* in_sizes, int n_in,
                              void* d_out, int out_size, void* d_ws, size_t ws_size,
                              hipStream_t stream) {
    const float* x_dna    = (const float*)d_in[0];
    const float* v_dna    = (const float*)d_in[1];
    const float* x_prot   = (const float*)d_in[2];
    const float* v_prot   = (const float*)d_in[3];
    const float* prot_vec = (const float*)d_in[4];
    const float* dna_vec  = (const float*)d_in[5];
    const int*   esrc     = (const int*)d_in[6];
    const int*   edst     = (const int*)d_in[7];
    const float* W1       = (const float*)d_in[8];
    const float* b1       = (const float*)d_in[9];
    const float* W2       = (const float*)d_in[10];
    const float* b2       = (const float*)d_in[11];

    const int E  = in_sizes[6];
    const int ND = in_sizes[0] / IN_C;       // N_DNA
    const int NP = in_sizes[2] / IN_C;       // N_PROT
    const int half = out_size / 2;
    float* out  = (float*)d_out;
    float* conv = out + half;

    const int NDp = ND + 160;
    const int nblk_scan = (NDp + 1023) / 1024;
    const int eb = (E + 255) / 256;

    // ws layout: counts|hist|blk|pbs|rowcur|node_order|pool | yp | yd
    const size_t base_ints = (size_t)ND + 256 + 256 + 8 + ND + NDp + E;
    const size_t ws_base   = base_ints * sizeof(int);
    const size_t yp_off    = (ws_base + 255) & ~(size_t)255;
    const size_t yp_bytes  = (size_t)NP * 4 * IN_C * sizeof(unsigned short);
    const size_t yd_off    = yp_off + yp_bytes;
    const size_t yd_bytes  = (size_t)ND * IN_C * sizeof(unsigned short);

    if (ND == half / IN_C && ws_size >= ws_base && nblk_scan <= 256) {
        int* counts     = (int*)d_ws;          // ND
        int* hist       = counts + ND;         // 256 (contiguous with counts!)
        int* blk        = hist + 256;          // 256
        int* pbs        = blk + 256;           // 8
        int* rowcur     = pbs + 8;             // ND
        int* node_order = rowcur + ND;         // NDp
        int* pool_src   = node_order + NDp;    // E
        unsigned short* yp = (unsigned short*)((char*)d_ws + yp_off);
        unsigned short* yd = (unsigned short*)((char*)d_ws + yd_off);

        int mode = 0;
        if (ws_size >= yd_off + yd_bytes && ND % 11 == 0) mode = 2;
        else if (ws_size >= yp_off + yp_bytes)            mode = 1;

        // one memset covers counts + hist (contiguous)
        hipMemsetAsync(counts, 0, ((size_t)ND + 256) * sizeof(int), stream);

        k_count<<<eb, 256, 0, stream>>>(edst, E, counts);
        k_scan1<<<nblk_scan, 1024, 0, stream>>>(counts, ND, NDp, rowcur, blk,
                                                hist, node_order);
        k_scan2<<<1, 256, 0, stream>>>(blk, nblk_scan);
        k_scan3<<<nblk_scan, 1024, 0, stream>>>(rowcur, blk, ND);
        k_fill<<<eb, 256, 0, stream>>>(esrc, edst, E, rowcur, pool_src);
        k_padscan2<<<1, 256, 0, stream>>>(hist, pbs);
        k_assign<<<(ND + 255) / 256, 256, 0, stream>>>(counts, ND, hist, node_order);

        int NPpad = (NP + 63) & ~63;
        int NB = ND / 11;
        int NBpad = (NB + 63) & ~63;
        if (mode >= 1) {
            int tot = 4 * NPpad + (mode == 2 ? 11 * NBpad : 0);
            k_precomp<<<(tot + 255) / 256, 256, 0, stream>>>(
                x_prot, x_dna, W1, b1, NP, NPpad, NB, NBpad, mode == 2, yp, yd);
        }

        int nb4 = (4 * NDp + 255) / 256;
        if (mode == 2) {
            k_nodes4<2><<<nb4, 256, 0, stream>>>(
                x_dna, v_dna, x_prot, v_prot, prot_vec, dna_vec,
                W1, b1, W2, b2, node_order, rowcur, counts, pool_src, pbs,
                yp, yd, NP, out, conv, NDp);
        } else if (mode == 1) {
            k_nodes4<1><<<nb4, 256, 0, stream>>>(
                x_dna, v_dna, x_prot, v_prot, prot_vec, dna_vec,
                W1, b1, W2, b2, node_order, rowcur, counts, pool_src, pbs,
                yp, nullptr, NP, out, conv, NDp);
        } else {
            k_nodes4<0><<<nb4, 256, 0, stream>>>(
                x_dna, v_dna, x_prot, v_prot, prot_vec, dna_vec,
                W1, b1, W2, b2, node_order, rowcur, counts, pool_src, pbs,
                nullptr, nullptr, NP, out, conv, NDp);
        }
    } else {
        hipMemsetAsync(conv, 0, (size_t)half * sizeof(float), stream);
        k_edges_fallback<<<eb, 256, 0, stream>>>(
            x_dna, v_dna, x_prot, v_prot, prot_vec, dna_vec,
            esrc, edst, W1, b1, W2, b2, E, conv);
        hipMemcpyAsync(out, conv, (size_t)half * sizeof(float),
                       hipMemcpyDeviceToDevice, stream);
    }
}

// Round 9
// 350.134 us; speedup vs baseline: 17.1403x; 1.3294x over previous
//
#include <hip/hip_runtime.h>

// ---------------------------------------------------------------------------
// BiNet R9: layer-2 GEMM on MFMA.
//   Per wave-iteration: 64 edge slots (32 nodes x 2 slots) -> X[64x32] bf16;
//   h2 = relu(h1)@W2 via 4x v_mfma_f32_32x32x16_bf16 (2 row-blocks x K=32).
//   W2 lives in 8 VGPRs (B-frags) -- kills R8's 4KB-per-iteration s_load
//   stream that serialized the h2 FMA chain on lgkmcnt.
//   h1 = yd[dst](bf16) + yp[src](bf16) + Wp.ppf  (VALU, scalar Wp only 512B).
//   A-frag: row=l&31, k=(l>>5)*8+e  -> 16x shfl_xor(32) + cndmask.
//   D layout (verified): col=lane&31, row=(reg&3)+8*(reg>>2)+4*(lane>>5).
//   Outer relu(D+b2) masked by validity ballot; acc[16] f32; coalesced store.
//   Wave-uniform loop bound (shfl-max); NO early returns (MFMA reads all
//   lanes' A/B regs -- partial-exec waves would corrupt B).
// ---------------------------------------------------------------------------

#define IN_C 32
#define IN_F 68

using bf16x8v = __attribute__((ext_vector_type(8))) short;
using f32x16v = __attribute__((ext_vector_type(16))) float;

union U4F { unsigned u[4]; bf16x8v v; };

__device__ __forceinline__ unsigned cvtpk_bf16(float a, float b) {
    unsigned r;
    asm("v_cvt_pk_bf16_f32 %0, %1, %2" : "=v"(r) : "v"(a), "v"(b));
    return r;
}
__device__ __forceinline__ float bflo(unsigned u) { return __uint_as_float(u << 16); }
__device__ __forceinline__ float bfhi(unsigned u) { return __uint_as_float(u & 0xffff0000u); }

__device__ __forceinline__ float angf(float ax, float ay, float az,
                                      float bx, float by, float bz) {
    float cx = ay * bz - az * by;
    float cy = az * bx - ax * bz;
    float cz = ax * by - ay * bx;
    float cn = sqrtf(cx * cx + cy * cy + cz * cz);
    float dt = ax * bx + ay * by + az * bz;
    return atan2f(cn, dt);
}

__device__ __forceinline__ int branch_of(int m) {
    if (m == 0 || m == 10) return 0;
    if (m == 1 || m == 9)  return 1;
    if (m >= 2 && m <= 5)  return 2;
    return 3;
}

__device__ __forceinline__ unsigned bf16r(float f) {
    unsigned u = __float_as_uint(f);
    return (u + 0x7fffu + ((u >> 16) & 1u)) >> 16;
}

// --- CSR build (identical to R8) ----------------------------------------------
__global__ void k_count(const int* __restrict__ edst, int E, int* counts) {
    int t = blockIdx.x * blockDim.x + threadIdx.x;
    if (t >= E) return;
    atomicAdd(&counts[edst[t]], 1);
}

__global__ __launch_bounds__(1024) void k_scan1(const int* __restrict__ counts,
                                                int NN, int NDp, int* cursor,
                                                int* blk, int* hist,
                                                int* node_order) {
    __shared__ int wsum[16];
    __shared__ int lh[256];
    if (threadIdx.x < 256) lh[threadIdx.x] = 0;
    __syncthreads();
    int t = blockIdx.x * 1024 + threadIdx.x;
    int lane = threadIdx.x & 63;
    int wid = threadIdx.x >> 6;
    int c = (t < NN) ? counts[t] : 0;
    if (t < NN) {
        int g = branch_of(t % 11);
        int cc = c > 63 ? 63 : c;
        atomicAdd(&lh[g * 64 + (63 - cc)], 1);
    }
    if (t < NDp) node_order[t] = -1;
    int inc = c;
    #pragma unroll
    for (int d = 1; d < 64; d <<= 1) {
        int v = __shfl_up(inc, d, 64);
        if (lane >= d) inc += v;
    }
    if (lane == 63) wsum[wid] = inc;
    __syncthreads();
    if (threadIdx.x < 16) {
        int v = wsum[threadIdx.x];
        int wi = v;
        #pragma unroll
        for (int d = 1; d < 16; d <<= 1) {
            int u = __shfl_up(wi, d, 64);
            if (threadIdx.x >= d) wi += u;
        }
        wsum[threadIdx.x] = wi - v;
        if (threadIdx.x == 15) blk[blockIdx.x] = wi;
    }
    __syncthreads();
    if (t < NN) cursor[t] = inc - c + wsum[wid];
    if (threadIdx.x < 256 && lh[threadIdx.x])
        atomicAdd(&hist[threadIdx.x], lh[threadIdx.x]);
}

__global__ __launch_bounds__(256) void k_scan2(int* blk, int nblk) {
    __shared__ int wsum[4];
    int lane = threadIdx.x & 63;
    int wid = threadIdx.x >> 6;
    int v = (threadIdx.x < nblk) ? blk[threadIdx.x] : 0;
    int inc = v;
    #pragma unroll
    for (int d = 1; d < 64; d <<= 1) {
        int u = __shfl_up(inc, d, 64);
        if (lane >= d) inc += u;
    }
    if (lane == 63) wsum[wid] = inc;
    __syncthreads();
    if (threadIdx.x < 4) {
        int w = wsum[threadIdx.x];
        int wi = w;
        #pragma unroll
        for (int d = 1; d < 4; d <<= 1) {
            int u = __shfl_up(wi, d, 64);
            if (threadIdx.x >= d) wi += u;
        }
        wsum[threadIdx.x] = wi - w;
    }
    __syncthreads();
    if (threadIdx.x < nblk) blk[threadIdx.x] = inc - v + wsum[wid];
}

__global__ __launch_bounds__(1024) void k_scan3(int* cursor, const int* blk, int NN) {
    int t = blockIdx.x * 1024 + threadIdx.x;
    if (t >= NN) return;
    cursor[t] += blk[blockIdx.x];
}

__global__ void k_fill(const int* __restrict__ esrc, const int* __restrict__ edst,
                       int E, int* cursor, int* __restrict__ pool_src) {
    int t = blockIdx.x * blockDim.x + threadIdx.x;
    if (t >= E) return;
    int pos = atomicAdd(&cursor[edst[t]], 1);
    pool_src[pos] = esrc[t];
}

__global__ __launch_bounds__(256) void k_padscan2(int* hist, int* pbs) {
    __shared__ int gsum[4];
    __shared__ int gbase[5];
    int lane = threadIdx.x & 63;
    int w = threadIdx.x >> 6;
    int v = hist[threadIdx.x];
    int inc = v;
    #pragma unroll
    for (int d = 1; d < 64; d <<= 1) {
        int u = __shfl_up(inc, d, 64);
        if (lane >= d) inc += u;
    }
    if (lane == 63) gsum[w] = inc;
    __syncthreads();
    if (threadIdx.x == 0) {
        int base = 0;
        #pragma unroll
        for (int g = 0; g < 4; ++g) {
            gbase[g] = base;
            base = (base + gsum[g] + 31) & ~31;   // 32-node aligned group base
        }
        gbase[4] = base;
    }
    __syncthreads();
    hist[threadIdx.x] = gbase[w] + inc - v;
    if (threadIdx.x < 5) pbs[threadIdx.x] = gbase[threadIdx.x];
}

__global__ __launch_bounds__(256) void k_assign(const int* __restrict__ counts,
                                                int ND, int* cur,
                                                int* __restrict__ node_order) {
    __shared__ int lh[256];
    __shared__ int lbase[256];
    lh[threadIdx.x] = 0;
    __syncthreads();
    int t = blockIdx.x * 256 + threadIdx.x;
    bool v = (t < ND);
    int bin = 0, rank = 0;
    if (v) {
        int g = branch_of(t % 11);
        int c = counts[t]; c = c > 63 ? 63 : c;
        bin = g * 64 + (63 - c);
        rank = atomicAdd(&lh[bin], 1);
    }
    __syncthreads();
    int cnt = lh[threadIdx.x];
    if (cnt > 0) lbase[threadIdx.x] = atomicAdd(&cur[threadIdx.x], cnt);
    __syncthreads();
    if (v) node_order[lbase[bin] + rank] = t;
}

// --- fused precompute (identical to R8) ----------------------------------------
__global__ __launch_bounds__(256) void k_precomp(
    const float* __restrict__ x_prot, const float* __restrict__ x_dna,
    const float* __restrict__ W1, const float* __restrict__ b1,
    int NP, int NPpad, int NB, int NBpad, int do_dna,
    unsigned short* __restrict__ yp, unsigned short* __restrict__ yd)
{
    int t = blockIdx.x * 256 + threadIdx.x;
    int NP4 = 4 * NPpad;
    float h[IN_C];
    unsigned short* dstp;

    if (t < NP4) {
        int g = t / NPpad;
        int p = t - g * NPpad;
        if (p >= NP) return;
        int bb = __builtin_amdgcn_readfirstlane(g);
        const float* Wa = W1 + bb * (IN_F * IN_C);
        #pragma unroll
        for (int c = 0; c < IN_C; ++c) h[c] = 0.0f;
        const float4* xp = reinterpret_cast<const float4*>(x_prot + (size_t)p * IN_C);
        #pragma unroll
        for (int kk = 0; kk < 8; ++kk) {
            float4 xv = xp[kk];
            float fs[4] = {xv.x, xv.y, xv.z, xv.w};
            #pragma unroll
            for (int j = 0; j < 4; ++j)
                #pragma unroll
                for (int c = 0; c < IN_C; ++c)
                    h[c] = fmaf(fs[j], Wa[(kk * 4 + j) * IN_C + c], h[c]);
        }
        dstp = yp + ((size_t)bb * NP + p) * IN_C;
    } else {
        if (!do_dna) return;
        int t2 = t - NP4;
        int q = t2 / NBpad;
        if (q >= 11) return;
        int idx = t2 - q * NBpad;
        if (idx >= NB) return;
        int g, m;
        if (q < 2)      { g = 0; m = q ? 10 : 0; }
        else if (q < 4) { g = 1; m = (q == 2) ? 1 : 9; }
        else if (q < 8) { g = 2; m = 2 + (q - 4); }
        else            { g = 3; m = 6 + (q - 8); }
        int bb = __builtin_amdgcn_readfirstlane(g);
        int dn = idx * 11 + m;
        const float* Wa = W1 + bb * (IN_F * IN_C);
        const float* ba = b1 + bb * IN_C;
        #pragma unroll
        for (int c = 0; c < IN_C; ++c) h[c] = ba[c];
        const float4* xd = reinterpret_cast<const float4*>(x_dna + (size_t)dn * IN_C);
        #pragma unroll
        for (int kk = 0; kk < 8; ++kk) {
            float4 xv = xd[kk];
            float fs[4] = {xv.x, xv.y, xv.z, xv.w};
            #pragma unroll
            for (int j = 0; j < 4; ++j)
                #pragma unroll
                for (int c = 0; c < IN_C; ++c)
                    h[c] = fmaf(fs[j], Wa[(36 + kk * 4 + j) * IN_C + c], h[c]);
        }
        dstp = yd + (size_t)dn * IN_C;
    }

    unsigned yw[16];
    #pragma unroll
    for (int j = 0; j < 16; ++j)
        yw[j] = bf16r(h[2 * j]) | (bf16r(h[2 * j + 1]) << 16);
    uint4* d4 = reinterpret_cast<uint4*>(dstp);
    d4[0] = make_uint4(yw[0], yw[1], yw[2], yw[3]);
    d4[1] = make_uint4(yw[4], yw[5], yw[6], yw[7]);
    d4[2] = make_uint4(yw[8], yw[9], yw[10], yw[11]);
    d4[3] = make_uint4(yw[12], yw[13], yw[14], yw[15]);
}

// --- MFMA main kernel: 32 nodes/wave, 2 slots/node -----------------------------
__global__ __launch_bounds__(256) void k_mfma(
    const float* __restrict__ v_dna, const float* __restrict__ v_prot,
    const float* __restrict__ prot_vec, const float* __restrict__ dna_vec,
    const float* __restrict__ W1, const float* __restrict__ W2,
    const float* __restrict__ b2,
    const int* __restrict__ node_order, const int* __restrict__ rowend,
    const int* __restrict__ counts, const int* __restrict__ pool_src,
    const int* __restrict__ pbs,
    const unsigned short* __restrict__ yp, const unsigned short* __restrict__ yd,
    int NP, float* __restrict__ out, float* __restrict__ conv, int NDp)
{
    int t = blockIdx.x * 256 + threadIdx.x;
    int lane = threadIdx.x & 63;
    int hi = lane >> 5;
    int col = lane & 31;
    int pid = t >> 1;
    int sub = t & 1;

    int pb1 = pbs[1], pb2v = pbs[2], pb3 = pbs[3];
    int g = (pid >= pb1) + (pid >= pb2v) + (pid >= pb3);
    int bb = __builtin_amdgcn_readfirstlane(g);

    int dst = (pid < NDp) ? node_order[pid] : -1;
    bool vnode = (dst >= 0);
    int dsafe = vnode ? dst : 0;
    int n_all = vnode ? counts[dsafe] : 0;
    int start = vnode ? (rowend[dsafe] - n_all) : 0;

    const float* Wp = W1 + bb * (IN_F * IN_C) + 32 * IN_C;   // ppf rows 32..35
    const float* Wb = W2 + bb * (IN_C * IN_C);
    float b2c = b2[bb * IN_C + col];

    // B frags: lane holds B[k = hi*8+e][col], e=0..7; B0 = k 0..15, B1 = 16..31
    U4F B0u, B1u;
    #pragma unroll
    for (int j = 0; j < 4; ++j) {
        int k0 = hi * 8 + 2 * j;
        B0u.u[j] = cvtpk_bf16(Wb[k0 * IN_C + col],        Wb[(k0 + 1) * IN_C + col]);
        B1u.u[j] = cvtpk_bf16(Wb[(16 + k0) * IN_C + col], Wb[(17 + k0) * IN_C + col]);
    }

    float vdx = v_dna[dsafe * 3 + 0], vdy = v_dna[dsafe * 3 + 1], vdz = v_dna[dsafe * 3 + 2];
    float nix = dna_vec[dsafe * 3 + 0], niy = dna_vec[dsafe * 3 + 1], niz = dna_vec[dsafe * 3 + 2];

    // yd packed bf16 (16 dwords)
    unsigned ydw[16];
    {
        const uint4* ydv = reinterpret_cast<const uint4*>(yd + (size_t)dsafe * IN_C);
        uint4 w0 = ydv[0], w1 = ydv[1], w2 = ydv[2], w3 = ydv[3];
        *reinterpret_cast<uint4*>(&ydw[0])  = w0;
        *reinterpret_cast<uint4*>(&ydw[4])  = w1;
        *reinterpret_cast<uint4*>(&ydw[8])  = w2;
        *reinterpret_cast<uint4*>(&ydw[12]) = w3;
    }

    float acc[16];
    #pragma unroll
    for (int i = 0; i < 16; ++i) acc[i] = 0.0f;

    // wave-uniform loop bound (all lanes iterate together -> MFMA never diverges)
    int niter = (n_all + 1) >> 1;
    #pragma unroll
    for (int d = 1; d < 64; d <<= 1) {
        int o = __shfl_xor(niter, d, 64);
        niter = niter > o ? niter : o;
    }

    for (int it = 0; it < niter; ++it) {
        int eidx = 2 * it + sub;
        bool valid = vnode && (eidx < n_all);
        unsigned long long vm = __ballot(valid);
        int off = valid ? (start + eidx) : 0;
        int src = pool_src[off];

        float vpx = v_prot[src * 3 + 0], vpy = v_prot[src * 3 + 1], vpz = v_prot[src * 3 + 2];
        float njx = prot_vec[src * 3 + 0], njy = prot_vec[src * 3 + 1], njz = prot_vec[src * 3 + 2];

        unsigned yw[16];
        {
            const uint4* ypv = reinterpret_cast<const uint4*>(yp + ((size_t)bb * NP + src) * IN_C);
            uint4 y0 = ypv[0], y1 = ypv[1], y2 = ypv[2], y3 = ypv[3];
            *reinterpret_cast<uint4*>(&yw[0])  = y0;
            *reinterpret_cast<uint4*>(&yw[4])  = y1;
            *reinterpret_cast<uint4*>(&yw[8])  = y2;
            *reinterpret_cast<uint4*>(&yw[12]) = y3;
        }

        float dx = vpx - vdx, dy = vpy - vdy, dz = vpz - vdz;
        float pf0 = sqrtf(dx * dx + dy * dy + dz * dz);
        float pf1 = angf(nix, niy, niz, dx, dy, dz);
        float pf2 = angf(njx, njy, njz, dx, dy, dz);
        float pf3 = angf(nix, niy, niz, njx, njy, njz);

        // h1 = yd + yp + Wp.ppf, relu, pack bf16 pairs -> p[16] dwords
        unsigned p[16];
        #pragma unroll
        for (int j = 0; j < 16; ++j) {
            int c0 = 2 * j, c1 = 2 * j + 1;
            float a0 = bflo(ydw[j]) + bflo(yw[j]);
            float a1 = bfhi(ydw[j]) + bfhi(yw[j]);
            a0 = fmaf(pf0, Wp[0 * IN_C + c0], a0);
            a0 = fmaf(pf1, Wp[1 * IN_C + c0], a0);
            a0 = fmaf(pf2, Wp[2 * IN_C + c0], a0);
            a0 = fmaf(pf3, Wp[3 * IN_C + c0], a0);
            a1 = fmaf(pf0, Wp[0 * IN_C + c1], a1);
            a1 = fmaf(pf1, Wp[1 * IN_C + c1], a1);
            a1 = fmaf(pf2, Wp[2 * IN_C + c1], a1);
            a1 = fmaf(pf3, Wp[3 * IN_C + c1], a1);
            a0 = fmaxf(a0, 0.0f);
            a1 = fmaxf(a1, 0.0f);
            p[j] = cvtpk_bf16(a0, a1);
        }

        // cross 32-lane halves: q[j] = lane^32's p[j]
        unsigned q[16];
        #pragma unroll
        for (int j = 0; j < 16; ++j)
            q[j] = (unsigned)__shfl_xor((int)p[j], 32, 64);

        // A frags: row=l&31, k=(l>>5)*8+e
        U4F a00, a01, a10, a11;
        #pragma unroll
        for (int d2 = 0; d2 < 4; ++d2) {
            a00.u[d2] = hi ? q[4 + d2]  : p[d2];       // rows 0-31,  k 0..15
            a01.u[d2] = hi ? q[12 + d2] : p[8 + d2];   // rows 0-31,  k 16..31
            a10.u[d2] = hi ? p[4 + d2]  : q[d2];       // rows 32-63, k 0..15
            a11.u[d2] = hi ? p[12 + d2] : q[8 + d2];   // rows 32-63, k 16..31
        }

        unsigned long long vms = vm >> (4 * hi);

        // row-block 0 (slots 0..31)
        {
            f32x16v D;
            #pragma unroll
            for (int r = 0; r < 16; ++r) D[r] = 0.0f;
            D = __builtin_amdgcn_mfma_f32_32x32x16_bf16(a00.v, B0u.v, D, 0, 0, 0);
            D = __builtin_amdgcn_mfma_f32_32x32x16_bf16(a01.v, B1u.v, D, 0, 0, 0);
            #pragma unroll
            for (int r = 0; r < 16; ++r) {
                int sh = (r & 3) + 8 * (r >> 2);           // +4*hi folded in vms
                float val = fmaxf(D[r] + b2c, 0.0f);
                bool ok = (vms >> sh) & 1ull;
                int ai = 2 * (r >> 2) + ((r & 3) >> 1);
                acc[ai] += ok ? val : 0.0f;
            }
        }
        // row-block 1 (slots 32..63)
        {
            f32x16v D;
            #pragma unroll
            for (int r = 0; r < 16; ++r) D[r] = 0.0f;
            D = __builtin_amdgcn_mfma_f32_32x32x16_bf16(a10.v, B0u.v, D, 0, 0, 0);
            D = __builtin_amdgcn_mfma_f32_32x32x16_bf16(a11.v, B1u.v, D, 0, 0, 0);
            #pragma unroll
            for (int r = 0; r < 16; ++r) {
                int sh = 32 + (r & 3) + 8 * (r >> 2);
                float val = fmaxf(D[r] + b2c, 0.0f);
                bool ok = (vms >> sh) & 1ull;
                int ai = 8 + 2 * (r >> 2) + ((r & 3) >> 1);
                acc[ai] += ok ? val : 0.0f;
            }
        }
    }

    // stores: acc[i] = channel col of wave-node m = 16*rb + 4*q + 2*hi + u
    #pragma unroll
    for (int i = 0; i < 16; ++i) {
        int rb = i >> 3, rem = i & 7;
        int q2 = rem >> 1, u = rem & 1;
        int m = 16 * rb + 4 * q2 + 2 * hi + u;
        int dm = __shfl(dst, 2 * m, 64);
        if (dm >= 0) {
            out[(size_t)dm * IN_C + col]  = acc[i];   // out == conv (msgs >= 0)
            conv[(size_t)dm * IN_C + col] = acc[i];
        }
    }
}

// --- non-MFMA fallbacks (R8's k_nodes4 mode 1/0) --------------------------------
template <int MODE>
__global__ __launch_bounds__(256) void k_nodes4(
    const float* __restrict__ x_dna, const float* __restrict__ v_dna,
    const float* __restrict__ x_prot, const float* __restrict__ v_prot,
    const float* __restrict__ prot_vec, const float* __restrict__ dna_vec,
    const float* __restrict__ W1, const float* __restrict__ b1,
    const float* __restrict__ W2, const float* __restrict__ b2,
    const int* __restrict__ node_order, const int* __restrict__ rowend,
    const int* __restrict__ counts, const int* __restrict__ pool_src,
    const int* __restrict__ pbs,
    const unsigned short* __restrict__ yp,
    int NP, float* __restrict__ out, float* __restrict__ conv, int NDp)
{
    int t = blockIdx.x * 256 + threadIdx.x;
    int pid = t >> 2;
    int sub = t & 3;
    if (pid >= NDp) return;

    int pb1 = pbs[1], pb2 = pbs[2], pb3 = pbs[3];
    int g = (pid >= pb1) + (pid >= pb2) + (pid >= pb3);
    int bb = __builtin_amdgcn_readfirstlane(g);

    int dst = node_order[pid];
    bool valid = (dst >= 0);
    int dsafe = valid ? dst : 0;

    int n_all = valid ? counts[dsafe] : 0;
    int start_all = valid ? (rowend[dsafe] - n_all) : 0;
    int nb4 = n_all >> 2, rem = n_all & 3;
    int n = nb4 + (sub < rem ? 1 : 0);
    int start = start_all + sub * nb4 + (sub < rem ? sub : rem);

    const float* Wa  = W1 + bb * (IN_F * IN_C);
    const float* Wp  = Wa + 32 * IN_C;
    const float* Wb  = W2 + bb * (IN_C * IN_C);
    const float* ba  = b1 + bb * IN_C;
    const float* bb2 = b2 + bb * IN_C;

    float vdx = v_dna[dsafe * 3 + 0], vdy = v_dna[dsafe * 3 + 1], vdz = v_dna[dsafe * 3 + 2];
    float nix = dna_vec[dsafe * 3 + 0], niy = dna_vec[dsafe * 3 + 1], niz = dna_vec[dsafe * 3 + 2];

    float h1b[IN_C];
    #pragma unroll
    for (int c = 0; c < IN_C; ++c) h1b[c] = ba[c];
    {
        const float4* xd = reinterpret_cast<const float4*>(x_dna + (size_t)dsafe * IN_C);
        #pragma unroll
        for (int kk = 0; kk < 8; ++kk) {
            float4 xv = xd[kk];
            float fs[4] = {xv.x, xv.y, xv.z, xv.w};
            #pragma unroll
            for (int j = 0; j < 4; ++j)
                #pragma unroll
                for (int c = 0; c < IN_C; ++c)
                    h1b[c] = fmaf(fs[j], Wa[(36 + kk * 4 + j) * IN_C + c], h1b[c]);
        }
    }

    float acc[IN_C];
    #pragma unroll
    for (int c = 0; c < IN_C; ++c) acc[c] = 0.0f;

    for (int k = 0; k < n; ++k) {
        int src = pool_src[start + k];
        float vpx = v_prot[src * 3 + 0], vpy = v_prot[src * 3 + 1], vpz = v_prot[src * 3 + 2];
        float njx = prot_vec[src * 3 + 0], njy = prot_vec[src * 3 + 1], njz = prot_vec[src * 3 + 2];
        float dx = vpx - vdx, dy = vpy - vdy, dz = vpz - vdz;
        float pf0 = sqrtf(dx * dx + dy * dy + dz * dz);
        float pf1 = angf(nix, niy, niz, dx, dy, dz);
        float pf2 = angf(njx, njy, njz, dx, dy, dz);
        float pf3 = angf(nix, niy, niz, njx, njy, njz);

        float h2[IN_C];
        #pragma unroll
        for (int c = 0; c < IN_C; ++c) h2[c] = bb2[c];

        if constexpr (MODE == 1) {
            unsigned yw[16];
            const uint4* ypv = reinterpret_cast<const uint4*>(yp + ((size_t)bb * NP + src) * IN_C);
            uint4 y0 = ypv[0], y1 = ypv[1], y2 = ypv[2], y3 = ypv[3];
            *reinterpret_cast<uint4*>(&yw[0])  = y0;
            *reinterpret_cast<uint4*>(&yw[4])  = y1;
            *reinterpret_cast<uint4*>(&yw[8])  = y2;
            *reinterpret_cast<uint4*>(&yw[12]) = y3;
            #pragma unroll
            for (int k2 = 0; k2 < IN_C; ++k2) {
                unsigned w = yw[k2 >> 1];
                float ypf = (k2 & 1) ? bfhi(w) : bflo(w);
                float h1v = h1b[k2] + ypf;
                h1v = fmaf(pf0, Wp[0 * IN_C + k2], h1v);
                h1v = fmaf(pf1, Wp[1 * IN_C + k2], h1v);
                h1v = fmaf(pf2, Wp[2 * IN_C + k2], h1v);
                h1v = fmaf(pf3, Wp[3 * IN_C + k2], h1v);
                float f = fmaxf(h1v, 0.0f);
                #pragma unroll
                for (int c = 0; c < IN_C; ++c)
                    h2[c] = fmaf(f, Wb[k2 * IN_C + c], h2[c]);
            }
        } else {
            float pf[4] = {pf0, pf1, pf2, pf3};
            const float4* xp = reinterpret_cast<const float4*>(x_prot + (size_t)src * IN_C);
            #pragma unroll
            for (int hh = 0; hh < 2; ++hh) {
                float h1h[16];
                #pragma unroll
                for (int c = 0; c < 16; ++c) h1h[c] = h1b[hh * 16 + c];
                #pragma unroll
                for (int kk = 0; kk < 8; ++kk) {
                    float4 xv = xp[kk];
                    float fs[4] = {xv.x, xv.y, xv.z, xv.w};
                    #pragma unroll
                    for (int j = 0; j < 4; ++j)
                        #pragma unroll
                        for (int c = 0; c < 16; ++c)
                            h1h[c] = fmaf(fs[j], Wa[(kk * 4 + j) * IN_C + hh * 16 + c], h1h[c]);
                }
                #pragma unroll
                for (int j = 0; j < 4; ++j)
                    #pragma unroll
                    for (int c = 0; c < 16; ++c)
                        h1h[c] = fmaf(pf[j], Wp[j * IN_C + hh * 16 + c], h1h[c]);
                #pragma unroll
                for (int k2 = 0; k2 < 16; ++k2) {
                    float f = fmaxf(h1h[k2], 0.0f);
                    #pragma unroll
                    for (int c = 0; c < IN_C; ++c)
                        h2[c] = fmaf(f, Wb[(hh * 16 + k2) * IN_C + c], h2[c]);
                }
            }
        }

        #pragma unroll
        for (int c = 0; c < IN_C; ++c)
            acc[c] += fmaxf(h2[c], 0.0f);
    }

    #pragma unroll
    for (int c = 0; c < IN_C; ++c)
        acc[c] += __shfl_xor(acc[c], 1, 64);
    #pragma unroll
    for (int c = 0; c < IN_C; ++c)
        acc[c] += __shfl_xor(acc[c], 2, 64);

    if (valid && sub < 2) {
        float* p = (sub ? conv : out) + (size_t)dst * IN_C;
        float4* p4 = reinterpret_cast<float4*>(p);
        #pragma unroll
        for (int qq = 0; qq < 8; ++qq) {
            float4 v;
            v.x = acc[qq * 4 + 0]; v.y = acc[qq * 4 + 1];
            v.z = acc[qq * 4 + 2]; v.w = acc[qq * 4 + 3];
            p4[qq] = v;
        }
    }
}

__global__ __launch_bounds__(256) void k_edges_fallback(
    const float* __restrict__ x_dna, const float* __restrict__ v_dna,
    const float* __restrict__ x_prot, const float* __restrict__ v_prot,
    const float* __restrict__ prot_vec, const float* __restrict__ dna_vec,
    const int* __restrict__ esrc, const int* __restrict__ edst,
    const float* __restrict__ W1, const float* __restrict__ b1,
    const float* __restrict__ W2, const float* __restrict__ b2,
    int E, float* __restrict__ conv)
{
    int t = blockIdx.x * blockDim.x + threadIdx.x;
    if (t >= E) return;
    int src = esrc[t], dst = edst[t];
    int b = branch_of(dst % 11);
    const float* Wa  = W1 + b * (IN_F * IN_C);
    const float* Wb  = W2 + b * (IN_C * IN_C);
    const float* ba  = b1 + b * IN_C;
    const float* bb2 = b2 + b * IN_C;

    float vdx = v_dna[dst * 3 + 0], vdy = v_dna[dst * 3 + 1], vdz = v_dna[dst * 3 + 2];
    float vpx = v_prot[src * 3 + 0], vpy = v_prot[src * 3 + 1], vpz = v_prot[src * 3 + 2];
    float nix = dna_vec[dst * 3 + 0], niy = dna_vec[dst * 3 + 1], niz = dna_vec[dst * 3 + 2];
    float njx = prot_vec[src * 3 + 0], njy = prot_vec[src * 3 + 1], njz = prot_vec[src * 3 + 2];
    float dx = vpx - vdx, dy = vpy - vdy, dz = vpz - vdz;
    float pf[4];
    pf[0] = sqrtf(dx * dx + dy * dy + dz * dz);
    pf[1] = angf(nix, niy, niz, dx, dy, dz);
    pf[2] = angf(njx, njy, njz, dx, dy, dz);
    pf[3] = angf(nix, niy, niz, njx, njy, njz);

    float h1[IN_C];
    #pragma unroll
    for (int c = 0; c < IN_C; ++c) h1[c] = ba[c];
    const float4* xp = reinterpret_cast<const float4*>(x_prot + (size_t)src * IN_C);
    #pragma unroll
    for (int kk = 0; kk < 8; ++kk) {
        float4 xv = xp[kk];
        float fs[4] = {xv.x, xv.y, xv.z, xv.w};
        #pragma unroll
        for (int j = 0; j < 4; ++j)
            #pragma unroll
            for (int c = 0; c < IN_C; ++c)
                h1[c] = fmaf(fs[j], Wa[(kk * 4 + j) * IN_C + c], h1[c]);
    }
    #pragma unroll
    for (int j = 0; j < 4; ++j)
        #pragma unroll
        for (int c = 0; c < IN_C; ++c)
            h1[c] = fmaf(pf[j], Wa[(32 + j) * IN_C + c], h1[c]);
    const float4* xd = reinterpret_cast<const float4*>(x_dna + (size_t)dst * IN_C);
    #pragma unroll
    for (int kk = 0; kk < 8; ++kk) {
        float4 xv = xd[kk];
        float fs[4] = {xv.x, xv.y, xv.z, xv.w};
        #pragma unroll
        for (int j = 0; j < 4; ++j)
            #pragma unroll
            for (int c = 0; c < IN_C; ++c)
                h1[c] = fmaf(fs[j], Wa[(36 + kk * 4 + j) * IN_C + c], h1[c]);
    }
    float h2[IN_C];
    #pragma unroll
    for (int c = 0; c < IN_C; ++c) h2[c] = bb2[c];
    #pragma unroll
    for (int k = 0; k < IN_C; ++k) {
        float f = fmaxf(h1[k], 0.0f);
        #pragma unroll
        for (int c = 0; c < IN_C; ++c)
            h2[c] = fmaf(f, Wb[k * IN_C + c], h2[c]);
    }
    float* cv = conv + (size_t)dst * IN_C;
    #pragma unroll
    for (int c = 0; c < IN_C; ++c)
        atomicAdd(&cv[c], fmaxf(h2[c], 0.0f));
}

extern "C" void kernel_launch(void* const* d_in, const int* in_sizes, int n_in,
                              void* d_out, int out_size, void* d_ws, size_t ws_size,
                              hipStream_t stream) {
    const float* x_dna    = (const float*)d_in[0];
    const float* v_dna    = (const float*)d_in[1];
    const float* x_prot   = (const float*)d_in[2];
    const float* v_prot   = (const float*)d_in[3];
    const float* prot_vec = (const float*)d_in[4];
    const float* dna_vec  = (const float*)d_in[5];
    const int*   esrc     = (const int*)d_in[6];
    const int*   edst     = (const int*)d_in[7];
    const float* W1       = (const float*)d_in[8];
    const float* b1       = (const float*)d_in[9];
    const float* W2       = (const float*)d_in[10];
    const float* b2       = (const float*)d_in[11];

    const int E  = in_sizes[6];
    const int ND = in_sizes[0] / IN_C;       // N_DNA
    const int NP = in_sizes[2] / IN_C;       // N_PROT
    const int half = out_size / 2;
    float* out  = (float*)d_out;
    float* conv = out + half;

    const int NDp = (ND + 160 + 31) & ~31;   // padded, 32-aligned
    const int nblk_scan = (NDp + 1023) / 1024;
    const int eb = (E + 255) / 256;

    const size_t base_ints = (size_t)ND + 256 + 256 + 8 + ND + NDp + E;
    const size_t ws_base   = base_ints * sizeof(int);
    const size_t yp_off    = (ws_base + 255) & ~(size_t)255;
    const size_t yp_bytes  = (size_t)NP * 4 * IN_C * sizeof(unsigned short);
    const size_t yd_off    = yp_off + yp_bytes;
    const size_t yd_bytes  = (size_t)ND * IN_C * sizeof(unsigned short);

    if (ND == half / IN_C && ws_size >= ws_base && nblk_scan <= 256) {
        int* counts     = (int*)d_ws;          // ND
        int* hist       = counts + ND;         // 256 (contiguous with counts)
        int* blk        = hist + 256;          // 256
        int* pbs        = blk + 256;           // 8
        int* rowcur     = pbs + 8;             // ND
        int* node_order = rowcur + ND;         // NDp
        int* pool_src   = node_order + NDp;    // E
        unsigned short* yp = (unsigned short*)((char*)d_ws + yp_off);
        unsigned short* yd = (unsigned short*)((char*)d_ws + yd_off);

        int mode = 0;
        if (ws_size >= yd_off + yd_bytes && ND % 11 == 0) mode = 2;
        else if (ws_size >= yp_off + yp_bytes)            mode = 1;

        hipMemsetAsync(counts, 0, ((size_t)ND + 256) * sizeof(int), stream);

        k_count<<<eb, 256, 0, stream>>>(edst, E, counts);
        k_scan1<<<nblk_scan, 1024, 0, stream>>>(counts, ND, NDp, rowcur, blk,
                                                hist, node_order);
        k_scan2<<<1, 256, 0, stream>>>(blk, nblk_scan);
        k_scan3<<<nblk_scan, 1024, 0, stream>>>(rowcur, blk, ND);
        k_fill<<<eb, 256, 0, stream>>>(esrc, edst, E, rowcur, pool_src);
        k_padscan2<<<1, 256, 0, stream>>>(hist, pbs);
        k_assign<<<(ND + 255) / 256, 256, 0, stream>>>(counts, ND, hist, node_order);

        int NPpad = (NP + 63) & ~63;
        int NB = ND / 11;
        int NBpad = (NB + 63) & ~63;
        if (mode >= 1) {
            int tot = 4 * NPpad + (mode == 2 ? 11 * NBpad : 0);
            k_precomp<<<(tot + 255) / 256, 256, 0, stream>>>(
                x_prot, x_dna, W1, b1, NP, NPpad, NB, NBpad, mode == 2, yp, yd);
        }

        if (mode == 2) {
            int nbm = (2 * NDp + 255) / 256;
            k_mfma<<<nbm, 256, 0, stream>>>(
                v_dna, v_prot, prot_vec, dna_vec, W1, W2, b2,
                node_order, rowcur, counts, pool_src, pbs,
                yp, yd, NP, out, conv, NDp);
        } else if (mode == 1) {
            int nb4 = (4 * NDp + 255) / 256;
            k_nodes4<1><<<nb4, 256, 0, stream>>>(
                x_dna, v_dna, x_prot, v_prot, prot_vec, dna_vec,
                W1, b1, W2, b2, node_order, rowcur, counts, pool_src, pbs,
                yp, NP, out, conv, NDp);
        } else {
            int nb4 = (4 * NDp + 255) / 256;
            k_nodes4<0><<<nb4, 256, 0, stream>>>(
                x_dna, v_dna, x_prot, v_prot, prot_vec, dna_vec,
                W1, b1, W2, b2, node_order, rowcur, counts, pool_src, pbs,
                nullptr, NP, out, conv, NDp);
        }
    } else {
        hipMemsetAsync(conv, 0, (size_t)half * sizeof(float), stream);
        k_edges_fallback<<<eb, 256, 0, stream>>>(
            x_dna, v_dna, x_prot, v_prot, prot_vec, dna_vec,
            esrc, edst, W1, b1, W2, b2, E, conv);
        hipMemcpyAsync(out, conv, (size_t)half * sizeof(float),
                       hipMemcpyDeviceToDevice, stream);
    }
}

// Round 10
// 290.538 us; speedup vs baseline: 20.6561x; 1.2051x over previous
//
#include <hip/hip_runtime.h>

// ---------------------------------------------------------------------------
// BiNet R10 = R9 (MFMA layer-2, count-sorted nodes, yp/yd precompute) with the
// CSR fill rebuilt as a two-pass bucketed scatter:
//   R9's k_fill: random 4B scatter -> 96MB dirty-line footprint -> 103MB HBM
//   write-through (measured), 118us.
//   passA: LDS tile-sort multisplit into 430 buckets (512 dst each); records
//     packed to 4B (dst%512<<17 | src); contiguous run writes per bin.
//   passB: block-per-bucket exact placement; scatter stays inside the 14KB
//     L2-resident bucket region -> lines fully dirtied -> ~6MB HBM writes.
//   stage (6MB) overlays the yp region (consumed before k_precomp writes yp).
// ---------------------------------------------------------------------------

#define IN_C 32
#define IN_F 68
#define TILE_A 4096
#define BK_SHIFT 9
#define NBKT_MAX 448

using bf16x8v = __attribute__((ext_vector_type(8))) short;
using f32x16v = __attribute__((ext_vector_type(16))) float;

union U4F { unsigned u[4]; bf16x8v v; };

__device__ __forceinline__ unsigned cvtpk_bf16(float a, float b) {
    unsigned r;
    asm("v_cvt_pk_bf16_f32 %0, %1, %2" : "=v"(r) : "v"(a), "v"(b));
    return r;
}
__device__ __forceinline__ float bflo(unsigned u) { return __uint_as_float(u << 16); }
__device__ __forceinline__ float bfhi(unsigned u) { return __uint_as_float(u & 0xffff0000u); }

__device__ __forceinline__ float angf(float ax, float ay, float az,
                                      float bx, float by, float bz) {
    float cx = ay * bz - az * by;
    float cy = az * bx - ax * bz;
    float cz = ax * by - ay * bx;
    float cn = sqrtf(cx * cx + cy * cy + cz * cz);
    float dt = ax * bx + ay * by + az * bz;
    return atan2f(cn, dt);
}

__device__ __forceinline__ int branch_of(int m) {
    if (m == 0 || m == 10) return 0;
    if (m == 1 || m == 9)  return 1;
    if (m >= 2 && m <= 5)  return 2;
    return 3;
}

__device__ __forceinline__ unsigned bf16r(float f) {
    unsigned u = __float_as_uint(f);
    return (u + 0x7fffu + ((u >> 16) & 1u)) >> 16;
}

// --- CSR build ----------------------------------------------------------------
__global__ void k_count(const int* __restrict__ edst, int E, int* counts) {
    int t = blockIdx.x * blockDim.x + threadIdx.x;
    if (t >= E) return;
    atomicAdd(&counts[edst[t]], 1);
}

__global__ __launch_bounds__(1024) void k_scan1(const int* __restrict__ counts,
                                                int NN, int NDp, int* cursor,
                                                int* blk, int* hist,
                                                int* node_order) {
    __shared__ int wsum[16];
    __shared__ int lh[256];
    if (threadIdx.x < 256) lh[threadIdx.x] = 0;
    __syncthreads();
    int t = blockIdx.x * 1024 + threadIdx.x;
    int lane = threadIdx.x & 63;
    int wid = threadIdx.x >> 6;
    int c = (t < NN) ? counts[t] : 0;
    if (t < NN) {
        int g = branch_of(t % 11);
        int cc = c > 63 ? 63 : c;
        atomicAdd(&lh[g * 64 + (63 - cc)], 1);
    }
    if (t < NDp) node_order[t] = -1;
    int inc = c;
    #pragma unroll
    for (int d = 1; d < 64; d <<= 1) {
        int v = __shfl_up(inc, d, 64);
        if (lane >= d) inc += v;
    }
    if (lane == 63) wsum[wid] = inc;
    __syncthreads();
    if (threadIdx.x < 16) {
        int v = wsum[threadIdx.x];
        int wi = v;
        #pragma unroll
        for (int d = 1; d < 16; d <<= 1) {
            int u = __shfl_up(wi, d, 64);
            if (threadIdx.x >= d) wi += u;
        }
        wsum[threadIdx.x] = wi - v;
        if (threadIdx.x == 15) blk[blockIdx.x] = wi;
    }
    __syncthreads();
    if (t < NN) cursor[t] = inc - c + wsum[wid];
    if (threadIdx.x < 256 && lh[threadIdx.x])
        atomicAdd(&hist[threadIdx.x], lh[threadIdx.x]);
}

__global__ __launch_bounds__(256) void k_scan2(int* blk, int nblk) {
    __shared__ int wsum[4];
    int lane = threadIdx.x & 63;
    int wid = threadIdx.x >> 6;
    int v = (threadIdx.x < nblk) ? blk[threadIdx.x] : 0;
    int inc = v;
    #pragma unroll
    for (int d = 1; d < 64; d <<= 1) {
        int u = __shfl_up(inc, d, 64);
        if (lane >= d) inc += u;
    }
    if (lane == 63) wsum[wid] = inc;
    __syncthreads();
    if (threadIdx.x < 4) {
        int w = wsum[threadIdx.x];
        int wi = w;
        #pragma unroll
        for (int d = 1; d < 4; d <<= 1) {
            int u = __shfl_up(wi, d, 64);
            if (threadIdx.x >= d) wi += u;
        }
        wsum[threadIdx.x] = wi - w;
    }
    __syncthreads();
    if (threadIdx.x < nblk) blk[threadIdx.x] = inc - v + wsum[wid];
}

__global__ __launch_bounds__(1024) void k_scan3(int* cursor, const int* blk, int NN) {
    int t = blockIdx.x * 1024 + threadIdx.x;
    if (t >= NN) return;
    cursor[t] += blk[blockIdx.x];
}

// old single-pass fill (fallback path)
__global__ void k_fill(const int* __restrict__ esrc, const int* __restrict__ edst,
                       int E, int* cursor, int* __restrict__ pool_src) {
    int t = blockIdx.x * blockDim.x + threadIdx.x;
    if (t >= E) return;
    int pos = atomicAdd(&cursor[edst[t]], 1);
    pool_src[pos] = esrc[t];
}

// --- two-pass bucketed fill -----------------------------------------------------
__global__ __launch_bounds__(512) void k_binit(const int* __restrict__ rowstart,
                                               int ND, int nbkt, int E,
                                               int* gbase, int* gcur) {
    int b = threadIdx.x;
    if (b <= nbkt) {
        int node = b << BK_SHIFT;
        int v = (node < ND) ? rowstart[node] : E;
        gbase[b] = v;
        if (b < nbkt) gcur[b] = v;
    }
}

__global__ __launch_bounds__(256) void k_passA(
    const int* __restrict__ esrc, const int* __restrict__ edst, int E,
    int nbkt, int* __restrict__ gcur, unsigned* __restrict__ stage)
{
    __shared__ unsigned rec[TILE_A];
    __shared__ unsigned short bkt[TILE_A];
    __shared__ int hist[NBKT_MAX];
    __shared__ int hscan[NBKT_MAX];
    __shared__ int cnt[NBKT_MAX];
    __shared__ int gpos[NBKT_MAX];
    __shared__ int chbase[8];

    int base = blockIdx.x * TILE_A;
    int n = E - base; if (n > TILE_A) n = TILE_A;
    if (n <= 0) return;

    for (int i = threadIdx.x; i < nbkt; i += 256) hist[i] = 0;
    __syncthreads();

    unsigned myrec[16];
    int mybkt[16];
    #pragma unroll
    for (int k = 0; k < 16; ++k) {
        int i = threadIdx.x + k * 256;
        mybkt[k] = -1;
        if (i < n) {
            int s = esrc[base + i];
            int d = edst[base + i];
            int b = d >> BK_SHIFT;
            myrec[k] = ((unsigned)(d & ((1 << BK_SHIFT) - 1)) << 17) | (unsigned)s;
            mybkt[k] = b;
            atomicAdd(&hist[b], 1);
        }
    }
    __syncthreads();

    // exclusive scan hist -> hscan (64-chunks, wave scans)
    {
        int lane = threadIdx.x & 63, w = threadIdx.x >> 6;
        int nch = (nbkt + 63) >> 6;
        for (int ch = w; ch < nch; ch += 4) {
            int idx = (ch << 6) + lane;
            int v = (idx < nbkt) ? hist[idx] : 0;
            int inc = v;
            #pragma unroll
            for (int d = 1; d < 64; d <<= 1) {
                int u = __shfl_up(inc, d, 64);
                if (lane >= d) inc += u;
            }
            if (idx < nbkt) hscan[idx] = inc - v;
            if (lane == 63) chbase[ch] = inc;
        }
        __syncthreads();
        if (threadIdx.x == 0) {
            int s = 0;
            for (int ch = 0; ch < nch; ++ch) { int t2 = chbase[ch]; chbase[ch] = s; s += t2; }
        }
        __syncthreads();
        for (int i = threadIdx.x; i < nbkt; i += 256) {
            int v = hscan[i] + chbase[i >> 6];
            hscan[i] = v;
            cnt[i] = v;
        }
    }
    // reserve global space per bin (one atomic per nonzero bin per tile)
    for (int b2 = threadIdx.x; b2 < nbkt; b2 += 256) {
        int c = hist[b2];
        if (c > 0) gpos[b2] = atomicAdd(&gcur[b2], c);
    }
    __syncthreads();

    // rank + scatter into LDS bucket-sorted order
    #pragma unroll
    for (int k = 0; k < 16; ++k) {
        if (mybkt[k] >= 0) {
            int p = atomicAdd(&cnt[mybkt[k]], 1);
            rec[p] = myrec[k];
            bkt[p] = (unsigned short)mybkt[k];
        }
    }
    __syncthreads();

    // write out: contiguous run per bin
    for (int i = threadIdx.x; i < n; i += 256) {
        int b2 = bkt[i];
        stage[gpos[b2] + (i - hscan[b2])] = rec[i];
    }
}

__global__ __launch_bounds__(256) void k_passB(
    const unsigned* __restrict__ stage, const int* __restrict__ gbase,
    int* cursor, int* __restrict__ pool_src)
{
    int b = blockIdx.x;
    int s0 = gbase[b], s1 = gbase[b + 1];
    int dbase = b << BK_SHIFT;
    for (int i = s0 + threadIdx.x; i < s1; i += 256) {
        unsigned r = stage[i];
        int src = (int)(r & 0x1FFFFu);
        int dst = dbase + (int)(r >> 17);
        int pos = atomicAdd(&cursor[dst], 1);
        pool_src[pos] = src;
    }
}

__global__ __launch_bounds__(256) void k_padscan2(int* hist, int* pbs) {
    __shared__ int gsum[4];
    __shared__ int gbase[5];
    int lane = threadIdx.x & 63;
    int w = threadIdx.x >> 6;
    int v = hist[threadIdx.x];
    int inc = v;
    #pragma unroll
    for (int d = 1; d < 64; d <<= 1) {
        int u = __shfl_up(inc, d, 64);
        if (lane >= d) inc += u;
    }
    if (lane == 63) gsum[w] = inc;
    __syncthreads();
    if (threadIdx.x == 0) {
        int base = 0;
        #pragma unroll
        for (int g = 0; g < 4; ++g) {
            gbase[g] = base;
            base = (base + gsum[g] + 31) & ~31;   // 32-node aligned group base
        }
        gbase[4] = base;
    }
    __syncthreads();
    hist[threadIdx.x] = gbase[w] + inc - v;
    if (threadIdx.x < 5) pbs[threadIdx.x] = gbase[threadIdx.x];
}

__global__ __launch_bounds__(256) void k_assign(const int* __restrict__ counts,
                                                int ND, int* cur,
                                                int* __restrict__ node_order) {
    __shared__ int lh[256];
    __shared__ int lbase[256];
    lh[threadIdx.x] = 0;
    __syncthreads();
    int t = blockIdx.x * 256 + threadIdx.x;
    bool v = (t < ND);
    int bin = 0, rank = 0;
    if (v) {
        int g = branch_of(t % 11);
        int c = counts[t]; c = c > 63 ? 63 : c;
        bin = g * 64 + (63 - c);
        rank = atomicAdd(&lh[bin], 1);
    }
    __syncthreads();
    int cnt = lh[threadIdx.x];
    if (cnt > 0) lbase[threadIdx.x] = atomicAdd(&cur[threadIdx.x], cnt);
    __syncthreads();
    if (v) node_order[lbase[bin] + rank] = t;
}

// --- fused precompute ------------------------------------------------------------
__global__ __launch_bounds__(256) void k_precomp(
    const float* __restrict__ x_prot, const float* __restrict__ x_dna,
    const float* __restrict__ W1, const float* __restrict__ b1,
    int NP, int NPpad, int NB, int NBpad, int do_dna,
    unsigned short* __restrict__ yp, unsigned short* __restrict__ yd)
{
    int t = blockIdx.x * 256 + threadIdx.x;
    int NP4 = 4 * NPpad;
    float h[IN_C];
    unsigned short* dstp;

    if (t < NP4) {
        int g = t / NPpad;
        int p = t - g * NPpad;
        if (p >= NP) return;
        int bb = __builtin_amdgcn_readfirstlane(g);
        const float* Wa = W1 + bb * (IN_F * IN_C);
        #pragma unroll
        for (int c = 0; c < IN_C; ++c) h[c] = 0.0f;
        const float4* xp = reinterpret_cast<const float4*>(x_prot + (size_t)p * IN_C);
        #pragma unroll
        for (int kk = 0; kk < 8; ++kk) {
            float4 xv = xp[kk];
            float fs[4] = {xv.x, xv.y, xv.z, xv.w};
            #pragma unroll
            for (int j = 0; j < 4; ++j)
                #pragma unroll
                for (int c = 0; c < IN_C; ++c)
                    h[c] = fmaf(fs[j], Wa[(kk * 4 + j) * IN_C + c], h[c]);
        }
        dstp = yp + ((size_t)bb * NP + p) * IN_C;
    } else {
        if (!do_dna) return;
        int t2 = t - NP4;
        int q = t2 / NBpad;
        if (q >= 11) return;
        int idx = t2 - q * NBpad;
        if (idx >= NB) return;
        int g, m;
        if (q < 2)      { g = 0; m = q ? 10 : 0; }
        else if (q < 4) { g = 1; m = (q == 2) ? 1 : 9; }
        else if (q < 8) { g = 2; m = 2 + (q - 4); }
        else            { g = 3; m = 6 + (q - 8); }
        int bb = __builtin_amdgcn_readfirstlane(g);
        int dn = idx * 11 + m;
        const float* Wa = W1 + bb * (IN_F * IN_C);
        const float* ba = b1 + bb * IN_C;
        #pragma unroll
        for (int c = 0; c < IN_C; ++c) h[c] = ba[c];
        const float4* xd = reinterpret_cast<const float4*>(x_dna + (size_t)dn * IN_C);
        #pragma unroll
        for (int kk = 0; kk < 8; ++kk) {
            float4 xv = xd[kk];
            float fs[4] = {xv.x, xv.y, xv.z, xv.w};
            #pragma unroll
            for (int j = 0; j < 4; ++j)
                #pragma unroll
                for (int c = 0; c < IN_C; ++c)
                    h[c] = fmaf(fs[j], Wa[(36 + kk * 4 + j) * IN_C + c], h[c]);
        }
        dstp = yd + (size_t)dn * IN_C;
    }

    unsigned yw[16];
    #pragma unroll
    for (int j = 0; j < 16; ++j)
        yw[j] = bf16r(h[2 * j]) | (bf16r(h[2 * j + 1]) << 16);
    uint4* d4 = reinterpret_cast<uint4*>(dstp);
    d4[0] = make_uint4(yw[0], yw[1], yw[2], yw[3]);
    d4[1] = make_uint4(yw[4], yw[5], yw[6], yw[7]);
    d4[2] = make_uint4(yw[8], yw[9], yw[10], yw[11]);
    d4[3] = make_uint4(yw[12], yw[13], yw[14], yw[15]);
}

// --- MFMA main kernel: 32 nodes/wave, 2 slots/node (unchanged from R9) ----------
__global__ __launch_bounds__(256) void k_mfma(
    const float* __restrict__ v_dna, const float* __restrict__ v_prot,
    const float* __restrict__ prot_vec, const float* __restrict__ dna_vec,
    const float* __restrict__ W1, const float* __restrict__ W2,
    const float* __restrict__ b2,
    const int* __restrict__ node_order, const int* __restrict__ rowend,
    const int* __restrict__ counts, const int* __restrict__ pool_src,
    const int* __restrict__ pbs,
    const unsigned short* __restrict__ yp, const unsigned short* __restrict__ yd,
    int NP, float* __restrict__ out, float* __restrict__ conv, int NDp)
{
    int t = blockIdx.x * 256 + threadIdx.x;
    int lane = threadIdx.x & 63;
    int hi = lane >> 5;
    int col = lane & 31;
    int pid = t >> 1;
    int sub = t & 1;

    int pb1 = pbs[1], pb2v = pbs[2], pb3 = pbs[3];
    int g = (pid >= pb1) + (pid >= pb2v) + (pid >= pb3);
    int bb = __builtin_amdgcn_readfirstlane(g);

    int dst = (pid < NDp) ? node_order[pid] : -1;
    bool vnode = (dst >= 0);
    int dsafe = vnode ? dst : 0;
    int n_all = vnode ? counts[dsafe] : 0;
    int start = vnode ? (rowend[dsafe] - n_all) : 0;

    const float* Wp = W1 + bb * (IN_F * IN_C) + 32 * IN_C;
    const float* Wb = W2 + bb * (IN_C * IN_C);
    float b2c = b2[bb * IN_C + col];

    U4F B0u, B1u;
    #pragma unroll
    for (int j = 0; j < 4; ++j) {
        int k0 = hi * 8 + 2 * j;
        B0u.u[j] = cvtpk_bf16(Wb[k0 * IN_C + col],        Wb[(k0 + 1) * IN_C + col]);
        B1u.u[j] = cvtpk_bf16(Wb[(16 + k0) * IN_C + col], Wb[(17 + k0) * IN_C + col]);
    }

    float vdx = v_dna[dsafe * 3 + 0], vdy = v_dna[dsafe * 3 + 1], vdz = v_dna[dsafe * 3 + 2];
    float nix = dna_vec[dsafe * 3 + 0], niy = dna_vec[dsafe * 3 + 1], niz = dna_vec[dsafe * 3 + 2];

    unsigned ydw[16];
    {
        const uint4* ydv = reinterpret_cast<const uint4*>(yd + (size_t)dsafe * IN_C);
        uint4 w0 = ydv[0], w1 = ydv[1], w2 = ydv[2], w3 = ydv[3];
        *reinterpret_cast<uint4*>(&ydw[0])  = w0;
        *reinterpret_cast<uint4*>(&ydw[4])  = w1;
        *reinterpret_cast<uint4*>(&ydw[8])  = w2;
        *reinterpret_cast<uint4*>(&ydw[12]) = w3;
    }

    float acc[16];
    #pragma unroll
    for (int i = 0; i < 16; ++i) acc[i] = 0.0f;

    int niter = (n_all + 1) >> 1;
    #pragma unroll
    for (int d = 1; d < 64; d <<= 1) {
        int o = __shfl_xor(niter, d, 64);
        niter = niter > o ? niter : o;
    }

    for (int it = 0; it < niter; ++it) {
        int eidx = 2 * it + sub;
        bool valid = vnode && (eidx < n_all);
        unsigned long long vm = __ballot(valid);
        int off = valid ? (start + eidx) : 0;
        int src = pool_src[off];

        float vpx = v_prot[src * 3 + 0], vpy = v_prot[src * 3 + 1], vpz = v_prot[src * 3 + 2];
        float njx = prot_vec[src * 3 + 0], njy = prot_vec[src * 3 + 1], njz = prot_vec[src * 3 + 2];

        unsigned yw[16];
        {
            const uint4* ypv = reinterpret_cast<const uint4*>(yp + ((size_t)bb * NP + src) * IN_C);
            uint4 y0 = ypv[0], y1 = ypv[1], y2 = ypv[2], y3 = ypv[3];
            *reinterpret_cast<uint4*>(&yw[0])  = y0;
            *reinterpret_cast<uint4*>(&yw[4])  = y1;
            *reinterpret_cast<uint4*>(&yw[8])  = y2;
            *reinterpret_cast<uint4*>(&yw[12]) = y3;
        }

        float dx = vpx - vdx, dy = vpy - vdy, dz = vpz - vdz;
        float pf0 = sqrtf(dx * dx + dy * dy + dz * dz);
        float pf1 = angf(nix, niy, niz, dx, dy, dz);
        float pf2 = angf(njx, njy, njz, dx, dy, dz);
        float pf3 = angf(nix, niy, niz, njx, njy, njz);

        unsigned p[16];
        #pragma unroll
        for (int j = 0; j < 16; ++j) {
            int c0 = 2 * j, c1 = 2 * j + 1;
            float a0 = bflo(ydw[j]) + bflo(yw[j]);
            float a1 = bfhi(ydw[j]) + bfhi(yw[j]);
            a0 = fmaf(pf0, Wp[0 * IN_C + c0], a0);
            a0 = fmaf(pf1, Wp[1 * IN_C + c0], a0);
            a0 = fmaf(pf2, Wp[2 * IN_C + c0], a0);
            a0 = fmaf(pf3, Wp[3 * IN_C + c0], a0);
            a1 = fmaf(pf0, Wp[0 * IN_C + c1], a1);
            a1 = fmaf(pf1, Wp[1 * IN_C + c1], a1);
            a1 = fmaf(pf2, Wp[2 * IN_C + c1], a1);
            a1 = fmaf(pf3, Wp[3 * IN_C + c1], a1);
            a0 = fmaxf(a0, 0.0f);
            a1 = fmaxf(a1, 0.0f);
            p[j] = cvtpk_bf16(a0, a1);
        }

        unsigned q[16];
        #pragma unroll
        for (int j = 0; j < 16; ++j)
            q[j] = (unsigned)__shfl_xor((int)p[j], 32, 64);

        U4F a00, a01, a10, a11;
        #pragma unroll
        for (int d2 = 0; d2 < 4; ++d2) {
            a00.u[d2] = hi ? q[4 + d2]  : p[d2];
            a01.u[d2] = hi ? q[12 + d2] : p[8 + d2];
            a10.u[d2] = hi ? p[4 + d2]  : q[d2];
            a11.u[d2] = hi ? p[12 + d2] : q[8 + d2];
        }

        unsigned long long vms = vm >> (4 * hi);

        {
            f32x16v D;
            #pragma unroll
            for (int r = 0; r < 16; ++r) D[r] = 0.0f;
            D = __builtin_amdgcn_mfma_f32_32x32x16_bf16(a00.v, B0u.v, D, 0, 0, 0);
            D = __builtin_amdgcn_mfma_f32_32x32x16_bf16(a01.v, B1u.v, D, 0, 0, 0);
            #pragma unroll
            for (int r = 0; r < 16; ++r) {
                int sh = (r & 3) + 8 * (r >> 2);
                float val = fmaxf(D[r] + b2c, 0.0f);
                bool ok = (vms >> sh) & 1ull;
                int ai = 2 * (r >> 2) + ((r & 3) >> 1);
                acc[ai] += ok ? val : 0.0f;
            }
        }
        {
            f32x16v D;
            #pragma unroll
            for (int r = 0; r < 16; ++r) D[r] = 0.0f;
            D = __builtin_amdgcn_mfma_f32_32x32x16_bf16(a10.v, B0u.v, D, 0, 0, 0);
            D = __builtin_amdgcn_mfma_f32_32x32x16_bf16(a11.v, B1u.v, D, 0, 0, 0);
            #pragma unroll
            for (int r = 0; r < 16; ++r) {
                int sh = 32 + (r & 3) + 8 * (r >> 2);
                float val = fmaxf(D[r] + b2c, 0.0f);
                bool ok = (vms >> sh) & 1ull;
                int ai = 8 + 2 * (r >> 2) + ((r & 3) >> 1);
                acc[ai] += ok ? val : 0.0f;
            }
        }
    }

    #pragma unroll
    for (int i = 0; i < 16; ++i) {
        int rb = i >> 3, rem = i & 7;
        int q2 = rem >> 1, u = rem & 1;
        int m = 16 * rb + 4 * q2 + 2 * hi + u;
        int dm = __shfl(dst, 2 * m, 64);
        if (dm >= 0) {
            out[(size_t)dm * IN_C + col]  = acc[i];
            conv[(size_t)dm * IN_C + col] = acc[i];
        }
    }
}

// --- non-MFMA fallbacks (unchanged) ----------------------------------------------
template <int MODE>
__global__ __launch_bounds__(256) void k_nodes4(
    const float* __restrict__ x_dna, const float* __restrict__ v_dna,
    const float* __restrict__ x_prot, const float* __restrict__ v_prot,
    const float* __restrict__ prot_vec, const float* __restrict__ dna_vec,
    const float* __restrict__ W1, const float* __restrict__ b1,
    const float* __restrict__ W2, const float* __restrict__ b2,
    const int* __restrict__ node_order, const int* __restrict__ rowend,
    const int* __restrict__ counts, const int* __restrict__ pool_src,
    const int* __restrict__ pbs,
    const unsigned short* __restrict__ yp,
    int NP, float* __restrict__ out, float* __restrict__ conv, int NDp)
{
    int t = blockIdx.x * 256 + threadIdx.x;
    int pid = t >> 2;
    int sub = t & 3;
    if (pid >= NDp) return;

    int pb1 = pbs[1], pb2 = pbs[2], pb3 = pbs[3];
    int g = (pid >= pb1) + (pid >= pb2) + (pid >= pb3);
    int bb = __builtin_amdgcn_readfirstlane(g);

    int dst = node_order[pid];
    bool valid = (dst >= 0);
    int dsafe = valid ? dst : 0;

    int n_all = valid ? counts[dsafe] : 0;
    int start_all = valid ? (rowend[dsafe] - n_all) : 0;
    int nb4 = n_all >> 2, rem = n_all & 3;
    int n = nb4 + (sub < rem ? 1 : 0);
    int start = start_all + sub * nb4 + (sub < rem ? sub : rem);

    const float* Wa  = W1 + bb * (IN_F * IN_C);
    const float* Wp  = Wa + 32 * IN_C;
    const float* Wb  = W2 + bb * (IN_C * IN_C);
    const float* ba  = b1 + bb * IN_C;
    const float* bb2 = b2 + bb * IN_C;

    float vdx = v_dna[dsafe * 3 + 0], vdy = v_dna[dsafe * 3 + 1], vdz = v_dna[dsafe * 3 + 2];
    float nix = dna_vec[dsafe * 3 + 0], niy = dna_vec[dsafe * 3 + 1], niz = dna_vec[dsafe * 3 + 2];

    float h1b[IN_C];
    #pragma unroll
    for (int c = 0; c < IN_C; ++c) h1b[c] = ba[c];
    {
        const float4* xd = reinterpret_cast<const float4*>(x_dna + (size_t)dsafe * IN_C);
        #pragma unroll
        for (int kk = 0; kk < 8; ++kk) {
            float4 xv = xd[kk];
            float fs[4] = {xv.x, xv.y, xv.z, xv.w};
            #pragma unroll
            for (int j = 0; j < 4; ++j)
                #pragma unroll
                for (int c = 0; c < IN_C; ++c)
                    h1b[c] = fmaf(fs[j], Wa[(36 + kk * 4 + j) * IN_C + c], h1b[c]);
        }
    }

    float acc[IN_C];
    #pragma unroll
    for (int c = 0; c < IN_C; ++c) acc[c] = 0.0f;

    for (int k = 0; k < n; ++k) {
        int src = pool_src[start + k];
        float vpx = v_prot[src * 3 + 0], vpy = v_prot[src * 3 + 1], vpz = v_prot[src * 3 + 2];
        float njx = prot_vec[src * 3 + 0], njy = prot_vec[src * 3 + 1], njz = prot_vec[src * 3 + 2];
        float dx = vpx - vdx, dy = vpy - vdy, dz = vpz - vdz;
        float pf0 = sqrtf(dx * dx + dy * dy + dz * dz);
        float pf1 = angf(nix, niy, niz, dx, dy, dz);
        float pf2 = angf(njx, njy, njz, dx, dy, dz);
        float pf3 = angf(nix, niy, niz, njx, njy, njz);

        float h2[IN_C];
        #pragma unroll
        for (int c = 0; c < IN_C; ++c) h2[c] = bb2[c];

        if constexpr (MODE == 1) {
            unsigned yw[16];
            const uint4* ypv = reinterpret_cast<const uint4*>(yp + ((size_t)bb * NP + src) * IN_C);
            uint4 y0 = ypv[0], y1 = ypv[1], y2 = ypv[2], y3 = ypv[3];
            *reinterpret_cast<uint4*>(&yw[0])  = y0;
            *reinterpret_cast<uint4*>(&yw[4])  = y1;
            *reinterpret_cast<uint4*>(&yw[8])  = y2;
            *reinterpret_cast<uint4*>(&yw[12]) = y3;
            #pragma unroll
            for (int k2 = 0; k2 < IN_C; ++k2) {
                unsigned w = yw[k2 >> 1];
                float ypf = (k2 & 1) ? bfhi(w) : bflo(w);
                float h1v = h1b[k2] + ypf;
                h1v = fmaf(pf0, Wp[0 * IN_C + k2], h1v);
                h1v = fmaf(pf1, Wp[1 * IN_C + k2], h1v);
                h1v = fmaf(pf2, Wp[2 * IN_C + k2], h1v);
                h1v = fmaf(pf3, Wp[3 * IN_C + k2], h1v);
                float f = fmaxf(h1v, 0.0f);
                #pragma unroll
                for (int c = 0; c < IN_C; ++c)
                    h2[c] = fmaf(f, Wb[k2 * IN_C + c], h2[c]);
            }
        } else {
            float pf[4] = {pf0, pf1, pf2, pf3};
            const float4* xp = reinterpret_cast<const float4*>(x_prot + (size_t)src * IN_C);
            #pragma unroll
            for (int hh = 0; hh < 2; ++hh) {
                float h1h[16];
                #pragma unroll
                for (int c = 0; c < 16; ++c) h1h[c] = h1b[hh * 16 + c];
                #pragma unroll
                for (int kk = 0; kk < 8; ++kk) {
                    float4 xv = xp[kk];
                    float fs[4] = {xv.x, xv.y, xv.z, xv.w};
                    #pragma unroll
                    for (int j = 0; j < 4; ++j)
                        #pragma unroll
                        for (int c = 0; c < 16; ++c)
                            h1h[c] = fmaf(fs[j], Wa[(kk * 4 + j) * IN_C + hh * 16 + c], h1h[c]);
                }
                #pragma unroll
                for (int j = 0; j < 4; ++j)
                    #pragma unroll
                    for (int c = 0; c < 16; ++c)
                        h1h[c] = fmaf(pf[j], Wp[j * IN_C + hh * 16 + c], h1h[c]);
                #pragma unroll
                for (int k2 = 0; k2 < 16; ++k2) {
                    float f = fmaxf(h1h[k2], 0.0f);
                    #pragma unroll
                    for (int c = 0; c < IN_C; ++c)
                        h2[c] = fmaf(f, Wb[(hh * 16 + k2) * IN_C + c], h2[c]);
                }
            }
        }

        #pragma unroll
        for (int c = 0; c < IN_C; ++c)
            acc[c] += fmaxf(h2[c], 0.0f);
    }

    #pragma unroll
    for (int c = 0; c < IN_C; ++c)
        acc[c] += __shfl_xor(acc[c], 1, 64);
    #pragma unroll
    for (int c = 0; c < IN_C; ++c)
        acc[c] += __shfl_xor(acc[c], 2, 64);

    if (valid && sub < 2) {
        float* p = (sub ? conv : out) + (size_t)dst * IN_C;
        float4* p4 = reinterpret_cast<float4*>(p);
        #pragma unroll
        for (int qq = 0; qq < 8; ++qq) {
            float4 v;
            v.x = acc[qq * 4 + 0]; v.y = acc[qq * 4 + 1];
            v.z = acc[qq * 4 + 2]; v.w = acc[qq * 4 + 3];
            p4[qq] = v;
        }
    }
}

__global__ __launch_bounds__(256) void k_edges_fallback(
    const float* __restrict__ x_dna, const float* __restrict__ v_dna,
    const float* __restrict__ x_prot, const float* __restrict__ v_prot,
    const float* __restrict__ prot_vec, const float* __restrict__ dna_vec,
    const int* __restrict__ esrc, const int* __restrict__ edst,
    const float* __restrict__ W1, const float* __restrict__ b1,
    const float* __restrict__ W2, const float* __restrict__ b2,
    int E, float* __restrict__ conv)
{
    int t = blockIdx.x * blockDim.x + threadIdx.x;
    if (t >= E) return;
    int src = esrc[t], dst = edst[t];
    int b = branch_of(dst % 11);
    const float* Wa  = W1 + b * (IN_F * IN_C);
    const float* Wb  = W2 + b * (IN_C * IN_C);
    const float* ba  = b1 + b * IN_C;
    const float* bb2 = b2 + b * IN_C;

    float vdx = v_dna[dst * 3 + 0], vdy = v_dna[dst * 3 + 1], vdz = v_dna[dst * 3 + 2];
    float vpx = v_prot[src * 3 + 0], vpy = v_prot[src * 3 + 1], vpz = v_prot[src * 3 + 2];
    float nix = dna_vec[dst * 3 + 0], niy = dna_vec[dst * 3 + 1], niz = dna_vec[dst * 3 + 2];
    float njx = prot_vec[src * 3 + 0], njy = prot_vec[src * 3 + 1], njz = prot_vec[src * 3 + 2];
    float dx = vpx - vdx, dy = vpy - vdy, dz = vpz - vdz;
    float pf[4];
    pf[0] = sqrtf(dx * dx + dy * dy + dz * dz);
    pf[1] = angf(nix, niy, niz, dx, dy, dz);
    pf[2] = angf(njx, njy, njz, dx, dy, dz);
    pf[3] = angf(nix, niy, niz, njx, njy, njz);

    float h1[IN_C];
    #pragma unroll
    for (int c = 0; c < IN_C; ++c) h1[c] = ba[c];
    const float4* xp = reinterpret_cast<const float4*>(x_prot + (size_t)src * IN_C);
    #pragma unroll
    for (int kk = 0; kk < 8; ++kk) {
        float4 xv = xp[kk];
        float fs[4] = {xv.x, xv.y, xv.z, xv.w};
        #pragma unroll
        for (int j = 0; j < 4; ++j)
            #pragma unroll
            for (int c = 0; c < IN_C; ++c)
                h1[c] = fmaf(fs[j], Wa[(kk * 4 + j) * IN_C + c], h1[c]);
    }
    #pragma unroll
    for (int j = 0; j < 4; ++j)
        #pragma unroll
        for (int c = 0; c < IN_C; ++c)
            h1[c] = fmaf(pf[j], Wa[(32 + j) * IN_C + c], h1[c]);
    const float4* xd = reinterpret_cast<const float4*>(x_dna + (size_t)dst * IN_C);
    #pragma unroll
    for (int kk = 0; kk < 8; ++kk) {
        float4 xv = xd[kk];
        float fs[4] = {xv.x, xv.y, xv.z, xv.w};
        #pragma unroll
        for (int j = 0; j < 4; ++j)
            #pragma unroll
            for (int c = 0; c < IN_C; ++c)
                h1[c] = fmaf(fs[j], Wa[(36 + kk * 4 + j) * IN_C + c], h1[c]);
    }
    float h2[IN_C];
    #pragma unroll
    for (int c = 0; c < IN_C; ++c) h2[c] = bb2[c];
    #pragma unroll
    for (int k = 0; k < IN_C; ++k) {
        float f = fmaxf(h1[k], 0.0f);
        #pragma unroll
        for (int c = 0; c < IN_C; ++c)
            h2[c] = fmaf(f, Wb[k * IN_C + c], h2[c]);
    }
    float* cv = conv + (size_t)dst * IN_C;
    #pragma unroll
    for (int c = 0; c < IN_C; ++c)
        atomicAdd(&cv[c], fmaxf(h2[c], 0.0f));
}

extern "C" void kernel_launch(void* const* d_in, const int* in_sizes, int n_in,
                              void* d_out, int out_size, void* d_ws, size_t ws_size,
                              hipStream_t stream) {
    const float* x_dna    = (const float*)d_in[0];
    const float* v_dna    = (const float*)d_in[1];
    const float* x_prot   = (const float*)d_in[2];
    const float* v_prot   = (const float*)d_in[3];
    const float* prot_vec = (const float*)d_in[4];
    const float* dna_vec  = (const float*)d_in[5];
    const int*   esrc     = (const int*)d_in[6];
    const int*   edst     = (const int*)d_in[7];
    const float* W1       = (const float*)d_in[8];
    const float* b1       = (const float*)d_in[9];
    const float* W2       = (const float*)d_in[10];
    const float* b2       = (const float*)d_in[11];

    const int E  = in_sizes[6];
    const int ND = in_sizes[0] / IN_C;       // N_DNA
    const int NP = in_sizes[2] / IN_C;       // N_PROT
    const int half = out_size / 2;
    float* out  = (float*)d_out;
    float* conv = out + half;

    const int NDp = (ND + 160 + 31) & ~31;
    const int nblk_scan = (NDp + 1023) / 1024;
    const int eb = (E + 255) / 256;

    // ws: counts|hist|blk|pbs|gbase|gcur|rowcur|node_order|pool | yp | yd
    const size_t base_ints = (size_t)ND + 256 + 256 + 8 + 512 + 512 + ND + NDp + E;
    const size_t ws_base   = base_ints * sizeof(int);
    const size_t yp_off    = (ws_base + 255) & ~(size_t)255;
    const size_t yp_bytes  = (size_t)NP * 4 * IN_C * sizeof(unsigned short);
    const size_t yd_off    = yp_off + yp_bytes;
    const size_t yd_bytes  = (size_t)ND * IN_C * sizeof(unsigned short);

    if (ND == half / IN_C && ws_size >= ws_base && nblk_scan <= 256) {
        int* counts     = (int*)d_ws;          // ND
        int* hist       = counts + ND;         // 256 (contiguous with counts)
        int* blk        = hist + 256;          // 256
        int* pbs        = blk + 256;           // 8
        int* gbase      = pbs + 8;             // 512
        int* gcur       = gbase + 512;         // 512
        int* rowcur     = gcur + 512;          // ND
        int* node_order = rowcur + ND;         // NDp
        int* pool_src   = node_order + NDp;    // E
        unsigned short* yp = (unsigned short*)((char*)d_ws + yp_off);
        unsigned short* yd = (unsigned short*)((char*)d_ws + yd_off);

        int mode = 0;
        if (ws_size >= yd_off + yd_bytes && ND % 11 == 0) mode = 2;
        else if (ws_size >= yp_off + yp_bytes)            mode = 1;

        const int nbkt = (ND + (1 << BK_SHIFT) - 1) >> BK_SHIFT;
        const bool fastfill = (mode == 2) && (NP < (1 << 17)) && (nbkt <= NBKT_MAX)
                              && ((size_t)E * sizeof(unsigned) <= yp_bytes);

        hipMemsetAsync(counts, 0, ((size_t)ND + 256) * sizeof(int), stream);

        k_count<<<eb, 256, 0, stream>>>(edst, E, counts);
        k_scan1<<<nblk_scan, 1024, 0, stream>>>(counts, ND, NDp, rowcur, blk,
                                                hist, node_order);
        k_scan2<<<1, 256, 0, stream>>>(blk, nblk_scan);
        k_scan3<<<nblk_scan, 1024, 0, stream>>>(rowcur, blk, ND);

        if (fastfill) {
            unsigned* stage = (unsigned*)yp;   // overlay; consumed before k_precomp
            k_binit<<<1, 512, 0, stream>>>(rowcur, ND, nbkt, E, gbase, gcur);
            int na = (E + TILE_A - 1) / TILE_A;
            k_passA<<<na, 256, 0, stream>>>(esrc, edst, E, nbkt, gcur, stage);
            k_passB<<<nbkt, 256, 0, stream>>>(stage, gbase, rowcur, pool_src);
        } else {
            k_fill<<<eb, 256, 0, stream>>>(esrc, edst, E, rowcur, pool_src);
        }

        k_padscan2<<<1, 256, 0, stream>>>(hist, pbs);
        k_assign<<<(ND + 255) / 256, 256, 0, stream>>>(counts, ND, hist, node_order);

        int NPpad = (NP + 63) & ~63;
        int NB = ND / 11;
        int NBpad = (NB + 63) & ~63;
        if (mode >= 1) {
            int tot = 4 * NPpad + (mode == 2 ? 11 * NBpad : 0);
            k_precomp<<<(tot + 255) / 256, 256, 0, stream>>>(
                x_prot, x_dna, W1, b1, NP, NPpad, NB, NBpad, mode == 2, yp, yd);
        }

        if (mode == 2) {
            int nbm = (2 * NDp + 255) / 256;
            k_mfma<<<nbm, 256, 0, stream>>>(
                v_dna, v_prot, prot_vec, dna_vec, W1, W2, b2,
                node_order, rowcur, counts, pool_src, pbs,
                yp, yd, NP, out, conv, NDp);
        } else if (mode == 1) {
            int nb4 = (4 * NDp + 255) / 256;
            k_nodes4<1><<<nb4, 256, 0, stream>>>(
                x_dna, v_dna, x_prot, v_prot, prot_vec, dna_vec,
                W1, b1, W2, b2, node_order, rowcur, counts, pool_src, pbs,
                yp, NP, out, conv, NDp);
        } else {
            int nb4 = (4 * NDp + 255) / 256;
            k_nodes4<0><<<nb4, 256, 0, stream>>>(
                x_dna, v_dna, x_prot, v_prot, prot_vec, dna_vec,
                W1, b1, W2, b2, node_order, rowcur, counts, pool_src, pbs,
                nullptr, NP, out, conv, NDp);
        }
    } else {
        hipMemsetAsync(conv, 0, (size_t)half * sizeof(float), stream);
        k_edges_fallback<<<eb, 256, 0, stream>>>(
            x_dna, v_dna, x_prot, v_prot, prot_vec, dna_vec,
            esrc, edst, W1, b1, W2, b2, E, conv);
        hipMemcpyAsync(out, conv, (size_t)half * sizeof(float),
                       hipMemcpyDeviceToDevice, stream);
    }
}

// Round 11
// 212.400 us; speedup vs baseline: 28.2551x; 1.3679x over previous
//
#include <hip/hip_runtime.h>

// ---------------------------------------------------------------------------
// BiNet R11 = R10 with:
//   * k_mfma software-pipelined: prefetch next src + geometry + yp row while
//     computing current iteration (breaks pool_src->yp dependent-gather chain
//     that left HBM at 37% and VALU at 37% -- latency-bound signature).
//   * XCD-bijective block swizzle (contiguous pid range per XCD -> per-XCD
//     yp working set ~7.7MB instead of 30MB).
//   * CSR front-end rebuilt: passA appends to fixed-capacity bucket regions;
//     k_bscan (1 tiny block) computes pool offsets; passB2 derives per-node
//     counts/rowend/pool AND the (branch,count) histogram in LDS.
//     Deletes k_count (1.5M random L2 atomics), scan1/2/3, and both memsets.
// ---------------------------------------------------------------------------

#define IN_C 32
#define IN_F 68
#define TILE_A 4096
#define BK_SHIFT 9
#define NBKT_MAX 448
#define BCAP 6144   // bucket capacity (avg 3488 at E=1.5M; >70 sigma margin)

using bf16x8v = __attribute__((ext_vector_type(8))) short;
using f32x16v = __attribute__((ext_vector_type(16))) float;

union U4F { unsigned u[4]; bf16x8v v; };

__device__ __forceinline__ unsigned cvtpk_bf16(float a, float b) {
    unsigned r;
    asm("v_cvt_pk_bf16_f32 %0, %1, %2" : "=v"(r) : "v"(a), "v"(b));
    return r;
}
__device__ __forceinline__ float bflo(unsigned u) { return __uint_as_float(u << 16); }
__device__ __forceinline__ float bfhi(unsigned u) { return __uint_as_float(u & 0xffff0000u); }

__device__ __forceinline__ float angf(float ax, float ay, float az,
                                      float bx, float by, float bz) {
    float cx = ay * bz - az * by;
    float cy = az * bx - ax * bz;
    float cz = ax * by - ay * bx;
    float cn = sqrtf(cx * cx + cy * cy + cz * cz);
    float dt = ax * bx + ay * by + az * bz;
    return atan2f(cn, dt);
}

__device__ __forceinline__ int branch_of(int m) {
    if (m == 0 || m == 10) return 0;
    if (m == 1 || m == 9)  return 1;
    if (m >= 2 && m <= 5)  return 2;
    return 3;
}

__device__ __forceinline__ unsigned bf16r(float f) {
    unsigned u = __float_as_uint(f);
    return (u + 0x7fffu + ((u >> 16) & 1u)) >> 16;
}

// ======================= FAST-PATH CSR BUILD =================================
__global__ void k_init(int* gcur, int nbkt, int* hist,
                       int* __restrict__ node_order, int NDp) {
    int t = blockIdx.x * 256 + threadIdx.x;
    if (t < nbkt) gcur[t] = t * BCAP;
    if (t < 256) hist[t] = 0;
    if (t < NDp) node_order[t] = -1;
}

__global__ __launch_bounds__(256) void k_passA(
    const int* __restrict__ esrc, const int* __restrict__ edst, int E,
    int nbkt, int* __restrict__ gcur, unsigned* __restrict__ stage)
{
    __shared__ unsigned rec[TILE_A];
    __shared__ unsigned short bkt[TILE_A];
    __shared__ int hist[NBKT_MAX];
    __shared__ int hscan[NBKT_MAX];
    __shared__ int cnt[NBKT_MAX];
    __shared__ int gpos[NBKT_MAX];
    __shared__ int chbase[8];

    int base = blockIdx.x * TILE_A;
    int n = E - base; if (n > TILE_A) n = TILE_A;
    if (n <= 0) return;

    for (int i = threadIdx.x; i < nbkt; i += 256) hist[i] = 0;
    __syncthreads();

    unsigned myrec[16];
    int mybkt[16];
    #pragma unroll
    for (int k = 0; k < 16; ++k) {
        int i = threadIdx.x + k * 256;
        mybkt[k] = -1;
        if (i < n) {
            int s = esrc[base + i];
            int d = edst[base + i];
            int b = d >> BK_SHIFT;
            myrec[k] = ((unsigned)(d & ((1 << BK_SHIFT) - 1)) << 17) | (unsigned)s;
            mybkt[k] = b;
            atomicAdd(&hist[b], 1);
        }
    }
    __syncthreads();

    {
        int lane = threadIdx.x & 63, w = threadIdx.x >> 6;
        int nch = (nbkt + 63) >> 6;
        for (int ch = w; ch < nch; ch += 4) {
            int idx = (ch << 6) + lane;
            int v = (idx < nbkt) ? hist[idx] : 0;
            int inc = v;
            #pragma unroll
            for (int d = 1; d < 64; d <<= 1) {
                int u = __shfl_up(inc, d, 64);
                if (lane >= d) inc += u;
            }
            if (idx < nbkt) hscan[idx] = inc - v;
            if (lane == 63) chbase[ch] = inc;
        }
        __syncthreads();
        if (threadIdx.x == 0) {
            int s = 0;
            for (int ch = 0; ch < nch; ++ch) { int t2 = chbase[ch]; chbase[ch] = s; s += t2; }
        }
        __syncthreads();
        for (int i = threadIdx.x; i < nbkt; i += 256) {
            int v = hscan[i] + chbase[i >> 6];
            hscan[i] = v;
            cnt[i] = v;
        }
    }
    for (int b2 = threadIdx.x; b2 < nbkt; b2 += 256) {
        int c = hist[b2];
        if (c > 0) gpos[b2] = atomicAdd(&gcur[b2], c);
    }
    __syncthreads();

    #pragma unroll
    for (int k = 0; k < 16; ++k) {
        if (mybkt[k] >= 0) {
            int p = atomicAdd(&cnt[mybkt[k]], 1);
            rec[p] = myrec[k];
            bkt[p] = (unsigned short)mybkt[k];
        }
    }
    __syncthreads();

    for (int i = threadIdx.x; i < n; i += 256) {
        int b2 = bkt[i];
        stage[gpos[b2] + (i - hscan[b2])] = rec[i];
    }
}

// exclusive scan of bucket counts -> bstart (pool offsets, hole-free pool)
__global__ __launch_bounds__(512) void k_bscan(const int* __restrict__ gcur,
                                               int nbkt, int* __restrict__ bstart) {
    __shared__ int wsum[8];
    int t = threadIdx.x;
    int v = (t < nbkt) ? (gcur[t] - t * BCAP) : 0;
    int lane = t & 63, w = t >> 6;
    int inc = v;
    #pragma unroll
    for (int d = 1; d < 64; d <<= 1) {
        int u = __shfl_up(inc, d, 64);
        if (lane >= d) inc += u;
    }
    if (lane == 63) wsum[w] = inc;
    __syncthreads();
    if (t == 0) {
        int a = 0;
        #pragma unroll
        for (int g = 0; g < 8; ++g) { int tmp = wsum[g]; wsum[g] = a; a += tmp; }
    }
    __syncthreads();
    if (t < nbkt) bstart[t] = inc - v + wsum[w];
}

// per-bucket: local CSR (counts/rowend/pool) + (branch,desc-count) histogram
__global__ __launch_bounds__(256) void k_passB2(
    const unsigned* __restrict__ stage, const int* __restrict__ gcur,
    const int* __restrict__ bstart, int ND,
    int* __restrict__ counts, int* __restrict__ rowend,
    int* __restrict__ pool_src, int* __restrict__ hist)
{
    __shared__ int lcnt[512];
    __shared__ int lpre[512];
    __shared__ int lh[256];
    __shared__ int wsum[4];

    int b = blockIdx.x;
    int cnt = gcur[b] - b * BCAP;
    int pstart = bstart[b];
    int dbase = b << BK_SHIFT;

    lcnt[threadIdx.x] = 0;
    lcnt[threadIdx.x + 256] = 0;
    lh[threadIdx.x] = 0;
    __syncthreads();

    for (int i = threadIdx.x; i < cnt; i += 256)
        atomicAdd(&lcnt[stage[(size_t)b * BCAP + i] >> 17], 1);
    __syncthreads();

    // exclusive scan of 512 counts, 2 per thread
    int e0 = lcnt[2 * threadIdx.x], e1 = lcnt[2 * threadIdx.x + 1];
    int s = e0 + e1;
    int lane = threadIdx.x & 63, w = threadIdx.x >> 6;
    int inc = s;
    #pragma unroll
    for (int d = 1; d < 64; d <<= 1) {
        int u = __shfl_up(inc, d, 64);
        if (lane >= d) inc += u;
    }
    if (lane == 63) wsum[w] = inc;
    __syncthreads();
    if (threadIdx.x == 0) {
        int a = 0;
        #pragma unroll
        for (int g = 0; g < 4; ++g) { int tmp = wsum[g]; wsum[g] = a; a += tmp; }
    }
    __syncthreads();
    int excl = inc - s + wsum[w];
    lpre[2 * threadIdx.x]     = excl;
    lpre[2 * threadIdx.x + 1] = excl + e0;

    // counts / rowend / local hist (reads own lcnt/lpre only)
    #pragma unroll
    for (int k = 0; k < 2; ++k) {
        int nid = 2 * threadIdx.x + k;
        int node = dbase + nid;
        if (node < ND) {
            int c = lcnt[nid];
            counts[node] = c;
            rowend[node] = pstart + lpre[nid] + c;
            int cc = c > 63 ? 63 : c;
            atomicAdd(&lh[branch_of(node % 11) * 64 + (63 - cc)], 1);
        }
    }
    __syncthreads();
    if (lh[threadIdx.x]) atomicAdd(&hist[threadIdx.x], lh[threadIdx.x]);

    // scatter using lpre as cursors (all reads of lpre done above)
    for (int i = threadIdx.x; i < cnt; i += 256) {
        unsigned r = stage[(size_t)b * BCAP + i];
        int nid = r >> 17;
        int pos = atomicAdd(&lpre[nid], 1);
        pool_src[pstart + pos] = (int)(r & 0x1FFFFu);
    }
}

// ======================= LEGACY CSR BUILD (fallback) =========================
__global__ void k_count(const int* __restrict__ edst, int E, int* counts) {
    int t = blockIdx.x * blockDim.x + threadIdx.x;
    if (t >= E) return;
    atomicAdd(&counts[edst[t]], 1);
}

__global__ __launch_bounds__(1024) void k_scan1(const int* __restrict__ counts,
                                                int NN, int NDp, int* cursor,
                                                int* blk, int* hist,
                                                int* node_order) {
    __shared__ int wsum[16];
    __shared__ int lh[256];
    if (threadIdx.x < 256) lh[threadIdx.x] = 0;
    __syncthreads();
    int t = blockIdx.x * 1024 + threadIdx.x;
    int lane = threadIdx.x & 63;
    int wid = threadIdx.x >> 6;
    int c = (t < NN) ? counts[t] : 0;
    if (t < NN) {
        int g = branch_of(t % 11);
        int cc = c > 63 ? 63 : c;
        atomicAdd(&lh[g * 64 + (63 - cc)], 1);
    }
    if (t < NDp) node_order[t] = -1;
    int inc = c;
    #pragma unroll
    for (int d = 1; d < 64; d <<= 1) {
        int v = __shfl_up(inc, d, 64);
        if (lane >= d) inc += v;
    }
    if (lane == 63) wsum[wid] = inc;
    __syncthreads();
    if (threadIdx.x < 16) {
        int v = wsum[threadIdx.x];
        int wi = v;
        #pragma unroll
        for (int d = 1; d < 16; d <<= 1) {
            int u = __shfl_up(wi, d, 64);
            if (threadIdx.x >= d) wi += u;
        }
        wsum[threadIdx.x] = wi - v;
        if (threadIdx.x == 15) blk[blockIdx.x] = wi;
    }
    __syncthreads();
    if (t < NN) cursor[t] = inc - c + wsum[wid];
    if (threadIdx.x < 256 && lh[threadIdx.x])
        atomicAdd(&hist[threadIdx.x], lh[threadIdx.x]);
}

__global__ __launch_bounds__(256) void k_scan2(int* blk, int nblk) {
    __shared__ int wsum[4];
    int lane = threadIdx.x & 63;
    int wid = threadIdx.x >> 6;
    int v = (threadIdx.x < nblk) ? blk[threadIdx.x] : 0;
    int inc = v;
    #pragma unroll
    for (int d = 1; d < 64; d <<= 1) {
        int u = __shfl_up(inc, d, 64);
        if (lane >= d) inc += u;
    }
    if (lane == 63) wsum[wid] = inc;
    __syncthreads();
    if (threadIdx.x < 4) {
        int w = wsum[threadIdx.x];
        int wi = w;
        #pragma unroll
        for (int d = 1; d < 4; d <<= 1) {
            int u = __shfl_up(wi, d, 64);
            if (threadIdx.x >= d) wi += u;
        }
        wsum[threadIdx.x] = wi - w;
    }
    __syncthreads();
    if (threadIdx.x < nblk) blk[threadIdx.x] = inc - v + wsum[wid];
}

__global__ __launch_bounds__(1024) void k_scan3(int* cursor, const int* blk, int NN) {
    int t = blockIdx.x * 1024 + threadIdx.x;
    if (t >= NN) return;
    cursor[t] += blk[blockIdx.x];
}

__global__ void k_fill(const int* __restrict__ esrc, const int* __restrict__ edst,
                       int E, int* cursor, int* __restrict__ pool_src) {
    int t = blockIdx.x * blockDim.x + threadIdx.x;
    if (t >= E) return;
    int pos = atomicAdd(&cursor[edst[t]], 1);
    pool_src[pos] = esrc[t];
}

// ======================= NODE ORDER ==========================================
__global__ __launch_bounds__(256) void k_padscan2(int* hist, int* pbs) {
    __shared__ int gsum[4];
    __shared__ int gbase[5];
    int lane = threadIdx.x & 63;
    int w = threadIdx.x >> 6;
    int v = hist[threadIdx.x];
    int inc = v;
    #pragma unroll
    for (int d = 1; d < 64; d <<= 1) {
        int u = __shfl_up(inc, d, 64);
        if (lane >= d) inc += u;
    }
    if (lane == 63) gsum[w] = inc;
    __syncthreads();
    if (threadIdx.x == 0) {
        int base = 0;
        #pragma unroll
        for (int g = 0; g < 4; ++g) {
            gbase[g] = base;
            base = (base + gsum[g] + 31) & ~31;
        }
        gbase[4] = base;
    }
    __syncthreads();
    hist[threadIdx.x] = gbase[w] + inc - v;
    if (threadIdx.x < 5) pbs[threadIdx.x] = gbase[threadIdx.x];
}

__global__ __launch_bounds__(256) void k_assign(const int* __restrict__ counts,
                                                int ND, int* cur,
                                                int* __restrict__ node_order) {
    __shared__ int lh[256];
    __shared__ int lbase[256];
    lh[threadIdx.x] = 0;
    __syncthreads();
    int t = blockIdx.x * 256 + threadIdx.x;
    bool v = (t < ND);
    int bin = 0, rank = 0;
    if (v) {
        int g = branch_of(t % 11);
        int c = counts[t]; c = c > 63 ? 63 : c;
        bin = g * 64 + (63 - c);
        rank = atomicAdd(&lh[bin], 1);
    }
    __syncthreads();
    int cnt = lh[threadIdx.x];
    if (cnt > 0) lbase[threadIdx.x] = atomicAdd(&cur[threadIdx.x], cnt);
    __syncthreads();
    if (v) node_order[lbase[bin] + rank] = t;
}

// ======================= PRECOMPUTE ==========================================
__global__ __launch_bounds__(256) void k_precomp(
    const float* __restrict__ x_prot, const float* __restrict__ x_dna,
    const float* __restrict__ W1, const float* __restrict__ b1,
    int NP, int NPpad, int NB, int NBpad, int do_dna,
    unsigned short* __restrict__ yp, unsigned short* __restrict__ yd)
{
    int t = blockIdx.x * 256 + threadIdx.x;
    int NP4 = 4 * NPpad;
    float h[IN_C];
    unsigned short* dstp;

    if (t < NP4) {
        int g = t / NPpad;
        int p = t - g * NPpad;
        if (p >= NP) return;
        int bb = __builtin_amdgcn_readfirstlane(g);
        const float* Wa = W1 + bb * (IN_F * IN_C);
        #pragma unroll
        for (int c = 0; c < IN_C; ++c) h[c] = 0.0f;
        const float4* xp = reinterpret_cast<const float4*>(x_prot + (size_t)p * IN_C);
        #pragma unroll
        for (int kk = 0; kk < 8; ++kk) {
            float4 xv = xp[kk];
            float fs[4] = {xv.x, xv.y, xv.z, xv.w};
            #pragma unroll
            for (int j = 0; j < 4; ++j)
                #pragma unroll
                for (int c = 0; c < IN_C; ++c)
                    h[c] = fmaf(fs[j], Wa[(kk * 4 + j) * IN_C + c], h[c]);
        }
        dstp = yp + ((size_t)bb * NP + p) * IN_C;
    } else {
        if (!do_dna) return;
        int t2 = t - NP4;
        int q = t2 / NBpad;
        if (q >= 11) return;
        int idx = t2 - q * NBpad;
        if (idx >= NB) return;
        int g, m;
        if (q < 2)      { g = 0; m = q ? 10 : 0; }
        else if (q < 4) { g = 1; m = (q == 2) ? 1 : 9; }
        else if (q < 8) { g = 2; m = 2 + (q - 4); }
        else            { g = 3; m = 6 + (q - 8); }
        int bb = __builtin_amdgcn_readfirstlane(g);
        int dn = idx * 11 + m;
        const float* Wa = W1 + bb * (IN_F * IN_C);
        const float* ba = b1 + bb * IN_C;
        #pragma unroll
        for (int c = 0; c < IN_C; ++c) h[c] = ba[c];
        const float4* xd = reinterpret_cast<const float4*>(x_dna + (size_t)dn * IN_C);
        #pragma unroll
        for (int kk = 0; kk < 8; ++kk) {
            float4 xv = xd[kk];
            float fs[4] = {xv.x, xv.y, xv.z, xv.w};
            #pragma unroll
            for (int j = 0; j < 4; ++j)
                #pragma unroll
                for (int c = 0; c < IN_C; ++c)
                    h[c] = fmaf(fs[j], Wa[(36 + kk * 4 + j) * IN_C + c], h[c]);
        }
        dstp = yd + (size_t)dn * IN_C;
    }

    unsigned yw[16];
    #pragma unroll
    for (int j = 0; j < 16; ++j)
        yw[j] = bf16r(h[2 * j]) | (bf16r(h[2 * j + 1]) << 16);
    uint4* d4 = reinterpret_cast<uint4*>(dstp);
    d4[0] = make_uint4(yw[0], yw[1], yw[2], yw[3]);
    d4[1] = make_uint4(yw[4], yw[5], yw[6], yw[7]);
    d4[2] = make_uint4(yw[8], yw[9], yw[10], yw[11]);
    d4[3] = make_uint4(yw[12], yw[13], yw[14], yw[15]);
}

// ======================= MFMA MAIN (pipelined + XCD swizzle) =================
__global__ __launch_bounds__(256) void k_mfma(
    const float* __restrict__ v_dna, const float* __restrict__ v_prot,
    const float* __restrict__ prot_vec, const float* __restrict__ dna_vec,
    const float* __restrict__ W1, const float* __restrict__ W2,
    const float* __restrict__ b2,
    const int* __restrict__ node_order, const int* __restrict__ rowend,
    const int* __restrict__ counts, const int* __restrict__ pool_src,
    const int* __restrict__ pbs,
    const unsigned short* __restrict__ yp, const unsigned short* __restrict__ yd,
    int NP, float* __restrict__ out, float* __restrict__ conv, int NDp)
{
    // bijective XCD swizzle (m204): contiguous logical range per XCD
    int nblk = gridDim.x;
    int q8 = nblk >> 3, r8 = nblk & 7;
    int x = blockIdx.x & 7, bidx = blockIdx.x >> 3;
    int lb = (x < r8 ? x * (q8 + 1) : r8 * (q8 + 1) + (x - r8) * q8) + bidx;

    int t = lb * 256 + threadIdx.x;
    int lane = threadIdx.x & 63;
    int hi = lane >> 5;
    int col = lane & 31;
    int pid = t >> 1;
    int sub = t & 1;

    int pb1 = pbs[1], pb2v = pbs[2], pb3 = pbs[3];
    int g = (pid >= pb1) + (pid >= pb2v) + (pid >= pb3);
    int bb = __builtin_amdgcn_readfirstlane(g);

    int dst = (pid < NDp) ? node_order[pid] : -1;
    bool vnode = (dst >= 0);
    int dsafe = vnode ? dst : 0;
    int n_all = vnode ? counts[dsafe] : 0;
    int start = vnode ? (rowend[dsafe] - n_all) : 0;

    const float* Wp = W1 + bb * (IN_F * IN_C) + 32 * IN_C;
    const float* Wb = W2 + bb * (IN_C * IN_C);
    float b2c = b2[bb * IN_C + col];

    U4F B0u, B1u;
    #pragma unroll
    for (int j = 0; j < 4; ++j) {
        int k0 = hi * 8 + 2 * j;
        B0u.u[j] = cvtpk_bf16(Wb[k0 * IN_C + col],        Wb[(k0 + 1) * IN_C + col]);
        B1u.u[j] = cvtpk_bf16(Wb[(16 + k0) * IN_C + col], Wb[(17 + k0) * IN_C + col]);
    }

    float vdx = v_dna[dsafe * 3 + 0], vdy = v_dna[dsafe * 3 + 1], vdz = v_dna[dsafe * 3 + 2];
    float nix = dna_vec[dsafe * 3 + 0], niy = dna_vec[dsafe * 3 + 1], niz = dna_vec[dsafe * 3 + 2];

    unsigned ydw[16];
    {
        const uint4* ydv = reinterpret_cast<const uint4*>(yd + (size_t)dsafe * IN_C);
        uint4 w0 = ydv[0], w1 = ydv[1], w2 = ydv[2], w3 = ydv[3];
        *reinterpret_cast<uint4*>(&ydw[0])  = w0;
        *reinterpret_cast<uint4*>(&ydw[4])  = w1;
        *reinterpret_cast<uint4*>(&ydw[8])  = w2;
        *reinterpret_cast<uint4*>(&ydw[12]) = w3;
    }

    float acc[16];
    #pragma unroll
    for (int i = 0; i < 16; ++i) acc[i] = 0.0f;

    int niter = (n_all + 1) >> 1;
    #pragma unroll
    for (int d = 1; d < 64; d <<= 1) {
        int o = __shfl_xor(niter, d, 64);
        niter = niter > o ? niter : o;
    }

    // --- software pipeline: prefetch src/geometry/yp one iteration ahead ----
    int src_c = 0;
    float vpx_c = 0, vpy_c = 0, vpz_c = 0, njx_c = 0, njy_c = 0, njz_c = 0;
    unsigned ywc[16];
    if (niter > 0) {
        bool v0 = vnode && (sub < n_all);
        int off0 = v0 ? (start + sub) : 0;
        src_c = pool_src[off0];
        vpx_c = v_prot[src_c * 3 + 0]; vpy_c = v_prot[src_c * 3 + 1]; vpz_c = v_prot[src_c * 3 + 2];
        njx_c = prot_vec[src_c * 3 + 0]; njy_c = prot_vec[src_c * 3 + 1]; njz_c = prot_vec[src_c * 3 + 2];
        const uint4* yp0 = reinterpret_cast<const uint4*>(yp + ((size_t)bb * NP + src_c) * IN_C);
        uint4 y0 = yp0[0], y1 = yp0[1], y2 = yp0[2], y3 = yp0[3];
        *reinterpret_cast<uint4*>(&ywc[0])  = y0;
        *reinterpret_cast<uint4*>(&ywc[4])  = y1;
        *reinterpret_cast<uint4*>(&ywc[8])  = y2;
        *reinterpret_cast<uint4*>(&ywc[12]) = y3;
    }

    for (int it = 0; it < niter; ++it) {
        bool valid = vnode && (2 * it + sub < n_all);
        unsigned long long vm = __ballot(valid);

        // prefetch next iteration (issues loads while current computes)
        int it1 = it + 1;
        bool vn = (it1 < niter) && vnode && (2 * it1 + sub < n_all);
        int offn = vn ? (start + 2 * it1 + sub) : 0;
        int src_n = pool_src[offn];
        float vpx_n = v_prot[src_n * 3 + 0], vpy_n = v_prot[src_n * 3 + 1], vpz_n = v_prot[src_n * 3 + 2];
        float njx_n = prot_vec[src_n * 3 + 0], njy_n = prot_vec[src_n * 3 + 1], njz_n = prot_vec[src_n * 3 + 2];
        const uint4* ypn = reinterpret_cast<const uint4*>(yp + ((size_t)bb * NP + src_n) * IN_C);
        uint4 n0 = ypn[0], n1 = ypn[1], n2 = ypn[2], n3 = ypn[3];

        // current geometry
        float dx = vpx_c - vdx, dy = vpy_c - vdy, dz = vpz_c - vdz;
        float pf0 = sqrtf(dx * dx + dy * dy + dz * dz);
        float pf1 = angf(nix, niy, niz, dx, dy, dz);
        float pf2 = angf(njx_c, njy_c, njz_c, dx, dy, dz);
        float pf3 = angf(nix, niy, niz, njx_c, njy_c, njz_c);

        unsigned p[16];
        #pragma unroll
        for (int j = 0; j < 16; ++j) {
            int c0 = 2 * j, c1 = 2 * j + 1;
            float a0 = bflo(ydw[j]) + bflo(ywc[j]);
            float a1 = bfhi(ydw[j]) + bfhi(ywc[j]);
            a0 = fmaf(pf0, Wp[0 * IN_C + c0], a0);
            a0 = fmaf(pf1, Wp[1 * IN_C + c0], a0);
            a0 = fmaf(pf2, Wp[2 * IN_C + c0], a0);
            a0 = fmaf(pf3, Wp[3 * IN_C + c0], a0);
            a1 = fmaf(pf0, Wp[0 * IN_C + c1], a1);
            a1 = fmaf(pf1, Wp[1 * IN_C + c1], a1);
            a1 = fmaf(pf2, Wp[2 * IN_C + c1], a1);
            a1 = fmaf(pf3, Wp[3 * IN_C + c1], a1);
            a0 = fmaxf(a0, 0.0f);
            a1 = fmaxf(a1, 0.0f);
            p[j] = cvtpk_bf16(a0, a1);
        }

        unsigned q[16];
        #pragma unroll
        for (int j = 0; j < 16; ++j)
            q[j] = (unsigned)__shfl_xor((int)p[j], 32, 64);

        U4F a00, a01, a10, a11;
        #pragma unroll
        for (int d2 = 0; d2 < 4; ++d2) {
            a00.u[d2] = hi ? q[4 + d2]  : p[d2];
            a01.u[d2] = hi ? q[12 + d2] : p[8 + d2];
            a10.u[d2] = hi ? p[4 + d2]  : q[d2];
            a11.u[d2] = hi ? p[12 + d2] : q[8 + d2];
        }

        unsigned long long vms = vm >> (4 * hi);

        {
            f32x16v D;
            #pragma unroll
            for (int r = 0; r < 16; ++r) D[r] = 0.0f;
            D = __builtin_amdgcn_mfma_f32_32x32x16_bf16(a00.v, B0u.v, D, 0, 0, 0);
            D = __builtin_amdgcn_mfma_f32_32x32x16_bf16(a01.v, B1u.v, D, 0, 0, 0);
            #pragma unroll
            for (int r = 0; r < 16; ++r) {
                int sh = (r & 3) + 8 * (r >> 2);
                float val = fmaxf(D[r] + b2c, 0.0f);
                bool ok = (vms >> sh) & 1ull;
                int ai = 2 * (r >> 2) + ((r & 3) >> 1);
                acc[ai] += ok ? val : 0.0f;
            }
        }
        {
            f32x16v D;
            #pragma unroll
            for (int r = 0; r < 16; ++r) D[r] = 0.0f;
            D = __builtin_amdgcn_mfma_f32_32x32x16_bf16(a10.v, B0u.v, D, 0, 0, 0);
            D = __builtin_amdgcn_mfma_f32_32x32x16_bf16(a11.v, B1u.v, D, 0, 0, 0);
            #pragma unroll
            for (int r = 0; r < 16; ++r) {
                int sh = 32 + (r & 3) + 8 * (r >> 2);
                float val = fmaxf(D[r] + b2c, 0.0f);
                bool ok = (vms >> sh) & 1ull;
                int ai = 8 + 2 * (r >> 2) + ((r & 3) >> 1);
                acc[ai] += ok ? val : 0.0f;
            }
        }

        // rotate pipeline registers
        src_c = src_n;
        vpx_c = vpx_n; vpy_c = vpy_n; vpz_c = vpz_n;
        njx_c = njx_n; njy_c = njy_n; njz_c = njz_n;
        *reinterpret_cast<uint4*>(&ywc[0])  = n0;
        *reinterpret_cast<uint4*>(&ywc[4])  = n1;
        *reinterpret_cast<uint4*>(&ywc[8])  = n2;
        *reinterpret_cast<uint4*>(&ywc[12]) = n3;
    }

    #pragma unroll
    for (int i = 0; i < 16; ++i) {
        int rb = i >> 3, rem = i & 7;
        int q2 = rem >> 1, u = rem & 1;
        int m = 16 * rb + 4 * q2 + 2 * hi + u;
        int dm = __shfl(dst, 2 * m, 64);
        if (dm >= 0) {
            out[(size_t)dm * IN_C + col]  = acc[i];
            conv[(size_t)dm * IN_C + col] = acc[i];
        }
    }
}

// ======================= non-MFMA fallbacks ==================================
template <int MODE>
__global__ __launch_bounds__(256) void k_nodes4(
    const float* __restrict__ x_dna, const float* __restrict__ v_dna,
    const float* __restrict__ x_prot, const float* __restrict__ v_prot,
    const float* __restrict__ prot_vec, const float* __restrict__ dna_vec,
    const float* __restrict__ W1, const float* __restrict__ b1,
    const float* __restrict__ W2, const float* __restrict__ b2,
    const int* __restrict__ node_order, const int* __restrict__ rowend,
    const int* __restrict__ counts, const int* __restrict__ pool_src,
    const int* __restrict__ pbs,
    const unsigned short* __restrict__ yp,
    int NP, float* __restrict__ out, float* __restrict__ conv, int NDp)
{
    int t = blockIdx.x * 256 + threadIdx.x;
    int pid = t >> 2;
    int sub = t & 3;
    if (pid >= NDp) return;

    int pb1 = pbs[1], pb2 = pbs[2], pb3 = pbs[3];
    int g = (pid >= pb1) + (pid >= pb2) + (pid >= pb3);
    int bb = __builtin_amdgcn_readfirstlane(g);

    int dst = node_order[pid];
    bool valid = (dst >= 0);
    int dsafe = valid ? dst : 0;

    int n_all = valid ? counts[dsafe] : 0;
    int start_all = valid ? (rowend[dsafe] - n_all) : 0;
    int nb4 = n_all >> 2, rem = n_all & 3;
    int n = nb4 + (sub < rem ? 1 : 0);
    int start = start_all + sub * nb4 + (sub < rem ? sub : rem);

    const float* Wa  = W1 + bb * (IN_F * IN_C);
    const float* Wp  = Wa + 32 * IN_C;
    const float* Wb  = W2 + bb * (IN_C * IN_C);
    const float* ba  = b1 + bb * IN_C;
    const float* bb2 = b2 + bb * IN_C;

    float vdx = v_dna[dsafe * 3 + 0], vdy = v_dna[dsafe * 3 + 1], vdz = v_dna[dsafe * 3 + 2];
    float nix = dna_vec[dsafe * 3 + 0], niy = dna_vec[dsafe * 3 + 1], niz = dna_vec[dsafe * 3 + 2];

    float h1b[IN_C];
    #pragma unroll
    for (int c = 0; c < IN_C; ++c) h1b[c] = ba[c];
    {
        const float4* xd = reinterpret_cast<const float4*>(x_dna + (size_t)dsafe * IN_C);
        #pragma unroll
        for (int kk = 0; kk < 8; ++kk) {
            float4 xv = xd[kk];
            float fs[4] = {xv.x, xv.y, xv.z, xv.w};
            #pragma unroll
            for (int j = 0; j < 4; ++j)
                #pragma unroll
                for (int c = 0; c < IN_C; ++c)
                    h1b[c] = fmaf(fs[j], Wa[(36 + kk * 4 + j) * IN_C + c], h1b[c]);
        }
    }

    float acc[IN_C];
    #pragma unroll
    for (int c = 0; c < IN_C; ++c) acc[c] = 0.0f;

    for (int k = 0; k < n; ++k) {
        int src = pool_src[start + k];
        float vpx = v_prot[src * 3 + 0], vpy = v_prot[src * 3 + 1], vpz = v_prot[src * 3 + 2];
        float njx = prot_vec[src * 3 + 0], njy = prot_vec[src * 3 + 1], njz = prot_vec[src * 3 + 2];
        float dx = vpx - vdx, dy = vpy - vdy, dz = vpz - vdz;
        float pf0 = sqrtf(dx * dx + dy * dy + dz * dz);
        float pf1 = angf(nix, niy, niz, dx, dy, dz);
        float pf2 = angf(njx, njy, njz, dx, dy, dz);
        float pf3 = angf(nix, niy, niz, njx, njy, njz);

        float h2[IN_C];
        #pragma unroll
        for (int c = 0; c < IN_C; ++c) h2[c] = bb2[c];

        if constexpr (MODE == 1) {
            unsigned yw[16];
            const uint4* ypv = reinterpret_cast<const uint4*>(yp + ((size_t)bb * NP + src) * IN_C);
            uint4 y0 = ypv[0], y1 = ypv[1], y2 = ypv[2], y3 = ypv[3];
            *reinterpret_cast<uint4*>(&yw[0])  = y0;
            *reinterpret_cast<uint4*>(&yw[4])  = y1;
            *reinterpret_cast<uint4*>(&yw[8])  = y2;
            *reinterpret_cast<uint4*>(&yw[12]) = y3;
            #pragma unroll
            for (int k2 = 0; k2 < IN_C; ++k2) {
                unsigned w = yw[k2 >> 1];
                float ypf = (k2 & 1) ? bfhi(w) : bflo(w);
                float h1v = h1b[k2] + ypf;
                h1v = fmaf(pf0, Wp[0 * IN_C + k2], h1v);
                h1v = fmaf(pf1, Wp[1 * IN_C + k2], h1v);
                h1v = fmaf(pf2, Wp[2 * IN_C + k2], h1v);
                h1v = fmaf(pf3, Wp[3 * IN_C + k2], h1v);
                float f = fmaxf(h1v, 0.0f);
                #pragma unroll
                for (int c = 0; c < IN_C; ++c)
                    h2[c] = fmaf(f, Wb[k2 * IN_C + c], h2[c]);
            }
        } else {
            float pf[4] = {pf0, pf1, pf2, pf3};
            const float4* xp = reinterpret_cast<const float4*>(x_prot + (size_t)src * IN_C);
            #pragma unroll
            for (int hh = 0; hh < 2; ++hh) {
                float h1h[16];
                #pragma unroll
                for (int c = 0; c < 16; ++c) h1h[c] = h1b[hh * 16 + c];
                #pragma unroll
                for (int kk = 0; kk < 8; ++kk) {
                    float4 xv = xp[kk];
                    float fs[4] = {xv.x, xv.y, xv.z, xv.w};
                    #pragma unroll
                    for (int j = 0; j < 4; ++j)
                        #pragma unroll
                        for (int c = 0; c < 16; ++c)
                            h1h[c] = fmaf(fs[j], Wa[(kk * 4 + j) * IN_C + hh * 16 + c], h1h[c]);
                }
                #pragma unroll
                for (int j = 0; j < 4; ++j)
                    #pragma unroll
                    for (int c = 0; c < 16; ++c)
                        h1h[c] = fmaf(pf[j], Wp[j * IN_C + hh * 16 + c], h1h[c]);
                #pragma unroll
                for (int k2 = 0; k2 < 16; ++k2) {
                    float f = fmaxf(h1h[k2], 0.0f);
                    #pragma unroll
                    for (int c = 0; c < IN_C; ++c)
                        h2[c] = fmaf(f, Wb[(hh * 16 + k2) * IN_C + c], h2[c]);
                }
            }
        }

        #pragma unroll
        for (int c = 0; c < IN_C; ++c)
            acc[c] += fmaxf(h2[c], 0.0f);
    }

    #pragma unroll
    for (int c = 0; c < IN_C; ++c)
        acc[c] += __shfl_xor(acc[c], 1, 64);
    #pragma unroll
    for (int c = 0; c < IN_C; ++c)
        acc[c] += __shfl_xor(acc[c], 2, 64);

    if (valid && sub < 2) {
        float* p = (sub ? conv : out) + (size_t)dst * IN_C;
        float4* p4 = reinterpret_cast<float4*>(p);
        #pragma unroll
        for (int qq = 0; qq < 8; ++qq) {
            float4 v;
            v.x = acc[qq * 4 + 0]; v.y = acc[qq * 4 + 1];
            v.z = acc[qq * 4 + 2]; v.w = acc[qq * 4 + 3];
            p4[qq] = v;
        }
    }
}

__global__ __launch_bounds__(256) void k_edges_fallback(
    const float* __restrict__ x_dna, const float* __restrict__ v_dna,
    const float* __restrict__ x_prot, const float* __restrict__ v_prot,
    const float* __restrict__ prot_vec, const float* __restrict__ dna_vec,
    const int* __restrict__ esrc, const int* __restrict__ edst,
    const float* __restrict__ W1, const float* __restrict__ b1,
    const float* __restrict__ W2, const float* __restrict__ b2,
    int E, float* __restrict__ conv)
{
    int t = blockIdx.x * blockDim.x + threadIdx.x;
    if (t >= E) return;
    int src = esrc[t], dst = edst[t];
    int b = branch_of(dst % 11);
    const float* Wa  = W1 + b * (IN_F * IN_C);
    const float* Wb  = W2 + b * (IN_C * IN_C);
    const float* ba  = b1 + b * IN_C;
    const float* bb2 = b2 + b * IN_C;

    float vdx = v_dna[dst * 3 + 0], vdy = v_dna[dst * 3 + 1], vdz = v_dna[dst * 3 + 2];
    float vpx = v_prot[src * 3 + 0], vpy = v_prot[src * 3 + 1], vpz = v_prot[src * 3 + 2];
    float nix = dna_vec[dst * 3 + 0], niy = dna_vec[dst * 3 + 1], niz = dna_vec[dst * 3 + 2];
    float njx = prot_vec[src * 3 + 0], njy = prot_vec[src * 3 + 1], njz = prot_vec[src * 3 + 2];
    float dx = vpx - vdx, dy = vpy - vdy, dz = vpz - vdz;
    float pf[4];
    pf[0] = sqrtf(dx * dx + dy * dy + dz * dz);
    pf[1] = angf(nix, niy, niz, dx, dy, dz);
    pf[2] = angf(njx, njy, njz, dx, dy, dz);
    pf[3] = angf(nix, niy, niz, njx, njy, njz);

    float h1[IN_C];
    #pragma unroll
    for (int c = 0; c < IN_C; ++c) h1[c] = ba[c];
    const float4* xp = reinterpret_cast<const float4*>(x_prot + (size_t)src * IN_C);
    #pragma unroll
    for (int kk = 0; kk < 8; ++kk) {
        float4 xv = xp[kk];
        float fs[4] = {xv.x, xv.y, xv.z, xv.w};
        #pragma unroll
        for (int j = 0; j < 4; ++j)
            #pragma unroll
            for (int c = 0; c < IN_C; ++c)
                h1[c] = fmaf(fs[j], Wa[(kk * 4 + j) * IN_C + c], h1[c]);
    }
    #pragma unroll
    for (int j = 0; j < 4; ++j)
        #pragma unroll
        for (int c = 0; c < IN_C; ++c)
            h1[c] = fmaf(pf[j], Wa[(32 + j) * IN_C + c], h1[c]);
    const float4* xd = reinterpret_cast<const float4*>(x_dna + (size_t)dst * IN_C);
    #pragma unroll
    for (int kk = 0; kk < 8; ++kk) {
        float4 xv = xd[kk];
        float fs[4] = {xv.x, xv.y, xv.z, xv.w};
        #pragma unroll
        for (int j = 0; j < 4; ++j)
            #pragma unroll
            for (int c = 0; c < IN_C; ++c)
                h1[c] = fmaf(fs[j], Wa[(36 + kk * 4 + j) * IN_C + c], h1[c]);
    }
    float h2[IN_C];
    #pragma unroll
    for (int c = 0; c < IN_C; ++c) h2[c] = bb2[c];
    #pragma unroll
    for (int k = 0; k < IN_C; ++k) {
        float f = fmaxf(h1[k], 0.0f);
        #pragma unroll
        for (int c = 0; c < IN_C; ++c)
            h2[c] = fmaf(f, Wb[k * IN_C + c], h2[c]);
    }
    float* cv = conv + (size_t)dst * IN_C;
    #pragma unroll
    for (int c = 0; c < IN_C; ++c)
        atomicAdd(&cv[c], fmaxf(h2[c], 0.0f));
}

extern "C" void kernel_launch(void* const* d_in, const int* in_sizes, int n_in,
                              void* d_out, int out_size, void* d_ws, size_t ws_size,
                              hipStream_t stream) {
    const float* x_dna    = (const float*)d_in[0];
    const float* v_dna    = (const float*)d_in[1];
    const float* x_prot   = (const float*)d_in[2];
    const float* v_prot   = (const float*)d_in[3];
    const float* prot_vec = (const float*)d_in[4];
    const float* dna_vec  = (const float*)d_in[5];
    const int*   esrc     = (const int*)d_in[6];
    const int*   edst     = (const int*)d_in[7];
    const float* W1       = (const float*)d_in[8];
    const float* b1       = (const float*)d_in[9];
    const float* W2       = (const float*)d_in[10];
    const float* b2       = (const float*)d_in[11];

    const int E  = in_sizes[6];
    const int ND = in_sizes[0] / IN_C;       // N_DNA
    const int NP = in_sizes[2] / IN_C;       // N_PROT
    const int half = out_size / 2;
    float* out  = (float*)d_out;
    float* conv = out + half;

    const int NDp = (ND + 160 + 31) & ~31;
    const int nblk_scan = (NDp + 1023) / 1024;
    const int eb = (E + 255) / 256;

    // ws: counts|hist|blk|pbs|gcur(512)|bstart(512)|rowcur|node_order|pool | yp | yd
    const size_t base_ints = (size_t)ND + 256 + 256 + 8 + 512 + 512 + ND + NDp + E;
    const size_t ws_base   = base_ints * sizeof(int);
    const size_t yp_off    = (ws_base + 255) & ~(size_t)255;
    const size_t yp_bytes  = (size_t)NP * 4 * IN_C * sizeof(unsigned short);
    const size_t yd_off    = yp_off + yp_bytes;
    const size_t yd_bytes  = (size_t)ND * IN_C * sizeof(unsigned short);

    if (ND == half / IN_C && ws_size >= ws_base && nblk_scan <= 256) {
        int* counts     = (int*)d_ws;          // ND
        int* hist       = counts + ND;         // 256
        int* blk        = hist + 256;          // 256
        int* pbs        = blk + 256;           // 8
        int* gcur       = pbs + 8;             // 512
        int* bstart     = gcur + 512;          // 512
        int* rowcur     = bstart + 512;        // ND  (rowend in fast path)
        int* node_order = rowcur + ND;         // NDp
        int* pool_src   = node_order + NDp;    // E
        unsigned short* yp = (unsigned short*)((char*)d_ws + yp_off);
        unsigned short* yd = (unsigned short*)((char*)d_ws + yd_off);

        int mode = 0;
        if (ws_size >= yd_off + yd_bytes && ND % 11 == 0) mode = 2;
        else if (ws_size >= yp_off + yp_bytes)            mode = 1;

        const int nbkt = (ND + (1 << BK_SHIFT) - 1) >> BK_SHIFT;
        const bool fastfill = (mode == 2) && (NP < (1 << 17)) && (nbkt <= NBKT_MAX)
                              && ((size_t)nbkt * BCAP * sizeof(unsigned) <= yp_bytes)
                              && (E / nbkt + 512 < BCAP);

        if (fastfill) {
            unsigned* stage = (unsigned*)yp;   // overlay; consumed before k_precomp
            k_init<<<(NDp + 255) / 256, 256, 0, stream>>>(gcur, nbkt, hist,
                                                          node_order, NDp);
            int na = (E + TILE_A - 1) / TILE_A;
            k_passA<<<na, 256, 0, stream>>>(esrc, edst, E, nbkt, gcur, stage);
            k_bscan<<<1, 512, 0, stream>>>(gcur, nbkt, bstart);
            k_passB2<<<nbkt, 256, 0, stream>>>(stage, gcur, bstart, ND,
                                               counts, rowcur, pool_src, hist);
        } else {
            hipMemsetAsync(counts, 0, ((size_t)ND + 256) * sizeof(int), stream);
            k_count<<<eb, 256, 0, stream>>>(edst, E, counts);
            k_scan1<<<nblk_scan, 1024, 0, stream>>>(counts, ND, NDp, rowcur, blk,
                                                    hist, node_order);
            k_scan2<<<1, 256, 0, stream>>>(blk, nblk_scan);
            k_scan3<<<nblk_scan, 1024, 0, stream>>>(rowcur, blk, ND);
            k_fill<<<eb, 256, 0, stream>>>(esrc, edst, E, rowcur, pool_src);
        }

        k_padscan2<<<1, 256, 0, stream>>>(hist, pbs);
        k_assign<<<(ND + 255) / 256, 256, 0, stream>>>(counts, ND, hist, node_order);

        int NPpad = (NP + 63) & ~63;
        int NB = ND / 11;
        int NBpad = (NB + 63) & ~63;
        if (mode >= 1) {
            int tot = 4 * NPpad + (mode == 2 ? 11 * NBpad : 0);
            k_precomp<<<(tot + 255) / 256, 256, 0, stream>>>(
                x_prot, x_dna, W1, b1, NP, NPpad, NB, NBpad, mode == 2, yp, yd);
        }

        if (mode == 2) {
            int nbm = (2 * NDp + 255) / 256;
            k_mfma<<<nbm, 256, 0, stream>>>(
                v_dna, v_prot, prot_vec, dna_vec, W1, W2, b2,
                node_order, rowcur, counts, pool_src, pbs,
                yp, yd, NP, out, conv, NDp);
        } else if (mode == 1) {
            int nb4 = (4 * NDp + 255) / 256;
            k_nodes4<1><<<nb4, 256, 0, stream>>>(
                x_dna, v_dna, x_prot, v_prot, prot_vec, dna_vec,
                W1, b1, W2, b2, node_order, rowcur, counts, pool_src, pbs,
                yp, NP, out, conv, NDp);
        } else {
            int nb4 = (4 * NDp + 255) / 256;
            k_nodes4<0><<<nb4, 256, 0, stream>>>(
                x_dna, v_dna, x_prot, v_prot, prot_vec, dna_vec,
                W1, b1, W2, b2, node_order, rowcur, counts, pool_src, pbs,
                nullptr, NP, out, conv, NDp);
        }
    } else {
        hipMemsetAsync(conv, 0, (size_t)half * sizeof(float), stream);
        k_edges_fallback<<<eb, 256, 0, stream>>>(
            x_dna, v_dna, x_prot, v_prot, prot_vec, dna_vec,
            esrc, edst, W1, b1, W2, b2, E, conv);
        hipMemcpyAsync(out, conv, (size_t)half * sizeof(float),
                       hipMemcpyDeviceToDevice, stream);
    }
}

// Round 12
// 194.484 us; speedup vs baseline: 30.8580x; 1.0921x over previous
//
#include <hip/hip_runtime.h>

// ---------------------------------------------------------------------------
// BiNet R12 = R11 with the k_mfma gather diet:
//   * yp stored fp8-e4m3 (32B/record): per-branch slice 3.84MB -> ~L2-resident
//     per XCD; 2 dwordx4 loads/edge instead of 4. (R11: FETCH 257MB = 5x
//     useful, prefetch-insensitive -> VMEM-throughput-bound, not latency.)
//   * geo[src] = {v_prot, prot_vec} packed 6xbf16 in 16B: 1 load/edge vs 6.
//   * per-edge load instructions 11 -> 4.
//   Revert plan: absmax > 0.825 -> yp back to bf16, keep geo packing.
// ---------------------------------------------------------------------------

#define IN_C 32
#define IN_F 68
#define TILE_A 4096
#define BK_SHIFT 9
#define NBKT_MAX 448
#define BCAP 6144

using bf16x8v = __attribute__((ext_vector_type(8))) short;
using f32x16v = __attribute__((ext_vector_type(16))) float;
using f32x2v  = __attribute__((ext_vector_type(2))) float;

union U4F { unsigned u[4]; bf16x8v v; };

__device__ __forceinline__ unsigned cvtpk_bf16(float a, float b) {
    unsigned r;
    asm("v_cvt_pk_bf16_f32 %0, %1, %2" : "=v"(r) : "v"(a), "v"(b));
    return r;
}
__device__ __forceinline__ float bflo(unsigned u) { return __uint_as_float(u << 16); }
__device__ __forceinline__ float bfhi(unsigned u) { return __uint_as_float(u & 0xffff0000u); }

__device__ __forceinline__ float angf(float ax, float ay, float az,
                                      float bx, float by, float bz) {
    float cx = ay * bz - az * by;
    float cy = az * bx - ax * bz;
    float cz = ax * by - ay * bx;
    float cn = sqrtf(cx * cx + cy * cy + cz * cz);
    float dt = ax * bx + ay * by + az * bz;
    return atan2f(cn, dt);
}

__device__ __forceinline__ int branch_of(int m) {
    if (m == 0 || m == 10) return 0;
    if (m == 1 || m == 9)  return 1;
    if (m >= 2 && m <= 5)  return 2;
    return 3;
}

__device__ __forceinline__ unsigned bf16r(float f) {
    unsigned u = __float_as_uint(f);
    return (u + 0x7fffu + ((u >> 16) & 1u)) >> 16;
}

// ======================= FAST-PATH CSR BUILD =================================
__global__ void k_init(int* gcur, int nbkt, int* hist,
                       int* __restrict__ node_order, int NDp) {
    int t = blockIdx.x * 256 + threadIdx.x;
    if (t < nbkt) gcur[t] = t * BCAP;
    if (t < 256) hist[t] = 0;
    if (t < NDp) node_order[t] = -1;
}

__global__ __launch_bounds__(256) void k_passA(
    const int* __restrict__ esrc, const int* __restrict__ edst, int E,
    int nbkt, int* __restrict__ gcur, unsigned* __restrict__ stage)
{
    __shared__ unsigned rec[TILE_A];
    __shared__ unsigned short bkt[TILE_A];
    __shared__ int hist[NBKT_MAX];
    __shared__ int hscan[NBKT_MAX];
    __shared__ int cnt[NBKT_MAX];
    __shared__ int gpos[NBKT_MAX];
    __shared__ int chbase[8];

    int base = blockIdx.x * TILE_A;
    int n = E - base; if (n > TILE_A) n = TILE_A;
    if (n <= 0) return;

    for (int i = threadIdx.x; i < nbkt; i += 256) hist[i] = 0;
    __syncthreads();

    unsigned myrec[16];
    int mybkt[16];
    #pragma unroll
    for (int k = 0; k < 16; ++k) {
        int i = threadIdx.x + k * 256;
        mybkt[k] = -1;
        if (i < n) {
            int s = esrc[base + i];
            int d = edst[base + i];
            int b = d >> BK_SHIFT;
            myrec[k] = ((unsigned)(d & ((1 << BK_SHIFT) - 1)) << 17) | (unsigned)s;
            mybkt[k] = b;
            atomicAdd(&hist[b], 1);
        }
    }
    __syncthreads();

    {
        int lane = threadIdx.x & 63, w = threadIdx.x >> 6;
        int nch = (nbkt + 63) >> 6;
        for (int ch = w; ch < nch; ch += 4) {
            int idx = (ch << 6) + lane;
            int v = (idx < nbkt) ? hist[idx] : 0;
            int inc = v;
            #pragma unroll
            for (int d = 1; d < 64; d <<= 1) {
                int u = __shfl_up(inc, d, 64);
                if (lane >= d) inc += u;
            }
            if (idx < nbkt) hscan[idx] = inc - v;
            if (lane == 63) chbase[ch] = inc;
        }
        __syncthreads();
        if (threadIdx.x == 0) {
            int s = 0;
            for (int ch = 0; ch < nch; ++ch) { int t2 = chbase[ch]; chbase[ch] = s; s += t2; }
        }
        __syncthreads();
        for (int i = threadIdx.x; i < nbkt; i += 256) {
            int v = hscan[i] + chbase[i >> 6];
            hscan[i] = v;
            cnt[i] = v;
        }
    }
    for (int b2 = threadIdx.x; b2 < nbkt; b2 += 256) {
        int c = hist[b2];
        if (c > 0) gpos[b2] = atomicAdd(&gcur[b2], c);
    }
    __syncthreads();

    #pragma unroll
    for (int k = 0; k < 16; ++k) {
        if (mybkt[k] >= 0) {
            int p = atomicAdd(&cnt[mybkt[k]], 1);
            rec[p] = myrec[k];
            bkt[p] = (unsigned short)mybkt[k];
        }
    }
    __syncthreads();

    for (int i = threadIdx.x; i < n; i += 256) {
        int b2 = bkt[i];
        stage[gpos[b2] + (i - hscan[b2])] = rec[i];
    }
}

__global__ __launch_bounds__(512) void k_bscan(const int* __restrict__ gcur,
                                               int nbkt, int* __restrict__ bstart) {
    __shared__ int wsum[8];
    int t = threadIdx.x;
    int v = (t < nbkt) ? (gcur[t] - t * BCAP) : 0;
    int lane = t & 63, w = t >> 6;
    int inc = v;
    #pragma unroll
    for (int d = 1; d < 64; d <<= 1) {
        int u = __shfl_up(inc, d, 64);
        if (lane >= d) inc += u;
    }
    if (lane == 63) wsum[w] = inc;
    __syncthreads();
    if (t == 0) {
        int a = 0;
        #pragma unroll
        for (int g = 0; g < 8; ++g) { int tmp = wsum[g]; wsum[g] = a; a += tmp; }
    }
    __syncthreads();
    if (t < nbkt) bstart[t] = inc - v + wsum[w];
}

__global__ __launch_bounds__(256) void k_passB2(
    const unsigned* __restrict__ stage, const int* __restrict__ gcur,
    const int* __restrict__ bstart, int ND,
    int* __restrict__ counts, int* __restrict__ rowend,
    int* __restrict__ pool_src, int* __restrict__ hist)
{
    __shared__ int lcnt[512];
    __shared__ int lpre[512];
    __shared__ int lh[256];
    __shared__ int wsum[4];

    int b = blockIdx.x;
    int cnt = gcur[b] - b * BCAP;
    int pstart = bstart[b];
    int dbase = b << BK_SHIFT;

    lcnt[threadIdx.x] = 0;
    lcnt[threadIdx.x + 256] = 0;
    lh[threadIdx.x] = 0;
    __syncthreads();

    for (int i = threadIdx.x; i < cnt; i += 256)
        atomicAdd(&lcnt[stage[(size_t)b * BCAP + i] >> 17], 1);
    __syncthreads();

    int e0 = lcnt[2 * threadIdx.x], e1 = lcnt[2 * threadIdx.x + 1];
    int s = e0 + e1;
    int lane = threadIdx.x & 63, w = threadIdx.x >> 6;
    int inc = s;
    #pragma unroll
    for (int d = 1; d < 64; d <<= 1) {
        int u = __shfl_up(inc, d, 64);
        if (lane >= d) inc += u;
    }
    if (lane == 63) wsum[w] = inc;
    __syncthreads();
    if (threadIdx.x == 0) {
        int a = 0;
        #pragma unroll
        for (int g = 0; g < 4; ++g) { int tmp = wsum[g]; wsum[g] = a; a += tmp; }
    }
    __syncthreads();
    int excl = inc - s + wsum[w];
    lpre[2 * threadIdx.x]     = excl;
    lpre[2 * threadIdx.x + 1] = excl + e0;

    #pragma unroll
    for (int k = 0; k < 2; ++k) {
        int nid = 2 * threadIdx.x + k;
        int node = dbase + nid;
        if (node < ND) {
            int c = lcnt[nid];
            counts[node] = c;
            rowend[node] = pstart + lpre[nid] + c;
            int cc = c > 63 ? 63 : c;
            atomicAdd(&lh[branch_of(node % 11) * 64 + (63 - cc)], 1);
        }
    }
    __syncthreads();
    if (lh[threadIdx.x]) atomicAdd(&hist[threadIdx.x], lh[threadIdx.x]);

    for (int i = threadIdx.x; i < cnt; i += 256) {
        unsigned r = stage[(size_t)b * BCAP + i];
        int nid = r >> 17;
        int pos = atomicAdd(&lpre[nid], 1);
        pool_src[pstart + pos] = (int)(r & 0x1FFFFu);
    }
}

// ======================= LEGACY CSR BUILD (fallback) =========================
__global__ void k_count(const int* __restrict__ edst, int E, int* counts) {
    int t = blockIdx.x * blockDim.x + threadIdx.x;
    if (t >= E) return;
    atomicAdd(&counts[edst[t]], 1);
}

__global__ __launch_bounds__(1024) void k_scan1(const int* __restrict__ counts,
                                                int NN, int NDp, int* cursor,
                                                int* blk, int* hist,
                                                int* node_order) {
    __shared__ int wsum[16];
    __shared__ int lh[256];
    if (threadIdx.x < 256) lh[threadIdx.x] = 0;
    __syncthreads();
    int t = blockIdx.x * 1024 + threadIdx.x;
    int lane = threadIdx.x & 63;
    int wid = threadIdx.x >> 6;
    int c = (t < NN) ? counts[t] : 0;
    if (t < NN) {
        int g = branch_of(t % 11);
        int cc = c > 63 ? 63 : c;
        atomicAdd(&lh[g * 64 + (63 - cc)], 1);
    }
    if (t < NDp) node_order[t] = -1;
    int inc = c;
    #pragma unroll
    for (int d = 1; d < 64; d <<= 1) {
        int v = __shfl_up(inc, d, 64);
        if (lane >= d) inc += v;
    }
    if (lane == 63) wsum[wid] = inc;
    __syncthreads();
    if (threadIdx.x < 16) {
        int v = wsum[threadIdx.x];
        int wi = v;
        #pragma unroll
        for (int d = 1; d < 16; d <<= 1) {
            int u = __shfl_up(wi, d, 64);
            if (threadIdx.x >= d) wi += u;
        }
        wsum[threadIdx.x] = wi - v;
        if (threadIdx.x == 15) blk[blockIdx.x] = wi;
    }
    __syncthreads();
    if (t < NN) cursor[t] = inc - c + wsum[wid];
    if (threadIdx.x < 256 && lh[threadIdx.x])
        atomicAdd(&hist[threadIdx.x], lh[threadIdx.x]);
}

__global__ __launch_bounds__(256) void k_scan2(int* blk, int nblk) {
    __shared__ int wsum[4];
    int lane = threadIdx.x & 63;
    int wid = threadIdx.x >> 6;
    int v = (threadIdx.x < nblk) ? blk[threadIdx.x] : 0;
    int inc = v;
    #pragma unroll
    for (int d = 1; d < 64; d <<= 1) {
        int u = __shfl_up(inc, d, 64);
        if (lane >= d) inc += u;
    }
    if (lane == 63) wsum[wid] = inc;
    __syncthreads();
    if (threadIdx.x < 4) {
        int w = wsum[threadIdx.x];
        int wi = w;
        #pragma unroll
        for (int d = 1; d < 4; d <<= 1) {
            int u = __shfl_up(wi, d, 64);
            if (threadIdx.x >= d) wi += u;
        }
        wsum[threadIdx.x] = wi - w;
    }
    __syncthreads();
    if (threadIdx.x < nblk) blk[threadIdx.x] = inc - v + wsum[wid];
}

__global__ __launch_bounds__(1024) void k_scan3(int* cursor, const int* blk, int NN) {
    int t = blockIdx.x * 1024 + threadIdx.x;
    if (t >= NN) return;
    cursor[t] += blk[blockIdx.x];
}

__global__ void k_fill(const int* __restrict__ esrc, const int* __restrict__ edst,
                       int E, int* cursor, int* __restrict__ pool_src) {
    int t = blockIdx.x * blockDim.x + threadIdx.x;
    if (t >= E) return;
    int pos = atomicAdd(&cursor[edst[t]], 1);
    pool_src[pos] = esrc[t];
}

// ======================= NODE ORDER ==========================================
__global__ __launch_bounds__(256) void k_padscan2(int* hist, int* pbs) {
    __shared__ int gsum[4];
    __shared__ int gbase[5];
    int lane = threadIdx.x & 63;
    int w = threadIdx.x >> 6;
    int v = hist[threadIdx.x];
    int inc = v;
    #pragma unroll
    for (int d = 1; d < 64; d <<= 1) {
        int u = __shfl_up(inc, d, 64);
        if (lane >= d) inc += u;
    }
    if (lane == 63) gsum[w] = inc;
    __syncthreads();
    if (threadIdx.x == 0) {
        int base = 0;
        #pragma unroll
        for (int g = 0; g < 4; ++g) {
            gbase[g] = base;
            base = (base + gsum[g] + 31) & ~31;
        }
        gbase[4] = base;
    }
    __syncthreads();
    hist[threadIdx.x] = gbase[w] + inc - v;
    if (threadIdx.x < 5) pbs[threadIdx.x] = gbase[threadIdx.x];
}

__global__ __launch_bounds__(256) void k_assign(const int* __restrict__ counts,
                                                int ND, int* cur,
                                                int* __restrict__ node_order) {
    __shared__ int lh[256];
    __shared__ int lbase[256];
    lh[threadIdx.x] = 0;
    __syncthreads();
    int t = blockIdx.x * 256 + threadIdx.x;
    bool v = (t < ND);
    int bin = 0, rank = 0;
    if (v) {
        int g = branch_of(t % 11);
        int c = counts[t]; c = c > 63 ? 63 : c;
        bin = g * 64 + (63 - c);
        rank = atomicAdd(&lh[bin], 1);
    }
    __syncthreads();
    int cnt = lh[threadIdx.x];
    if (cnt > 0) lbase[threadIdx.x] = atomicAdd(&cur[threadIdx.x], cnt);
    __syncthreads();
    if (v) node_order[lbase[bin] + rank] = t;
}

// ======================= PRECOMPUTE ==========================================
// fp8mode: yp stored e4m3 (32B) + geo (16B bf16x6). else legacy bf16 yp (64B).
__global__ __launch_bounds__(256) void k_precomp(
    const float* __restrict__ x_prot, const float* __restrict__ x_dna,
    const float* __restrict__ v_prot, const float* __restrict__ prot_vec,
    const float* __restrict__ W1, const float* __restrict__ b1,
    int NP, int NPpad, int NB, int NBpad, int do_dna, int fp8mode,
    unsigned* __restrict__ yp8, unsigned* __restrict__ geo,
    unsigned short* __restrict__ ypb, unsigned short* __restrict__ yd)
{
    int t = blockIdx.x * 256 + threadIdx.x;
    int NP4 = 4 * NPpad;
    float h[IN_C];

    if (t < NP4) {
        int g = t / NPpad;
        int p = t - g * NPpad;
        if (p >= NP) return;
        int bb = __builtin_amdgcn_readfirstlane(g);
        const float* Wa = W1 + bb * (IN_F * IN_C);
        #pragma unroll
        for (int c = 0; c < IN_C; ++c) h[c] = 0.0f;
        const float4* xp = reinterpret_cast<const float4*>(x_prot + (size_t)p * IN_C);
        #pragma unroll
        for (int kk = 0; kk < 8; ++kk) {
            float4 xv = xp[kk];
            float fs[4] = {xv.x, xv.y, xv.z, xv.w};
            #pragma unroll
            for (int j = 0; j < 4; ++j)
                #pragma unroll
                for (int c = 0; c < IN_C; ++c)
                    h[c] = fmaf(fs[j], Wa[(kk * 4 + j) * IN_C + c], h[c]);
        }
        if (fp8mode) {
            unsigned yw[8];
            #pragma unroll
            for (int j = 0; j < 8; ++j) {
                int w = 0;
                w = __builtin_amdgcn_cvt_pk_fp8_f32(h[4 * j],     h[4 * j + 1], w, false);
                w = __builtin_amdgcn_cvt_pk_fp8_f32(h[4 * j + 2], h[4 * j + 3], w, true);
                yw[j] = (unsigned)w;
            }
            uint4* d4 = reinterpret_cast<uint4*>(yp8 + ((size_t)bb * NP + p) * 8);
            d4[0] = make_uint4(yw[0], yw[1], yw[2], yw[3]);
            d4[1] = make_uint4(yw[4], yw[5], yw[6], yw[7]);
            if (bb == 0) {  // geo once per src
                float vpx = v_prot[p * 3 + 0], vpy = v_prot[p * 3 + 1], vpz = v_prot[p * 3 + 2];
                float njx = prot_vec[p * 3 + 0], njy = prot_vec[p * 3 + 1], njz = prot_vec[p * 3 + 2];
                uint4 gr;
                gr.x = bf16r(vpx) | (bf16r(vpy) << 16);
                gr.y = bf16r(vpz) | (bf16r(njx) << 16);
                gr.z = bf16r(njy) | (bf16r(njz) << 16);
                gr.w = 0;
                reinterpret_cast<uint4*>(geo + (size_t)p * 4)[0] = gr;
            }
        } else {
            unsigned yw[16];
            #pragma unroll
            for (int j = 0; j < 16; ++j)
                yw[j] = bf16r(h[2 * j]) | (bf16r(h[2 * j + 1]) << 16);
            uint4* d4 = reinterpret_cast<uint4*>(ypb + ((size_t)bb * NP + p) * IN_C);
            d4[0] = make_uint4(yw[0], yw[1], yw[2], yw[3]);
            d4[1] = make_uint4(yw[4], yw[5], yw[6], yw[7]);
            d4[2] = make_uint4(yw[8], yw[9], yw[10], yw[11]);
            d4[3] = make_uint4(yw[12], yw[13], yw[14], yw[15]);
        }
    } else {
        if (!do_dna) return;
        int t2 = t - NP4;
        int q = t2 / NBpad;
        if (q >= 11) return;
        int idx = t2 - q * NBpad;
        if (idx >= NB) return;
        int g, m;
        if (q < 2)      { g = 0; m = q ? 10 : 0; }
        else if (q < 4) { g = 1; m = (q == 2) ? 1 : 9; }
        else if (q < 8) { g = 2; m = 2 + (q - 4); }
        else            { g = 3; m = 6 + (q - 8); }
        int bb = __builtin_amdgcn_readfirstlane(g);
        int dn = idx * 11 + m;
        const float* Wa = W1 + bb * (IN_F * IN_C);
        const float* ba = b1 + bb * IN_C;
        #pragma unroll
        for (int c = 0; c < IN_C; ++c) h[c] = ba[c];
        const float4* xd = reinterpret_cast<const float4*>(x_dna + (size_t)dn * IN_C);
        #pragma unroll
        for (int kk = 0; kk < 8; ++kk) {
            float4 xv = xd[kk];
            float fs[4] = {xv.x, xv.y, xv.z, xv.w};
            #pragma unroll
            for (int j = 0; j < 4; ++j)
                #pragma unroll
                for (int c = 0; c < IN_C; ++c)
                    h[c] = fmaf(fs[j], Wa[(36 + kk * 4 + j) * IN_C + c], h[c]);
        }
        unsigned yw[16];
        #pragma unroll
        for (int j = 0; j < 16; ++j)
            yw[j] = bf16r(h[2 * j]) | (bf16r(h[2 * j + 1]) << 16);
        uint4* d4 = reinterpret_cast<uint4*>(yd + (size_t)dn * IN_C);
        d4[0] = make_uint4(yw[0], yw[1], yw[2], yw[3]);
        d4[1] = make_uint4(yw[4], yw[5], yw[6], yw[7]);
        d4[2] = make_uint4(yw[8], yw[9], yw[10], yw[11]);
        d4[3] = make_uint4(yw[12], yw[13], yw[14], yw[15]);
    }
}

// ======================= MFMA MAIN ===========================================
__global__ __launch_bounds__(256) void k_mfma(
    const float* __restrict__ v_dna, const float* __restrict__ dna_vec,
    const float* __restrict__ W1, const float* __restrict__ W2,
    const float* __restrict__ b2,
    const int* __restrict__ node_order, const int* __restrict__ rowend,
    const int* __restrict__ counts, const int* __restrict__ pool_src,
    const int* __restrict__ pbs,
    const unsigned* __restrict__ yp8, const unsigned* __restrict__ geo,
    const unsigned short* __restrict__ yd,
    int NP, float* __restrict__ out, float* __restrict__ conv, int NDp)
{
    // bijective XCD swizzle: contiguous logical range per XCD
    int nblk = gridDim.x;
    int q8 = nblk >> 3, r8 = nblk & 7;
    int x = blockIdx.x & 7, bidx = blockIdx.x >> 3;
    int lb = (x < r8 ? x * (q8 + 1) : r8 * (q8 + 1) + (x - r8) * q8) + bidx;

    int t = lb * 256 + threadIdx.x;
    int lane = threadIdx.x & 63;
    int hi = lane >> 5;
    int col = lane & 31;
    int pid = t >> 1;
    int sub = t & 1;

    int pb1 = pbs[1], pb2v = pbs[2], pb3 = pbs[3];
    int g = (pid >= pb1) + (pid >= pb2v) + (pid >= pb3);
    int bb = __builtin_amdgcn_readfirstlane(g);

    int dst = (pid < NDp) ? node_order[pid] : -1;
    bool vnode = (dst >= 0);
    int dsafe = vnode ? dst : 0;
    int n_all = vnode ? counts[dsafe] : 0;
    int start = vnode ? (rowend[dsafe] - n_all) : 0;

    const float* Wp = W1 + bb * (IN_F * IN_C) + 32 * IN_C;
    const float* Wb = W2 + bb * (IN_C * IN_C);
    float b2c = b2[bb * IN_C + col];

    U4F B0u, B1u;
    #pragma unroll
    for (int j = 0; j < 4; ++j) {
        int k0 = hi * 8 + 2 * j;
        B0u.u[j] = cvtpk_bf16(Wb[k0 * IN_C + col],        Wb[(k0 + 1) * IN_C + col]);
        B1u.u[j] = cvtpk_bf16(Wb[(16 + k0) * IN_C + col], Wb[(17 + k0) * IN_C + col]);
    }

    float vdx = v_dna[dsafe * 3 + 0], vdy = v_dna[dsafe * 3 + 1], vdz = v_dna[dsafe * 3 + 2];
    float nix = dna_vec[dsafe * 3 + 0], niy = dna_vec[dsafe * 3 + 1], niz = dna_vec[dsafe * 3 + 2];

    unsigned ydw[16];
    {
        const uint4* ydv = reinterpret_cast<const uint4*>(yd + (size_t)dsafe * IN_C);
        uint4 w0 = ydv[0], w1 = ydv[1], w2 = ydv[2], w3 = ydv[3];
        *reinterpret_cast<uint4*>(&ydw[0])  = w0;
        *reinterpret_cast<uint4*>(&ydw[4])  = w1;
        *reinterpret_cast<uint4*>(&ydw[8])  = w2;
        *reinterpret_cast<uint4*>(&ydw[12]) = w3;
    }

    float acc[16];
    #pragma unroll
    for (int i = 0; i < 16; ++i) acc[i] = 0.0f;

    int niter = (n_all + 1) >> 1;
    #pragma unroll
    for (int d = 1; d < 64; d <<= 1) {
        int o = __shfl_xor(niter, d, 64);
        niter = niter > o ? niter : o;
    }

    // software pipeline: prefetch pool/geo/yp one iteration ahead
    unsigned gwc[4];
    unsigned ywc[8];
    if (niter > 0) {
        bool v0 = vnode && (sub < n_all);
        int off0 = v0 ? (start + sub) : 0;
        int src0 = pool_src[off0];
        uint4 gg = reinterpret_cast<const uint4*>(geo + (size_t)src0 * 4)[0];
        *reinterpret_cast<uint4*>(&gwc[0]) = gg;
        const uint4* yv = reinterpret_cast<const uint4*>(yp8 + ((size_t)bb * NP + src0) * 8);
        uint4 y0 = yv[0], y1 = yv[1];
        *reinterpret_cast<uint4*>(&ywc[0]) = y0;
        *reinterpret_cast<uint4*>(&ywc[4]) = y1;
    }

    for (int it = 0; it < niter; ++it) {
        bool valid = vnode && (2 * it + sub < n_all);
        unsigned long long vm = __ballot(valid);

        // prefetch next iteration
        int it1 = it + 1;
        bool vn = (it1 < niter) && vnode && (2 * it1 + sub < n_all);
        int offn = vn ? (start + 2 * it1 + sub) : 0;
        int src_n = pool_src[offn];
        uint4 ggn = reinterpret_cast<const uint4*>(geo + (size_t)src_n * 4)[0];
        const uint4* yvn = reinterpret_cast<const uint4*>(yp8 + ((size_t)bb * NP + src_n) * 8);
        uint4 n0 = yvn[0], n1 = yvn[1];

        // decode current geometry (bf16)
        float vpx = bflo(gwc[0]), vpy = bfhi(gwc[0]);
        float vpz = bflo(gwc[1]), njx = bfhi(gwc[1]);
        float njy = bflo(gwc[2]), njz = bfhi(gwc[2]);
        float dx = vpx - vdx, dy = vpy - vdy, dz = vpz - vdz;
        float pf0 = sqrtf(dx * dx + dy * dy + dz * dz);
        float pf1 = angf(nix, niy, niz, dx, dy, dz);
        float pf2 = angf(njx, njy, njz, dx, dy, dz);
        float pf3 = angf(nix, niy, niz, njx, njy, njz);

        // h1 = yd + yp(fp8) + Wp.ppf, relu, pack bf16 -> p[16]
        unsigned p[16];
        #pragma unroll
        for (int jj = 0; jj < 8; ++jj) {
            f32x2v f01 = __builtin_amdgcn_cvt_pk_f32_fp8((int)ywc[jj], false);
            f32x2v f23 = __builtin_amdgcn_cvt_pk_f32_fp8((int)ywc[jj], true);
            int c0 = 4 * jj;
            float a0 = bflo(ydw[2 * jj])     + f01[0];
            float a1 = bfhi(ydw[2 * jj])     + f01[1];
            float a2 = bflo(ydw[2 * jj + 1]) + f23[0];
            float a3 = bfhi(ydw[2 * jj + 1]) + f23[1];
            a0 = fmaf(pf0, Wp[0 * IN_C + c0],     a0);
            a0 = fmaf(pf1, Wp[1 * IN_C + c0],     a0);
            a0 = fmaf(pf2, Wp[2 * IN_C + c0],     a0);
            a0 = fmaf(pf3, Wp[3 * IN_C + c0],     a0);
            a1 = fmaf(pf0, Wp[0 * IN_C + c0 + 1], a1);
            a1 = fmaf(pf1, Wp[1 * IN_C + c0 + 1], a1);
            a1 = fmaf(pf2, Wp[2 * IN_C + c0 + 1], a1);
            a1 = fmaf(pf3, Wp[3 * IN_C + c0 + 1], a1);
            a2 = fmaf(pf0, Wp[0 * IN_C + c0 + 2], a2);
            a2 = fmaf(pf1, Wp[1 * IN_C + c0 + 2], a2);
            a2 = fmaf(pf2, Wp[2 * IN_C + c0 + 2], a2);
            a2 = fmaf(pf3, Wp[3 * IN_C + c0 + 2], a2);
            a3 = fmaf(pf0, Wp[0 * IN_C + c0 + 3], a3);
            a3 = fmaf(pf1, Wp[1 * IN_C + c0 + 3], a3);
            a3 = fmaf(pf2, Wp[2 * IN_C + c0 + 3], a3);
            a3 = fmaf(pf3, Wp[3 * IN_C + c0 + 3], a3);
            p[2 * jj]     = cvtpk_bf16(fmaxf(a0, 0.0f), fmaxf(a1, 0.0f));
            p[2 * jj + 1] = cvtpk_bf16(fmaxf(a2, 0.0f), fmaxf(a3, 0.0f));
        }

        unsigned q[16];
        #pragma unroll
        for (int j = 0; j < 16; ++j)
            q[j] = (unsigned)__shfl_xor((int)p[j], 32, 64);

        U4F a00, a01, a10, a11;
        #pragma unroll
        for (int d2 = 0; d2 < 4; ++d2) {
            a00.u[d2] = hi ? q[4 + d2]  : p[d2];
            a01.u[d2] = hi ? q[12 + d2] : p[8 + d2];
            a10.u[d2] = hi ? p[4 + d2]  : q[d2];
            a11.u[d2] = hi ? p[12 + d2] : q[8 + d2];
        }

        unsigned long long vms = vm >> (4 * hi);

        {
            f32x16v D;
            #pragma unroll
            for (int r = 0; r < 16; ++r) D[r] = 0.0f;
            D = __builtin_amdgcn_mfma_f32_32x32x16_bf16(a00.v, B0u.v, D, 0, 0, 0);
            D = __builtin_amdgcn_mfma_f32_32x32x16_bf16(a01.v, B1u.v, D, 0, 0, 0);
            #pragma unroll
            for (int r = 0; r < 16; ++r) {
                int sh = (r & 3) + 8 * (r >> 2);
                float val = fmaxf(D[r] + b2c, 0.0f);
                bool ok = (vms >> sh) & 1ull;
                int ai = 2 * (r >> 2) + ((r & 3) >> 1);
                acc[ai] += ok ? val : 0.0f;
            }
        }
        {
            f32x16v D;
            #pragma unroll
            for (int r = 0; r < 16; ++r) D[r] = 0.0f;
            D = __builtin_amdgcn_mfma_f32_32x32x16_bf16(a10.v, B0u.v, D, 0, 0, 0);
            D = __builtin_amdgcn_mfma_f32_32x32x16_bf16(a11.v, B1u.v, D, 0, 0, 0);
            #pragma unroll
            for (int r = 0; r < 16; ++r) {
                int sh = 32 + (r & 3) + 8 * (r >> 2);
                float val = fmaxf(D[r] + b2c, 0.0f);
                bool ok = (vms >> sh) & 1ull;
                int ai = 8 + 2 * (r >> 2) + ((r & 3) >> 1);
                acc[ai] += ok ? val : 0.0f;
            }
        }

        // rotate pipeline registers
        *reinterpret_cast<uint4*>(&gwc[0]) = ggn;
        *reinterpret_cast<uint4*>(&ywc[0]) = n0;
        *reinterpret_cast<uint4*>(&ywc[4]) = n1;
    }

    #pragma unroll
    for (int i = 0; i < 16; ++i) {
        int rb = i >> 3, rem = i & 7;
        int q2 = rem >> 1, u = rem & 1;
        int m = 16 * rb + 4 * q2 + 2 * hi + u;
        int dm = __shfl(dst, 2 * m, 64);
        if (dm >= 0) {
            out[(size_t)dm * IN_C + col]  = acc[i];
            conv[(size_t)dm * IN_C + col] = acc[i];
        }
    }
}

// ======================= non-MFMA fallbacks ==================================
template <int MODE>
__global__ __launch_bounds__(256) void k_nodes4(
    const float* __restrict__ x_dna, const float* __restrict__ v_dna,
    const float* __restrict__ x_prot, const float* __restrict__ v_prot,
    const float* __restrict__ prot_vec, const float* __restrict__ dna_vec,
    const float* __restrict__ W1, const float* __restrict__ b1,
    const float* __restrict__ W2, const float* __restrict__ b2,
    const int* __restrict__ node_order, const int* __restrict__ rowend,
    const int* __restrict__ counts, const int* __restrict__ pool_src,
    const int* __restrict__ pbs,
    const unsigned short* __restrict__ yp,
    int NP, float* __restrict__ out, float* __restrict__ conv, int NDp)
{
    int t = blockIdx.x * 256 + threadIdx.x;
    int pid = t >> 2;
    int sub = t & 3;
    if (pid >= NDp) return;

    int pb1 = pbs[1], pb2 = pbs[2], pb3 = pbs[3];
    int g = (pid >= pb1) + (pid >= pb2) + (pid >= pb3);
    int bb = __builtin_amdgcn_readfirstlane(g);

    int dst = node_order[pid];
    bool valid = (dst >= 0);
    int dsafe = valid ? dst : 0;

    int n_all = valid ? counts[dsafe] : 0;
    int start_all = valid ? (rowend[dsafe] - n_all) : 0;
    int nb4 = n_all >> 2, rem = n_all & 3;
    int n = nb4 + (sub < rem ? 1 : 0);
    int start = start_all + sub * nb4 + (sub < rem ? sub : rem);

    const float* Wa  = W1 + bb * (IN_F * IN_C);
    const float* Wp  = Wa + 32 * IN_C;
    const float* Wb  = W2 + bb * (IN_C * IN_C);
    const float* ba  = b1 + bb * IN_C;
    const float* bb2 = b2 + bb * IN_C;

    float vdx = v_dna[dsafe * 3 + 0], vdy = v_dna[dsafe * 3 + 1], vdz = v_dna[dsafe * 3 + 2];
    float nix = dna_vec[dsafe * 3 + 0], niy = dna_vec[dsafe * 3 + 1], niz = dna_vec[dsafe * 3 + 2];

    float h1b[IN_C];
    #pragma unroll
    for (int c = 0; c < IN_C; ++c) h1b[c] = ba[c];
    {
        const float4* xd = reinterpret_cast<const float4*>(x_dna + (size_t)dsafe * IN_C);
        #pragma unroll
        for (int kk = 0; kk < 8; ++kk) {
            float4 xv = xd[kk];
            float fs[4] = {xv.x, xv.y, xv.z, xv.w};
            #pragma unroll
            for (int j = 0; j < 4; ++j)
                #pragma unroll
                for (int c = 0; c < IN_C; ++c)
                    h1b[c] = fmaf(fs[j], Wa[(36 + kk * 4 + j) * IN_C + c], h1b[c]);
        }
    }

    float acc[IN_C];
    #pragma unroll
    for (int c = 0; c < IN_C; ++c) acc[c] = 0.0f;

    for (int k = 0; k < n; ++k) {
        int src = pool_src[start + k];
        float vpx = v_prot[src * 3 + 0], vpy = v_prot[src * 3 + 1], vpz = v_prot[src * 3 + 2];
        float njx = prot_vec[src * 3 + 0], njy = prot_vec[src * 3 + 1], njz = prot_vec[src * 3 + 2];
        float dx = vpx - vdx, dy = vpy - vdy, dz = vpz - vdz;
        float pf0 = sqrtf(dx * dx + dy * dy + dz * dz);
        float pf1 = angf(nix, niy, niz, dx, dy, dz);
        float pf2 = angf(njx, njy, njz, dx, dy, dz);
        float pf3 = angf(nix, niy, niz, njx, njy, njz);

        float h2[IN_C];
        #pragma unroll
        for (int c = 0; c < IN_C; ++c) h2[c] = bb2[c];

        if constexpr (MODE == 1) {
            unsigned yw[16];
            const uint4* ypv = reinterpret_cast<const uint4*>(yp + ((size_t)bb * NP + src) * IN_C);
            uint4 y0 = ypv[0], y1 = ypv[1], y2 = ypv[2], y3 = ypv[3];
            *reinterpret_cast<uint4*>(&yw[0])  = y0;
            *reinterpret_cast<uint4*>(&yw[4])  = y1;
            *reinterpret_cast<uint4*>(&yw[8])  = y2;
            *reinterpret_cast<uint4*>(&yw[12]) = y3;
            #pragma unroll
            for (int k2 = 0; k2 < IN_C; ++k2) {
                unsigned w = yw[k2 >> 1];
                float ypf = (k2 & 1) ? bfhi(w) : bflo(w);
                float h1v = h1b[k2] + ypf;
                h1v = fmaf(pf0, Wp[0 * IN_C + k2], h1v);
                h1v = fmaf(pf1, Wp[1 * IN_C + k2], h1v);
                h1v = fmaf(pf2, Wp[2 * IN_C + k2], h1v);
                h1v = fmaf(pf3, Wp[3 * IN_C + k2], h1v);
                float f = fmaxf(h1v, 0.0f);
                #pragma unroll
                for (int c = 0; c < IN_C; ++c)
                    h2[c] = fmaf(f, Wb[k2 * IN_C + c], h2[c]);
            }
        } else {
            float pf[4] = {pf0, pf1, pf2, pf3};
            const float4* xp = reinterpret_cast<const float4*>(x_prot + (size_t)src * IN_C);
            #pragma unroll
            for (int hh = 0; hh < 2; ++hh) {
                float h1h[16];
                #pragma unroll
                for (int c = 0; c < 16; ++c) h1h[c] = h1b[hh * 16 + c];
                #pragma unroll
                for (int kk = 0; kk < 8; ++kk) {
                    float4 xv = xp[kk];
                    float fs[4] = {xv.x, xv.y, xv.z, xv.w};
                    #pragma unroll
                    for (int j = 0; j < 4; ++j)
                        #pragma unroll
                        for (int c = 0; c < 16; ++c)
                            h1h[c] = fmaf(fs[j], Wa[(kk * 4 + j) * IN_C + hh * 16 + c], h1h[c]);
                }
                #pragma unroll
                for (int j = 0; j < 4; ++j)
                    #pragma unroll
                    for (int c = 0; c < 16; ++c)
                        h1h[c] = fmaf(pf[j], Wp[j * IN_C + hh * 16 + c], h1h[c]);
                #pragma unroll
                for (int k2 = 0; k2 < 16; ++k2) {
                    float f = fmaxf(h1h[k2], 0.0f);
                    #pragma unroll
                    for (int c = 0; c < IN_C; ++c)
                        h2[c] = fmaf(f, Wb[(hh * 16 + k2) * IN_C + c], h2[c]);
                }
            }
        }

        #pragma unroll
        for (int c = 0; c < IN_C; ++c)
            acc[c] += fmaxf(h2[c], 0.0f);
    }

    #pragma unroll
    for (int c = 0; c < IN_C; ++c)
        acc[c] += __shfl_xor(acc[c], 1, 64);
    #pragma unroll
    for (int c = 0; c < IN_C; ++c)
        acc[c] += __shfl_xor(acc[c], 2, 64);

    if (valid && sub < 2) {
        float* p = (sub ? conv : out) + (size_t)dst * IN_C;
        float4* p4 = reinterpret_cast<float4*>(p);
        #pragma unroll
        for (int qq = 0; qq < 8; ++qq) {
            float4 v;
            v.x = acc[qq * 4 + 0]; v.y = acc[qq * 4 + 1];
            v.z = acc[qq * 4 + 2]; v.w = acc[qq * 4 + 3];
            p4[qq] = v;
        }
    }
}

__global__ __launch_bounds__(256) void k_edges_fallback(
    const float* __restrict__ x_dna, const float* __restrict__ v_dna,
    const float* __restrict__ x_prot, const float* __restrict__ v_prot,
    const float* __restrict__ prot_vec, const float* __restrict__ dna_vec,
    const int* __restrict__ esrc, const int* __restrict__ edst,
    const float* __restrict__ W1, const float* __restrict__ b1,
    const float* __restrict__ W2, const float* __restrict__ b2,
    int E, float* __restrict__ conv)
{
    int t = blockIdx.x * blockDim.x + threadIdx.x;
    if (t >= E) return;
    int src = esrc[t], dst = edst[t];
    int b = branch_of(dst % 11);
    const float* Wa  = W1 + b * (IN_F * IN_C);
    const float* Wb  = W2 + b * (IN_C * IN_C);
    const float* ba  = b1 + b * IN_C;
    const float* bb2 = b2 + b * IN_C;

    float vdx = v_dna[dst * 3 + 0], vdy = v_dna[dst * 3 + 1], vdz = v_dna[dst * 3 + 2];
    float vpx = v_prot[src * 3 + 0], vpy = v_prot[src * 3 + 1], vpz = v_prot[src * 3 + 2];
    float nix = dna_vec[dst * 3 + 0], niy = dna_vec[dst * 3 + 1], niz = dna_vec[dst * 3 + 2];
    float njx = prot_vec[src * 3 + 0], njy = prot_vec[src * 3 + 1], njz = prot_vec[src * 3 + 2];
    float dx = vpx - vdx, dy = vpy - vdy, dz = vpz - vdz;
    float pf[4];
    pf[0] = sqrtf(dx * dx + dy * dy + dz * dz);
    pf[1] = angf(nix, niy, niz, dx, dy, dz);
    pf[2] = angf(njx, njy, njz, dx, dy, dz);
    pf[3] = angf(nix, niy, niz, njx, njy, njz);

    float h1[IN_C];
    #pragma unroll
    for (int c = 0; c < IN_C; ++c) h1[c] = ba[c];
    const float4* xp = reinterpret_cast<const float4*>(x_prot + (size_t)src * IN_C);
    #pragma unroll
    for (int kk = 0; kk < 8; ++kk) {
        float4 xv = xp[kk];
        float fs[4] = {xv.x, xv.y, xv.z, xv.w};
        #pragma unroll
        for (int j = 0; j < 4; ++j)
            #pragma unroll
            for (int c = 0; c < IN_C; ++c)
                h1[c] = fmaf(fs[j], Wa[(kk * 4 + j) * IN_C + c], h1[c]);
    }
    #pragma unroll
    for (int j = 0; j < 4; ++j)
        #pragma unroll
        for (int c = 0; c < IN_C; ++c)
            h1[c] = fmaf(pf[j], Wa[(32 + j) * IN_C + c], h1[c]);
    const float4* xd = reinterpret_cast<const float4*>(x_dna + (size_t)dst * IN_C);
    #pragma unroll
    for (int kk = 0; kk < 8; ++kk) {
        float4 xv = xd[kk];
        float fs[4] = {xv.x, xv.y, xv.z, xv.w};
        #pragma unroll
        for (int j = 0; j < 4; ++j)
            #pragma unroll
            for (int c = 0; c < IN_C; ++c)
                h1[c] = fmaf(fs[j], Wa[(36 + kk * 4 + j) * IN_C + c], h1[c]);
    }
    float h2[IN_C];
    #pragma unroll
    for (int c = 0; c < IN_C; ++c) h2[c] = bb2[c];
    #pragma unroll
    for (int k = 0; k < IN_C; ++k) {
        float f = fmaxf(h1[k], 0.0f);
        #pragma unroll
        for (int c = 0; c < IN_C; ++c)
            h2[c] = fmaf(f, Wb[k * IN_C + c], h2[c]);
    }
    float* cv = conv + (size_t)dst * IN_C;
    #pragma unroll
    for (int c = 0; c < IN_C; ++c)
        atomicAdd(&cv[c], fmaxf(h2[c], 0.0f));
}

extern "C" void kernel_launch(void* const* d_in, const int* in_sizes, int n_in,
                              void* d_out, int out_size, void* d_ws, size_t ws_size,
                              hipStream_t stream) {
    const float* x_dna    = (const float*)d_in[0];
    const float* v_dna    = (const float*)d_in[1];
    const float* x_prot   = (const float*)d_in[2];
    const float* v_prot   = (const float*)d_in[3];
    const float* prot_vec = (const float*)d_in[4];
    const float* dna_vec  = (const float*)d_in[5];
    const int*   esrc     = (const int*)d_in[6];
    const int*   edst     = (const int*)d_in[7];
    const float* W1       = (const float*)d_in[8];
    const float* b1       = (const float*)d_in[9];
    const float* W2       = (const float*)d_in[10];
    const float* b2       = (const float*)d_in[11];

    const int E  = in_sizes[6];
    const int ND = in_sizes[0] / IN_C;       // N_DNA
    const int NP = in_sizes[2] / IN_C;       // N_PROT
    const int half = out_size / 2;
    float* out  = (float*)d_out;
    float* conv = out + half;

    const int NDp = (ND + 160 + 31) & ~31;
    const int nblk_scan = (NDp + 1023) / 1024;
    const int eb = (E + 255) / 256;

    // ws: counts|hist|blk|pbs|gcur|bstart|rowcur|node_order|pool | yp8 | yd | geo
    const size_t base_ints = (size_t)ND + 256 + 256 + 8 + 512 + 512 + ND + NDp + E;
    const size_t ws_base   = base_ints * sizeof(int);
    const size_t yp_off    = (ws_base + 255) & ~(size_t)255;
    const size_t yp8_bytes = (size_t)NP * 4 * IN_C;                 // fp8: 32B/rec
    const size_t ypb_bytes = (size_t)NP * 4 * IN_C * 2;             // bf16 legacy
    const size_t yd_off    = yp_off + yp8_bytes;
    const size_t yd_bytes  = (size_t)ND * IN_C * sizeof(unsigned short);
    const size_t geo_off   = (yd_off + yd_bytes + 255) & ~(size_t)255;
    const size_t geo_bytes = (size_t)NP * 16;

    if (ND == half / IN_C && ws_size >= ws_base && nblk_scan <= 256) {
        int* counts     = (int*)d_ws;          // ND
        int* hist       = counts + ND;         // 256
        int* blk        = hist + 256;          // 256
        int* pbs        = blk + 256;           // 8
        int* gcur       = pbs + 8;             // 512
        int* bstart     = gcur + 512;          // 512
        int* rowcur     = bstart + 512;        // ND  (rowend in fast path)
        int* node_order = rowcur + ND;         // NDp
        int* pool_src   = node_order + NDp;    // E
        unsigned*       yp8 = (unsigned*)((char*)d_ws + yp_off);
        unsigned short* ypb = (unsigned short*)((char*)d_ws + yp_off);  // legacy alias
        unsigned short* yd  = (unsigned short*)((char*)d_ws + yd_off);
        unsigned*       geo = (unsigned*)((char*)d_ws + geo_off);

        int mode = 0;
        if (ws_size >= geo_off + geo_bytes && ND % 11 == 0 && NP % 8 == 0) mode = 2;
        else if (ws_size >= yp_off + ypb_bytes)                            mode = 1;

        const int nbkt = (ND + (1 << BK_SHIFT) - 1) >> BK_SHIFT;
        const size_t stage_bytes = (size_t)nbkt * BCAP * sizeof(unsigned);
        const bool fastfill = (mode == 2) && (NP < (1 << 17)) && (nbkt <= NBKT_MAX)
                              && (stage_bytes <= ws_size - yp_off)
                              && (E / nbkt + 512 < BCAP);

        if (fastfill) {
            unsigned* stage = yp8;   // overlay; consumed before k_precomp
            k_init<<<(NDp + 255) / 256, 256, 0, stream>>>(gcur, nbkt, hist,
                                                          node_order, NDp);
            int na = (E + TILE_A - 1) / TILE_A;
            k_passA<<<na, 256, 0, stream>>>(esrc, edst, E, nbkt, gcur, stage);
            k_bscan<<<1, 512, 0, stream>>>(gcur, nbkt, bstart);
            k_passB2<<<nbkt, 256, 0, stream>>>(stage, gcur, bstart, ND,
                                               counts, rowcur, pool_src, hist);
        } else {
            hipMemsetAsync(counts, 0, ((size_t)ND + 256) * sizeof(int), stream);
            k_count<<<eb, 256, 0, stream>>>(edst, E, counts);
            k_scan1<<<nblk_scan, 1024, 0, stream>>>(counts, ND, NDp, rowcur, blk,
                                                    hist, node_order);
            k_scan2<<<1, 256, 0, stream>>>(blk, nblk_scan);
            k_scan3<<<nblk_scan, 1024, 0, stream>>>(rowcur, blk, ND);
            k_fill<<<eb, 256, 0, stream>>>(esrc, edst, E, rowcur, pool_src);
        }

        k_padscan2<<<1, 256, 0, stream>>>(hist, pbs);
        k_assign<<<(ND + 255) / 256, 256, 0, stream>>>(counts, ND, hist, node_order);

        int NPpad = (NP + 63) & ~63;
        int NB = ND / 11;
        int NBpad = (NB + 63) & ~63;
        if (mode >= 1) {
            int tot = 4 * NPpad + (mode == 2 ? 11 * NBpad : 0);
            k_precomp<<<(tot + 255) / 256, 256, 0, stream>>>(
                x_prot, x_dna, v_prot, prot_vec, W1, b1,
                NP, NPpad, NB, NBpad, mode == 2, mode == 2,
                yp8, geo, ypb, yd);
        }

        if (mode == 2) {
            int nbm = (2 * NDp + 255) / 256;
            k_mfma<<<nbm, 256, 0, stream>>>(
                v_dna, dna_vec, W1, W2, b2,
                node_order, rowcur, counts, pool_src, pbs,
                yp8, geo, yd, NP, out, conv, NDp);
        } else if (mode == 1) {
            int nb4 = (4 * NDp + 255) / 256;
            k_nodes4<1><<<nb4, 256, 0, stream>>>(
                x_dna, v_dna, x_prot, v_prot, prot_vec, dna_vec,
                W1, b1, W2, b2, node_order, rowcur, counts, pool_src, pbs,
                ypb, NP, out, conv, NDp);
        } else {
            int nb4 = (4 * NDp + 255) / 256;
            k_nodes4<0><<<nb4, 256, 0, stream>>>(
                x_dna, v_dna, x_prot, v_prot, prot_vec, dna_vec,
                W1, b1, W2, b2, node_order, rowcur, counts, pool_src, pbs,
                nullptr, NP, out, conv, NDp);
        }
    } else {
        hipMemsetAsync(conv, 0, (size_t)half * sizeof(float), stream);
        k_edges_fallback<<<eb, 256, 0, stream>>>(
            x_dna, v_dna, x_prot, v_prot, prot_vec, dna_vec,
            esrc, edst, W1, b1, W2, b2, E, conv);
        hipMemcpyAsync(out, conv, (size_t)half * sizeof(float),
                       hipMemcpyDeviceToDevice, stream);
    }
}